// Round 3
// baseline (446.307 us; speedup 1.0000x reference)
//
#include <hip/hip_runtime.h>
#include <cstdint>
#include <cstddef>

typedef _Float16 f16;
typedef _Float16 f16x8 __attribute__((ext_vector_type(8)));
typedef float    f32x4 __attribute__((ext_vector_type(4)));

// ---------------- problem constants ----------------
constexpr int NTOKC  = 197;
constexpr int TTOK   = 128 * 197;         // 25216
constexpr int EMB    = 384;
constexpr int HID    = 1536;

// ---------------- workspace layout (bytes) ----------------
constexpr size_t OFF_CONVW   = 0;                        // 384*768 f16
constexpr size_t OFF_EW1T    = 1179648;                  // 4*1536*384 f16
constexpr size_t OFF_EW2T    = 5898240;                  // 4*384*1536 f16
constexpr size_t OFF_HEADW16 = 10616832;                 // 1024*384 f16
constexpr size_t OFF_XCLS16  = 11403264;                 // 384 f16
constexpr size_t OFF_Q       = 11404800;                 // 384 f32
constexpr size_t OFF_HCLS16  = 11799552;                 // 128*384 f16
constexpr size_t OFF_MASKW   = 11897856;                 // 128*4 f32
constexpr size_t OFF_EH      = 11899904;                 // 4*128*1536 f16
constexpr size_t OFF_EPART   = 13472768;                 // 4kc*4e*128*384 f32
constexpr size_t OFF_HFIN    = 16618496;                 // 128*384 f16
constexpr size_t OFF_XH      = 16716800;                 // TTOK*384 f16
constexpr size_t OFF_R       = 36082688;                 // 6*384 f32
constexpr size_t OFF_CVEC    = 36094976;                 // 6 f32
constexpr size_t WS_NEEDED   = 36704256;                 // ~36.7 MB

// ---------------- global_load_lds helper ----------------
__device__ __forceinline__ void gload16(const void* g, void* l) {
  __builtin_amdgcn_global_load_lds(
      (__attribute__((address_space(1))) void*)(void*)g,
      (__attribute__((address_space(3))) void*)l, 16, 0, 0);
}

// ---------------- prep: conv-w cast + head-w pad-cast in one launch ------------
__global__ __launch_bounds__(256) void prep_cast_k(
    const float* __restrict__ conv_w, const float* __restrict__ head_w,
    f16* __restrict__ convw, f16* __restrict__ headw16) {
  int i = blockIdx.x * 256 + threadIdx.x;
  if (i < 294912) convw[i] = (f16)conv_w[i];
  int j = i - 294912;
  if (j >= 0 && j < 1024 * 384) {
    int row = j / 384;
    headw16[j] = (row < 1000) ? (f16)head_w[j] : (f16)0.f;
  }
}

__global__ __launch_bounds__(256) void transpose_cast_k(
    const float* __restrict__ in, f16* __restrict__ outp, int R, int C) {
  __shared__ float tile[32][33];
  int e = blockIdx.z;
  const float* pin = in + (size_t)e * R * C;
  f16* pout = outp + (size_t)e * R * C;
  int c0 = blockIdx.x * 32, r0 = blockIdx.y * 32;
  int tx = threadIdx.x & 31, ty = threadIdx.x >> 5;
#pragma unroll
  for (int i = 0; i < 4; i++)
    tile[ty + 8 * i][tx] = pin[(size_t)(r0 + ty + 8 * i) * C + c0 + tx];
  __syncthreads();
#pragma unroll
  for (int i = 0; i < 4; i++)
    pout[(size_t)(c0 + ty + 8 * i) * R + r0 + tx] = (f16)tile[tx][ty + 8 * i];
}

// ---------------- cls precompute: xcls = LN(cls+pos[0]); q = Wq.xcls + bq ----------
__global__ __launch_bounds__(384) void clsprep_k(
    const float* __restrict__ cls, const float* __restrict__ posw,
    const float* __restrict__ g, const float* __restrict__ bb,
    const float* __restrict__ Wq, const float* __restrict__ bq,
    f16* __restrict__ xcls16, float* __restrict__ qout) {
  __shared__ float xs[EMB];
  __shared__ float red[16];
  int t = threadIdx.x, lane = t & 63, wave = t >> 6;
  float v = cls[t] + posw[t];
  float s = v, sq = v * v;
#pragma unroll
  for (int off = 32; off; off >>= 1) {
    s += __shfl_xor(s, off);
    sq += __shfl_xor(sq, off);
  }
  if (lane == 0) { red[wave] = s; red[8 + wave] = sq; }
  __syncthreads();
  float S = 0.f, SQ = 0.f;
#pragma unroll
  for (int i = 0; i < 6; i++) { S += red[i]; SQ += red[8 + i]; }
  float m = S * (1.f / 384.f);
  float rs = rsqrtf(SQ * (1.f / 384.f) - m * m + 1e-5f);
  float y = (v - m) * rs * g[t] + bb[t];
  xs[t] = y;
  xcls16[t] = (f16)y;
  __syncthreads();
  const float4* w4 = (const float4*)(Wq + (size_t)t * EMB);
  const float4* s4 = (const float4*)xs;
  float a = bq[t];
#pragma unroll 8
  for (int i = 0; i < 96; i++) {
    float4 xx = s4[i], ww = w4[i];
    a += xx.x * ww.x + xx.y * ww.y + xx.z * ww.z + xx.w * ww.w;
  }
  qout[t] = a;
}

// ---------------- R precompute: r_h = Wk_h^T q_h, c_h = q_h . bk_h -------------
__global__ __launch_bounds__(384) void rprep_k(
    const float* __restrict__ inp_w, const float* __restrict__ inp_b,
    const float* __restrict__ qv, float* __restrict__ Rg, float* __restrict__ Cg) {
  int h = blockIdx.x, t = threadIdx.x;
  __shared__ float qs[64];
  __shared__ float cred[64];
  if (t < 64) {
    float q = qv[h * 64 + t];
    qs[t] = q;
    cred[t] = q * inp_b[384 + h * 64 + t];
  }
  __syncthreads();
  const float* wp = inp_w + ((size_t)(384 + h * 64)) * 384 + t;
  float a = 0.f;
#pragma unroll 8
  for (int d = 0; d < 64; d++) a += wp[(size_t)d * 384] * qs[d];
  Rg[h * 384 + t] = a;
  if (t == 0) {
    float c = 0.f;
    for (int d = 0; d < 64; d++) c += cred[d];
    Cg[h] = c;
  }
}

__global__ __launch_bounds__(384) void bcast_cls_k(
    const f16* __restrict__ xcls16, f16* __restrict__ xh) {
  int b = blockIdx.x, t = threadIdx.x;
  xh[(size_t)b * NTOKC * EMB + t] = xcls16[t];
}

// ---------------- fused IMPLICIT-im2col patch-embed GEMM + bias + pos + LN1 ------
// A[row=patch p][col=c*256+ky*16+kx] = img[((b*3+c)*224 + py*16+ky)*224 + px*16+kx]
__global__ __launch_bounds__(1024) void embed_ln_k(
    const float* __restrict__ img, const f16* __restrict__ B,
    const float* __restrict__ bias, const float* __restrict__ posw,
    const float* __restrict__ g, const float* __restrict__ bb,
    f16* __restrict__ xh) {
  __shared__ f16 As[64 * 32];       // 4 KB
  __shared__ f16 Bs[384 * 32];      // 24 KB
  __shared__ float prm[3 * 384];    // bias | gamma | beta
  __shared__ float psum[64 * 4];
  __shared__ float pqsum[64 * 4];
  const int K = 768;
  const int tid = threadIdx.x;
  const int lane = tid & 63;
  const int wave = tid >> 6;        // 0..15
  const int rowgrp = wave & 3;
  const int colgrp = wave >> 2;
  const int m0 = (int)blockIdx.x * 64;
  const int fr = lane & 15;
  const int fq = lane >> 4;

  for (int i = tid; i < 384; i += 1024) {
    prm[i] = bias[i]; prm[384 + i] = g[i]; prm[768 + i] = bb[i];
  }

  f32x4 acc[6];
#pragma unroll
  for (int j = 0; j < 6; j++) acc[j] = f32x4{0.f, 0.f, 0.f, 0.f};

  const int sr = lane >> 2, sc = (lane & 3) * 8;
  // ---- A-staging lane constants (waves 0..3) ----
  const float* abase = nullptr;
  f16* adst = nullptr;
  if (wave < 4) {
    int row = m0 + wave * 16 + sr;          // patch index 0..25087
    int bimg = row / 196;
    int pp = row - bimg * 196;
    int py = pp / 14, px = pp - py * 14;
    int kx0 = sc & 15;                      // 0 or 8
    abase = img + ((size_t)(bimg * 3) * 224 + py * 16) * 224 + px * 16 + kx0;
    adst = As + (wave * 16 + sr) * 32 + sc;
  }
  // ---- B-staging pointers (waves 4..15) ----
  const f16* gb0 = nullptr;
  f16* lb0 = nullptr;
  if (wave >= 4) {
    int brow = (wave - 4) * 32;
    gb0 = B + (size_t)(brow + sr) * K + sc;
    lb0 = Bs + brow * 32;
  }

  for (int k0 = 0; k0 < K; k0 += 32) {
    if (wave < 4) {
      int col = k0 + sc;
      int c = col >> 8;
      int ky = (col >> 4) & 15;
      const float* src = abase + c * 50176 + ky * 224;
      float4 p0 = *(const float4*)src;
      float4 p1 = *(const float4*)(src + 4);
      f16x8 hv;
      hv[0] = (f16)p0.x; hv[1] = (f16)p0.y; hv[2] = (f16)p0.z; hv[3] = (f16)p0.w;
      hv[4] = (f16)p1.x; hv[5] = (f16)p1.y; hv[6] = (f16)p1.z; hv[7] = (f16)p1.w;
      *(f16x8*)adst = hv;
    } else {
      gload16(gb0, lb0); gload16(gb0 + (size_t)16 * K, lb0 + 16 * 32);
      gb0 += 32;
    }
    __syncthreads();
    f16x8 af = *(const f16x8*)&As[(rowgrp * 16 + fr) * 32 + fq * 8];
#pragma unroll
    for (int j = 0; j < 6; j++) {
      f16x8 bf = *(const f16x8*)&Bs[(colgrp * 96 + j * 16 + fr) * 32 + fq * 8];
      acc[j] = __builtin_amdgcn_mfma_f32_16x16x32_f16(af, bf, acc[j], 0, 0, 0);
    }
    __syncthreads();
  }

  // ---- epilogue: bias+pos, LN partials ----
  float v[4][6];
#pragma unroll
  for (int rg = 0; rg < 4; rg++) {
    int lrow = rowgrp * 16 + fq * 4 + rg;
    int row = m0 + lrow;
    int bimg = row / 196;
    int pp = row - bimg * 196;
    const float* prow = posw + (size_t)(pp + 1) * EMB;
    float s = 0.f, sq = 0.f;
#pragma unroll
    for (int j = 0; j < 6; j++) {
      int col = colgrp * 96 + j * 16 + fr;
      float t = acc[j][rg] + prm[col] + prow[col];
      v[rg][j] = t;
      s += t; sq += t * t;
    }
#pragma unroll
    for (int off = 1; off < 16; off <<= 1) {
      s += __shfl_xor(s, off);
      sq += __shfl_xor(sq, off);
    }
    if (fr == 0) { psum[lrow * 4 + colgrp] = s; pqsum[lrow * 4 + colgrp] = sq; }
  }
  __syncthreads();

#pragma unroll
  for (int rg = 0; rg < 4; rg++) {
    int lrow = rowgrp * 16 + fq * 4 + rg;
    float S = psum[lrow * 4] + psum[lrow * 4 + 1] + psum[lrow * 4 + 2] + psum[lrow * 4 + 3];
    float SQ = pqsum[lrow * 4] + pqsum[lrow * 4 + 1] + pqsum[lrow * 4 + 2] + pqsum[lrow * 4 + 3];
    float m = S * (1.f / 384.f);
    float rs = rsqrtf(SQ * (1.f / 384.f) - m * m + 1e-5f);
    int row = m0 + lrow;
    int bimg = row / 196;
    int pp = row - bimg * 196;
    f16* orow = xh + ((size_t)bimg * NTOKC + pp + 1) * EMB;
#pragma unroll
    for (int j = 0; j < 6; j++) {
      int col = colgrp * 96 + j * 16 + fr;
      orow[col] = (f16)((v[rg][j] - m) * rs * prm[384 + col] + prm[768 + col]);
    }
  }
}

// ---------------- fused attention tail: scores + softmax + u + Wv.u + out-proj
//                  + LN(ln1) + router top-2.  grid 128 (per batch), 768 thr.
__global__ __launch_bounds__(768) void combine_all_k(
    const f16* __restrict__ xh, const float* __restrict__ Rg,
    const float* __restrict__ Cg,
    const float* __restrict__ inp_w, const float* __restrict__ inp_b,
    const float* __restrict__ Wout, const float* __restrict__ bout,
    const float* __restrict__ lng, const float* __restrict__ lnb,
    const float* __restrict__ rw, const float* __restrict__ rb,
    f16* __restrict__ hcls16, float* __restrict__ maskw) {
  __shared__ float Rs[6 * 384];       // 9216 B
  __shared__ float cs[6];
  __shared__ float ps[6][208];        // raw scores -> exp(p)
  __shared__ float sinv[6];
  __shared__ float us[4 * 6 * 384];   // 36864 B  [quarter][head][col]
  __shared__ float po[2][384];        // 3072 B
  __shared__ float orow[384];
  __shared__ float o2row[384];
  __shared__ float red[16];
  __shared__ float part[6][4];
  __shared__ float logits[4];
  const int b = blockIdx.x, tid = threadIdx.x;
  const int wave = tid >> 6, lane = tid & 63;

  // ---- phase 0: load R, c ----
  for (int i = tid; i < 2304; i += 768) Rs[i] = Rg[i];
  if (tid < 6) cs[tid] = Cg[tid];
  __syncthreads();

  // ---- phase 0b: raw scores S[h][t] = xh[b,t,:] . r_h + c_h ----
  {
    const int grp = tid >> 2;         // 0..191  (token group)
    const int qtr = tid & 3;          // 96-col strip
    for (int t = grp; t < 197; t += 192) {
      const f16* xp = xh + ((size_t)b * NTOKC + t) * EMB + qtr * 96;
      float a[6];
#pragma unroll
      for (int h = 0; h < 6; h++) a[h] = 0.f;
#pragma unroll
      for (int i = 0; i < 12; i++) {
        f16x8 v = *(const f16x8*)(xp + i * 8);
        float xf[8];
#pragma unroll
        for (int j = 0; j < 8; j++) xf[j] = (float)v[j];
#pragma unroll
        for (int h = 0; h < 6; h++) {
          const float* rp = &Rs[h * 384 + qtr * 96 + i * 8];
          float aa = a[h];
#pragma unroll
          for (int j = 0; j < 8; j++) aa += xf[j] * rp[j];
          a[h] = aa;
        }
      }
#pragma unroll
      for (int h = 0; h < 6; h++) {
        a[h] += __shfl_xor(a[h], 1);
        a[h] += __shfl_xor(a[h], 2);
      }
      if (qtr < 4) {
        int h0 = qtr;
        ps[h0][t] = a[h0] + cs[h0];
        if (qtr < 2) ps[qtr + 4][t] = a[qtr + 4] + cs[qtr + 4];
      }
    }
  }
  __syncthreads();

  // ---- phase 1: per-head softmax over 197 keys (waves 0..5), in place ----
  if (wave < 6) {
    float z[4];
#pragma unroll
    for (int k = 0; k < 4; k++) {
      int t = lane + 64 * k;
      z[k] = (t < 197) ? ps[wave][t] * 0.125f : -1e30f;
    }
    float mx = fmaxf(fmaxf(z[0], z[1]), fmaxf(z[2], z[3]));
#pragma unroll
    for (int off = 32; off; off >>= 1) mx = fmaxf(mx, __shfl_xor(mx, off));
    float sum = 0.f;
#pragma unroll
    for (int k = 0; k < 4; k++) {
      int t = lane + 64 * k;
      if (t < 197) {
        float p = __expf(z[k] - mx);
        ps[wave][t] = p;
        sum += p;
      }
    }
#pragma unroll
    for (int off = 32; off; off >>= 1) sum += __shfl_xor(sum, off);
    if (lane == 0) sinv[wave] = 1.f / sum;
  }
  __syncthreads();

  // ---- phase 2: u[h][col] = sum_t p[h][t] * xh[b][t][col] ----
  {
    const int qg = tid / 192;
    const int within = tid - qg * 192;
    const int col0 = within * 2;
    const int t0 = 49 * qg;
    const int t1 = (qg == 3) ? 197 : 49 * (qg + 1);
    float acc0[6], acc1[6];
#pragma unroll
    for (int h = 0; h < 6; h++) { acc0[h] = 0.f; acc1[h] = 0.f; }
    const f16* xp = xh + ((size_t)b * NTOKC + t0) * EMB + col0;
    for (int t = t0; t < t1; t++) {
      float x0 = (float)xp[0];
      float x1 = (float)xp[1];
      xp += EMB;
#pragma unroll
      for (int h = 0; h < 6; h++) {
        float p = ps[h][t];
        acc0[h] += p * x0;
        acc1[h] += p * x1;
      }
    }
#pragma unroll
    for (int h = 0; h < 6; h++) {
      us[(qg * 6 + h) * 384 + col0] = acc0[h];
      us[(qg * 6 + h) * 384 + col0 + 1] = acc1[h];
    }
  }
  __syncthreads();
  for (int idx = tid; idx < 2304; idx += 768) {
    int h = idx / 384;
    us[idx] = (us[idx] + us[2304 + idx] + us[4608 + idx] + us[6912 + idx]) * sinv[h];
  }
  __syncthreads();

  // ---- phase 3: o[c] = bv[c] + Wv[c,:] . u[h(c)]  (f32 exact, half-dots) ----
  {
    const int c = (tid < 384) ? tid : tid - 384;
    const int jh = (tid < 384) ? 0 : 1;
    const int h = c >> 6;
    const float4* w4 = (const float4*)(inp_w + ((size_t)(768 + c)) * 384 + jh * 192);
    const float4* u4 = (const float4*)&us[h * 384 + jh * 192];
    float a = 0.f;
#pragma unroll 8
    for (int i = 0; i < 48; i++) {
      float4 ww = w4[i], uu = u4[i];
      a += ww.x * uu.x + ww.y * uu.y + ww.z * uu.z + ww.w * uu.w;
    }
    po[jh][c] = a;
  }
  __syncthreads();
  if (tid < 384) orow[tid] = po[0][tid] + po[1][tid] + inp_b[768 + tid];
  __syncthreads();

  // ---- phase 4: o2[c] = bout[c] + Wout[c,:] . orow  (half-dots, reuse po) ----
  {
    const int c = (tid < 384) ? tid : tid - 384;
    const int jh = (tid < 384) ? 0 : 1;
    const float4* w4 = (const float4*)(Wout + (size_t)c * 384 + jh * 192);
    const float4* u4 = (const float4*)&orow[jh * 192];
    float a = 0.f;
#pragma unroll 8
    for (int i = 0; i < 48; i++) {
      float4 ww = w4[i], uu = u4[i];
      a += ww.x * uu.x + ww.y * uu.y + ww.z * uu.z + ww.w * uu.w;
    }
    po[jh][c] = a;
  }
  __syncthreads();
  if (tid < 384) o2row[tid] = po[0][tid] + po[1][tid] + bout[tid];
  __syncthreads();

  // ---- phase 5: LN (ln1 params) + router top-2 ----
  float y = 0.f, vv = 0.f;
  if (tid < 384) {
    vv = o2row[tid];
    float s = vv, sq = vv * vv;
#pragma unroll
    for (int off = 32; off; off >>= 1) {
      s += __shfl_xor(s, off);
      sq += __shfl_xor(sq, off);
    }
    if (lane == 0) { red[wave] = s; red[8 + wave] = sq; }
  }
  __syncthreads();
  if (tid < 384) {
    float S = 0.f, SQ = 0.f;
#pragma unroll
    for (int i = 0; i < 6; i++) { S += red[i]; SQ += red[8 + i]; }
    float m = S * (1.f / 384.f);
    float rs = rsqrtf(SQ * (1.f / 384.f) - m * m + 1e-5f);
    y = (vv - m) * rs * lng[tid] + lnb[tid];
    hcls16[(size_t)b * EMB + tid] = (f16)y;
    float p0 = y * rw[tid];
    float p1 = y * rw[EMB + tid];
    float p2 = y * rw[2 * EMB + tid];
    float p3 = y * rw[3 * EMB + tid];
#pragma unroll
    for (int off = 32; off; off >>= 1) {
      p0 += __shfl_xor(p0, off);
      p1 += __shfl_xor(p1, off);
      p2 += __shfl_xor(p2, off);
      p3 += __shfl_xor(p3, off);
    }
    if (lane == 0) {
      part[wave][0] = p0; part[wave][1] = p1;
      part[wave][2] = p2; part[wave][3] = p3;
    }
  }
  __syncthreads();
  if (tid < 4) {
    float a = rb[tid];
#pragma unroll
    for (int i = 0; i < 6; i++) a += part[i][tid];
    logits[tid] = a;
  }
  __syncthreads();
  if (tid == 0) {
    float l0 = logits[0], l1 = logits[1], l2 = logits[2], l3 = logits[3];
    int i1 = 0; float b1 = l0;
    if (l1 > b1) { b1 = l1; i1 = 1; }
    if (l2 > b1) { b1 = l2; i1 = 2; }
    if (l3 > b1) { b1 = l3; i1 = 3; }
    int i2 = -1; float b2 = 0.f;
    float lv[4] = {l0, l1, l2, l3};
#pragma unroll
    for (int i = 0; i < 4; i++) {
      if (i == i1) continue;
      if (i2 < 0 || lv[i] > b2) { i2 = i; b2 = lv[i]; }
    }
#pragma unroll
    for (int e = 0; e < 4; e++)
      maskw[(size_t)b * 4 + e] = (e == i1 || e == i2) ? 0.5f : 0.f;
  }
}

// ---------------- MoE GEMM1: hcls16[128x384] @ ew1t^T + GELU -> ehbuf f16 ---------
__global__ __launch_bounds__(256) void moe1_k(
    const f16* __restrict__ A, const f16* __restrict__ Bm,
    const float* __restrict__ bias, f16* __restrict__ outh) {
  __shared__ f16 As[128 * 32];
  __shared__ f16 Bs[64 * 32];
  const int K = EMB;
  const int tid = threadIdx.x;
  const int lane = tid & 63;
  const int wave = tid >> 6;
  const int e = (int)blockIdx.y;
  const int n0 = (int)blockIdx.x * 64;
  const int wm = (wave >> 1) * 64;
  const int wn = (wave & 1) * 32;
  const int fr = lane & 15;
  const int fq = lane >> 4;
  Bm += (size_t)e * HID * EMB;
  bias += (size_t)e * HID;

  f32x4 acc[4][2];
#pragma unroll
  for (int i = 0; i < 4; i++)
#pragma unroll
    for (int j = 0; j < 2; j++) acc[i][j] = f32x4{0.f, 0.f, 0.f, 0.f};

  const int sr = lane >> 2;
  const int sc = (lane & 3) * 8;
  const f16* ag = A + (size_t)(wave * 32 + sr) * K + sc;
  const f16* bg = Bm + (size_t)(n0 + wave * 16 + sr) * K + sc;
  const size_t rstep = (size_t)16 * K;
  f16* la = As + wave * 32 * 32;
  f16* lb = Bs + wave * 16 * 32;

  for (int k0 = 0; k0 < K; k0 += 32) {
    gload16(ag, la);  gload16(ag + rstep, la + 16 * 32);
    gload16(bg, lb);
    ag += 32; bg += 32;
    __syncthreads();
    f16x8 af[4], bf[2];
#pragma unroll
    for (int i = 0; i < 4; i++)
      af[i] = *(const f16x8*)&As[(wm + i * 16 + fr) * 32 + fq * 8];
#pragma unroll
    for (int j = 0; j < 2; j++)
      bf[j] = *(const f16x8*)&Bs[(wn + j * 16 + fr) * 32 + fq * 8];
#pragma unroll
    for (int i = 0; i < 4; i++)
#pragma unroll
      for (int j = 0; j < 2; j++)
        acc[i][j] = __builtin_amdgcn_mfma_f32_16x16x32_f16(af[i], bf[j], acc[i][j], 0, 0, 0);
    __syncthreads();
  }

#pragma unroll
  for (int i = 0; i < 4; i++)
#pragma unroll
    for (int j = 0; j < 2; j++)
#pragma unroll
      for (int rg = 0; rg < 4; rg++) {
        int gm = wm + i * 16 + fq * 4 + rg;
        int gn = n0 + wn + j * 16 + fr;
        float v = acc[i][j][rg] + bias[gn];
        float gl = 0.5f * v * (1.0f + erff(v * 0.70710678118654752f));
        outh[(size_t)e * 128 * HID + (size_t)gm * HID + gn] = (f16)gl;
      }
}

// ---------------- MoE GEMM2 split-K ----------------
__global__ __launch_bounds__(256) void moe2_k(
    const f16* __restrict__ EH, const f16* __restrict__ W2,
    float* __restrict__ part) {
  __shared__ f16 As[128 * 32];
  __shared__ f16 Bs[64 * 32];
  const int tid = threadIdx.x;
  const int lane = tid & 63;
  const int wave = tid >> 6;
  const int n0 = (int)blockIdx.x * 64;
  const int e = (int)blockIdx.y;
  const int kc = (int)blockIdx.z;
  const int wm = (wave >> 1) * 64;
  const int wn = (wave & 1) * 32;
  const int fr = lane & 15;
  const int fq = lane >> 4;
  const f16* A = EH + (size_t)e * 128 * HID + kc * 384;
  const f16* B = W2 + (size_t)e * EMB * HID + kc * 384;

  f32x4 acc[4][2];
#pragma unroll
  for (int i = 0; i < 4; i++)
#pragma unroll
    for (int j = 0; j < 2; j++) acc[i][j] = f32x4{0.f, 0.f, 0.f, 0.f};

  const int sr = lane >> 2;
  const int sc = (lane & 3) * 8;
  const f16* ag = A + (size_t)(wave * 32 + sr) * HID + sc;
  const f16* bg = B + (size_t)(n0 + wave * 16 + sr) * HID + sc;
  const size_t rstep = (size_t)16 * HID;
  f16* la = As + wave * 32 * 32;
  f16* lb = Bs + wave * 16 * 32;

  for (int k0 = 0; k0 < 384; k0 += 32) {
    gload16(ag, la);  gload16(ag + rstep, la + 16 * 32);
    gload16(bg, lb);
    ag += 32; bg += 32;
    __syncthreads();
    f16x8 af[4], bf[2];
#pragma unroll
    for (int i = 0; i < 4; i++)
      af[i] = *(const f16x8*)&As[(wm + i * 16 + fr) * 32 + fq * 8];
#pragma unroll
    for (int j = 0; j < 2; j++)
      bf[j] = *(const f16x8*)&Bs[(wn + j * 16 + fr) * 32 + fq * 8];
#pragma unroll
    for (int i = 0; i < 4; i++)
#pragma unroll
      for (int j = 0; j < 2; j++)
        acc[i][j] = __builtin_amdgcn_mfma_f32_16x16x32_f16(af[i], bf[j], acc[i][j], 0, 0, 0);
    __syncthreads();
  }

#pragma unroll
  for (int i = 0; i < 4; i++)
#pragma unroll
    for (int j = 0; j < 2; j++)
#pragma unroll
      for (int rg = 0; rg < 4; rg++) {
        int gm = wm + i * 16 + fq * 4 + rg;
        int gn = n0 + wn + j * 16 + fr;
        part[(((size_t)kc * 4 + e) * 128 + gm) * EMB + gn] = acc[i][j][rg];
      }
}

// ---------------- combine split-K + experts + LN2 -> f16 ----------------
__global__ __launch_bounds__(384) void combine_ln2_k(
    const float* __restrict__ part, const float* __restrict__ eb2,
    const float* __restrict__ maskw,
    const float* __restrict__ g, const float* __restrict__ bb,
    f16* __restrict__ hfin) {
  __shared__ float red[16];
  int b = blockIdx.x, t = threadIdx.x;
  int lane = t & 63, wave = t >> 6;
  float v = 0.f;
#pragma unroll
  for (int e = 0; e < 4; e++) {
    float s = eb2[e * EMB + t];
#pragma unroll
    for (int kc = 0; kc < 4; kc++)
      s += part[(((size_t)kc * 4 + e) * 128 + b) * EMB + t];
    v += maskw[b * 4 + e] * s;
  }
  float s = v, sq = v * v;
#pragma unroll
  for (int off = 32; off; off >>= 1) {
    s += __shfl_xor(s, off);
    sq += __shfl_xor(sq, off);
  }
  if (lane == 0) { red[wave] = s; red[8 + wave] = sq; }
  __syncthreads();
  float S = 0.f, SQ = 0.f;
#pragma unroll
  for (int i = 0; i < 6; i++) { S += red[i]; SQ += red[8 + i]; }
  float m = S * (1.f / 384.f);
  float rs = rsqrtf(SQ * (1.f / 384.f) - m * m + 1e-5f);
  hfin[(size_t)b * EMB + t] = (f16)((v - m) * rs * g[t] + bb[t]);
}

// ---------------- head GEMM ----------------
__global__ __launch_bounds__(256) void head_gemm_k(
    const f16* __restrict__ A, const f16* __restrict__ B,
    const float* __restrict__ hb, float* __restrict__ outp) {
  __shared__ f16 As[128 * 32];
  __shared__ f16 Bs[128 * 32];
  const int K = 384;
  const int tid = threadIdx.x;
  const int lane = tid & 63;
  const int wave = tid >> 6;
  const int n0 = (int)blockIdx.x * 128;
  const int wm = (wave >> 1) * 64;
  const int wn = (wave & 1) * 64;
  const int fr = lane & 15;
  const int fq = lane >> 4;

  f32x4 acc[4][4];
#pragma unroll
  for (int i = 0; i < 4; i++)
#pragma unroll
    for (int j = 0; j < 4; j++) acc[i][j] = f32x4{0.f, 0.f, 0.f, 0.f};

  const int srow = wave * 32 + (lane >> 2);
  const int scol = (lane & 3) * 8;
  const f16* ag = A + (size_t)srow * K + scol;
  const f16* bg = B + (size_t)(n0 + srow) * K + scol;
  const size_t rstep = (size_t)16 * K;
  f16* la = As + wave * 32 * 32;
  f16* lb = Bs + wave * 32 * 32;

  for (int k0 = 0; k0 < K; k0 += 32) {
    gload16(ag, la);          gload16(ag + rstep, la + 16 * 32);
    gload16(bg, lb);          gload16(bg + rstep, lb + 16 * 32);
    ag += 32; bg += 32;
    __syncthreads();
    f16x8 af[4], bf[4];
#pragma unroll
    for (int i = 0; i < 4; i++) {
      af[i] = *(const f16x8*)&As[(wm + i * 16 + fr) * 32 + fq * 8];
      bf[i] = *(const f16x8*)&Bs[(wn + i * 16 + fr) * 32 + fq * 8];
    }
#pragma unroll
    for (int i = 0; i < 4; i++)
#pragma unroll
      for (int j = 0; j < 4; j++)
        acc[i][j] = __builtin_amdgcn_mfma_f32_16x16x32_f16(af[i], bf[j], acc[i][j], 0, 0, 0);
    __syncthreads();
  }

#pragma unroll
  for (int i = 0; i < 4; i++)
#pragma unroll
    for (int j = 0; j < 4; j++)
#pragma unroll
      for (int rg = 0; rg < 4; rg++) {
        int gm = wm + i * 16 + fq * 4 + rg;
        int gn = n0 + wn + j * 16 + fr;
        if (gn < 1000)
          outp[(size_t)gm * 1000 + gn] = acc[i][j][rg] + hb[gn];
      }
}

// ---------------- host ----------------
extern "C" void kernel_launch(void* const* d_in, const int* in_sizes, int n_in,
                              void* d_out, int out_size, void* d_ws, size_t ws_size,
                              hipStream_t stream) {
  const float* x      = (const float*)d_in[0];
  const float* conv_w = (const float*)d_in[1];
  const float* conv_b = (const float*)d_in[2];
  const float* cls_t  = (const float*)d_in[3];
  const float* pos    = (const float*)d_in[4];
  const float* ln1_g  = (const float*)d_in[5];
  const float* ln1_b  = (const float*)d_in[6];
  const float* inp_w  = (const float*)d_in[7];
  const float* inp_b  = (const float*)d_in[8];
  const float* outp_w = (const float*)d_in[9];
  const float* outp_b = (const float*)d_in[10];
  const float* rt_w   = (const float*)d_in[11];
  const float* rt_b   = (const float*)d_in[12];
  const float* ew1    = (const float*)d_in[13];
  const float* eb1    = (const float*)d_in[14];
  const float* ew2    = (const float*)d_in[15];
  const float* eb2    = (const float*)d_in[16];
  const float* ln2_g  = (const float*)d_in[17];
  const float* ln2_b  = (const float*)d_in[18];
  const float* head_w = (const float*)d_in[19];
  const float* head_b = (const float*)d_in[20];
  float* out = (float*)d_out;
  char* w = (char*)d_ws;
  if (ws_size < WS_NEEDED) return;

  f16* convw    = (f16*)(w + OFF_CONVW);
  f16* ew1t     = (f16*)(w + OFF_EW1T);
  f16* ew2t     = (f16*)(w + OFF_EW2T);
  f16* headw16  = (f16*)(w + OFF_HEADW16);
  f16* xcls16   = (f16*)(w + OFF_XCLS16);
  float* qvec   = (float*)(w + OFF_Q);
  f16* hcls16   = (f16*)(w + OFF_HCLS16);
  float* maskw  = (float*)(w + OFF_MASKW);
  f16* ehbuf    = (f16*)(w + OFF_EH);
  float* epart  = (float*)(w + OFF_EPART);
  f16* hfin     = (f16*)(w + OFF_HFIN);
  f16* xh       = (f16*)(w + OFF_XH);
  float* Rg     = (float*)(w + OFF_R);
  float* Cg     = (float*)(w + OFF_CVEC);

  // ---- weight prep ----
  prep_cast_k<<<dim3((294912 + 393216 + 255) / 256), 256, 0, stream>>>(
      conv_w, head_w, convw, headw16);
  transpose_cast_k<<<dim3(48, 12, 4), 256, 0, stream>>>(ew1, ew1t, 384, 1536);
  transpose_cast_k<<<dim3(12, 48, 4), 256, 0, stream>>>(ew2, ew2t, 1536, 384);

  // ---- cls precompute + r_h precompute + broadcast ----
  clsprep_k<<<dim3(1), 384, 0, stream>>>(cls_t, pos, ln1_g, ln1_b, inp_w, inp_b, xcls16, qvec);
  rprep_k<<<dim3(6), 384, 0, stream>>>(inp_w, inp_b, qvec, Rg, Cg);
  bcast_cls_k<<<dim3(128), 384, 0, stream>>>(xcls16, xh);

  // ---- fused implicit-im2col embed GEMM + LN1 -> xh patch rows ----
  embed_ln_k<<<dim3(392), 1024, 0, stream>>>(x, convw, conv_b, pos, ln1_g, ln1_b, xh);

  // ---- fused attention tail: scores+softmax+u+Wv.u+out-proj+LN+router ----
  combine_all_k<<<dim3(128), 768, 0, stream>>>(
      xh, Rg, Cg, inp_w, inp_b, outp_w, outp_b,
      ln1_g, ln1_b, rt_w, rt_b, hcls16, maskw);

  // ---- MoE ----
  moe1_k<<<dim3(24, 4), 256, 0, stream>>>(hcls16, ew1t, eb1, ehbuf);
  moe2_k<<<dim3(6, 4, 4), 256, 0, stream>>>(ehbuf, ew2t, epart);
  combine_ln2_k<<<dim3(128), 384, 0, stream>>>(epart, eb2, maskw, ln2_g, ln2_b, hfin);

  // ---- head ----
  head_gemm_k<<<dim3(8), 256, 0, stream>>>(hfin, headw16, head_b, out);
  (void)in_sizes; (void)n_in; (void)out_size;
}

// Round 4
// 435.305 us; speedup vs baseline: 1.0253x; 1.0253x over previous
//
#include <hip/hip_runtime.h>
#include <cstdint>
#include <cstddef>

typedef _Float16 f16;
typedef _Float16 f16x8 __attribute__((ext_vector_type(8)));
typedef float    f32x4 __attribute__((ext_vector_type(4)));

// ---------------- problem constants ----------------
constexpr int NTOKC  = 197;
constexpr int TTOK   = 128 * 197;         // 25216
constexpr int EMB    = 384;
constexpr int HID    = 1536;

// ---------------- workspace layout (bytes) ----------------
constexpr size_t OFF_CONVW   = 0;                        // 384*768 f16
constexpr size_t OFF_EW1T    = 1179648;                  // 4*1536*384 f16
constexpr size_t OFF_EW2T    = 5898240;                  // 4*384*1536 f16
constexpr size_t OFF_HEADW16 = 10616832;                 // 1024*384 f16
constexpr size_t OFF_XCLS16  = 11403264;                 // 384 f16
constexpr size_t OFF_Q       = 11404800;                 // 384 f32
constexpr size_t OFF_HCLS16  = 11799552;                 // 128*384 f16
constexpr size_t OFF_MASKW   = 11897856;                 // 128*4 f32
constexpr size_t OFF_EH      = 11899904;                 // 4*128*1536 f16
constexpr size_t OFF_EPART   = 13472768;                 // 4kc*4e*128*384 f32
constexpr size_t OFF_HFIN    = 16618496;                 // 128*384 f16
constexpr size_t OFF_XH      = 16716800;                 // TTOK*384 f16
constexpr size_t OFF_R       = 36082688;                 // 6*384 f32
constexpr size_t OFF_CVEC    = 36094976;                 // 6 f32
constexpr size_t OFF_U16     = 36099072;                 // 128*2304 f16
constexpr size_t OFF_O16     = 36688896;                 // 128*384 f16
constexpr size_t OFF_WV16    = 36787200;                 // 384*384 f16
constexpr size_t OFF_WOUT16  = 37082112;                 // 384*384 f16
constexpr size_t OFF_O2CLS   = 37377024;                 // 128*384 f32
constexpr size_t WS_NEEDED   = 37573632;                 // ~37.6 MB

// ---------------- global_load_lds helper ----------------
__device__ __forceinline__ void gload16(const void* g, void* l) {
  __builtin_amdgcn_global_load_lds(
      (__attribute__((address_space(1))) void*)(void*)g,
      (__attribute__((address_space(3))) void*)l, 16, 0, 0);
}

// ---------------- prep: all weight casts in one launch ------------
// conv_w(294912) | head_w pad(393216) | Wv=inp_w rows 768.. (147456) | Wout(147456)
__global__ __launch_bounds__(256) void prep_cast_k(
    const float* __restrict__ conv_w, const float* __restrict__ head_w,
    const float* __restrict__ inp_w, const float* __restrict__ outp_w,
    f16* __restrict__ convw, f16* __restrict__ headw16,
    f16* __restrict__ wv16, f16* __restrict__ wout16) {
  int i = blockIdx.x * 256 + threadIdx.x;
  if (i < 294912) convw[i] = (f16)conv_w[i];
  int j = i - 294912;
  if (j >= 0 && j < 393216) {
    int row = j / 384;
    headw16[j] = (row < 1000) ? (f16)head_w[j] : (f16)0.f;
  }
  int k = i - 688128;
  if (k >= 0 && k < 147456) wv16[k] = (f16)inp_w[294912 + k];
  int l = i - 835584;
  if (l >= 0 && l < 147456) wout16[l] = (f16)outp_w[l];
}

__global__ __launch_bounds__(256) void transpose_cast_k(
    const float* __restrict__ in, f16* __restrict__ outp, int R, int C) {
  __shared__ float tile[32][33];
  int e = blockIdx.z;
  const float* pin = in + (size_t)e * R * C;
  f16* pout = outp + (size_t)e * R * C;
  int c0 = blockIdx.x * 32, r0 = blockIdx.y * 32;
  int tx = threadIdx.x & 31, ty = threadIdx.x >> 5;
#pragma unroll
  for (int i = 0; i < 4; i++)
    tile[ty + 8 * i][tx] = pin[(size_t)(r0 + ty + 8 * i) * C + c0 + tx];
  __syncthreads();
#pragma unroll
  for (int i = 0; i < 4; i++)
    pout[(size_t)(c0 + ty + 8 * i) * R + r0 + tx] = (f16)tile[tx][ty + 8 * i];
}

// ---------------- cls precompute: xcls = LN(cls+pos[0]); q = Wq.xcls + bq ----------
__global__ __launch_bounds__(384) void clsprep_k(
    const float* __restrict__ cls, const float* __restrict__ posw,
    const float* __restrict__ g, const float* __restrict__ bb,
    const float* __restrict__ Wq, const float* __restrict__ bq,
    f16* __restrict__ xcls16, float* __restrict__ qout) {
  __shared__ float xs[EMB];
  __shared__ float red[16];
  int t = threadIdx.x, lane = t & 63, wave = t >> 6;
  float v = cls[t] + posw[t];
  float s = v, sq = v * v;
#pragma unroll
  for (int off = 32; off; off >>= 1) {
    s += __shfl_xor(s, off);
    sq += __shfl_xor(sq, off);
  }
  if (lane == 0) { red[wave] = s; red[8 + wave] = sq; }
  __syncthreads();
  float S = 0.f, SQ = 0.f;
#pragma unroll
  for (int i = 0; i < 6; i++) { S += red[i]; SQ += red[8 + i]; }
  float m = S * (1.f / 384.f);
  float rs = rsqrtf(SQ * (1.f / 384.f) - m * m + 1e-5f);
  float y = (v - m) * rs * g[t] + bb[t];
  xs[t] = y;
  xcls16[t] = (f16)y;
  __syncthreads();
  const float4* w4 = (const float4*)(Wq + (size_t)t * EMB);
  const float4* s4 = (const float4*)xs;
  float a = bq[t];
#pragma unroll 8
  for (int i = 0; i < 96; i++) {
    float4 xx = s4[i], ww = w4[i];
    a += xx.x * ww.x + xx.y * ww.y + xx.z * ww.z + xx.w * ww.w;
  }
  qout[t] = a;
}

// ---------------- R precompute: r_h = Wk_h^T q_h, c_h = q_h . bk_h -------------
__global__ __launch_bounds__(384) void rprep_k(
    const float* __restrict__ inp_w, const float* __restrict__ inp_b,
    const float* __restrict__ qv, float* __restrict__ Rg, float* __restrict__ Cg) {
  int h = blockIdx.x, t = threadIdx.x;
  __shared__ float qs[64];
  __shared__ float cred[64];
  if (t < 64) {
    float q = qv[h * 64 + t];
    qs[t] = q;
    cred[t] = q * inp_b[384 + h * 64 + t];
  }
  __syncthreads();
  const float* wp = inp_w + ((size_t)(384 + h * 64)) * 384 + t;
  float a = 0.f;
#pragma unroll 8
  for (int d = 0; d < 64; d++) a += wp[(size_t)d * 384] * qs[d];
  Rg[h * 384 + t] = a;
  if (t == 0) {
    float c = 0.f;
    for (int d = 0; d < 64; d++) c += cred[d];
    Cg[h] = c;
  }
}

__global__ __launch_bounds__(384) void bcast_cls_k(
    const f16* __restrict__ xcls16, f16* __restrict__ xh) {
  int b = blockIdx.x, t = threadIdx.x;
  xh[(size_t)b * NTOKC * EMB + t] = xcls16[t];
}

// ---------------- fused IMPLICIT-im2col patch-embed GEMM + bias + pos + LN1 ------
__global__ __launch_bounds__(1024) void embed_ln_k(
    const float* __restrict__ img, const f16* __restrict__ B,
    const float* __restrict__ bias, const float* __restrict__ posw,
    const float* __restrict__ g, const float* __restrict__ bb,
    f16* __restrict__ xh) {
  __shared__ f16 As[64 * 32];       // 4 KB
  __shared__ f16 Bs[384 * 32];      // 24 KB
  __shared__ float prm[3 * 384];    // bias | gamma | beta
  __shared__ float psum[64 * 4];
  __shared__ float pqsum[64 * 4];
  const int K = 768;
  const int tid = threadIdx.x;
  const int lane = tid & 63;
  const int wave = tid >> 6;        // 0..15
  const int rowgrp = wave & 3;
  const int colgrp = wave >> 2;
  const int m0 = (int)blockIdx.x * 64;
  const int fr = lane & 15;
  const int fq = lane >> 4;

  for (int i = tid; i < 384; i += 1024) {
    prm[i] = bias[i]; prm[384 + i] = g[i]; prm[768 + i] = bb[i];
  }

  f32x4 acc[6];
#pragma unroll
  for (int j = 0; j < 6; j++) acc[j] = f32x4{0.f, 0.f, 0.f, 0.f};

  const int sr = lane >> 2, sc = (lane & 3) * 8;
  const float* abase = nullptr;
  f16* adst = nullptr;
  if (wave < 4) {
    int row = m0 + wave * 16 + sr;          // patch index 0..25087
    int bimg = row / 196;
    int pp = row - bimg * 196;
    int py = pp / 14, px = pp - py * 14;
    int kx0 = sc & 15;                      // 0 or 8
    abase = img + ((size_t)(bimg * 3) * 224 + py * 16) * 224 + px * 16 + kx0;
    adst = As + (wave * 16 + sr) * 32 + sc;
  }
  const f16* gb0 = nullptr;
  f16* lb0 = nullptr;
  if (wave >= 4) {
    int brow = (wave - 4) * 32;
    gb0 = B + (size_t)(brow + sr) * K + sc;
    lb0 = Bs + brow * 32;
  }

  for (int k0 = 0; k0 < K; k0 += 32) {
    if (wave < 4) {
      int col = k0 + sc;
      int c = col >> 8;
      int ky = (col >> 4) & 15;
      const float* src = abase + c * 50176 + ky * 224;
      float4 p0 = *(const float4*)src;
      float4 p1 = *(const float4*)(src + 4);
      f16x8 hv;
      hv[0] = (f16)p0.x; hv[1] = (f16)p0.y; hv[2] = (f16)p0.z; hv[3] = (f16)p0.w;
      hv[4] = (f16)p1.x; hv[5] = (f16)p1.y; hv[6] = (f16)p1.z; hv[7] = (f16)p1.w;
      *(f16x8*)adst = hv;
    } else {
      gload16(gb0, lb0); gload16(gb0 + (size_t)16 * K, lb0 + 16 * 32);
      gb0 += 32;
    }
    __syncthreads();
    f16x8 af = *(const f16x8*)&As[(rowgrp * 16 + fr) * 32 + fq * 8];
#pragma unroll
    for (int j = 0; j < 6; j++) {
      f16x8 bf = *(const f16x8*)&Bs[(colgrp * 96 + j * 16 + fr) * 32 + fq * 8];
      acc[j] = __builtin_amdgcn_mfma_f32_16x16x32_f16(af, bf, acc[j], 0, 0, 0);
    }
    __syncthreads();
  }

  float v[4][6];
#pragma unroll
  for (int rg = 0; rg < 4; rg++) {
    int lrow = rowgrp * 16 + fq * 4 + rg;
    int row = m0 + lrow;
    int bimg = row / 196;
    int pp = row - bimg * 196;
    const float* prow = posw + (size_t)(pp + 1) * EMB;
    float s = 0.f, sq = 0.f;
#pragma unroll
    for (int j = 0; j < 6; j++) {
      int col = colgrp * 96 + j * 16 + fr;
      float t = acc[j][rg] + prm[col] + prow[col];
      v[rg][j] = t;
      s += t; sq += t * t;
    }
#pragma unroll
    for (int off = 1; off < 16; off <<= 1) {
      s += __shfl_xor(s, off);
      sq += __shfl_xor(sq, off);
    }
    if (fr == 0) { psum[lrow * 4 + colgrp] = s; pqsum[lrow * 4 + colgrp] = sq; }
  }
  __syncthreads();

#pragma unroll
  for (int rg = 0; rg < 4; rg++) {
    int lrow = rowgrp * 16 + fq * 4 + rg;
    float S = psum[lrow * 4] + psum[lrow * 4 + 1] + psum[lrow * 4 + 2] + psum[lrow * 4 + 3];
    float SQ = pqsum[lrow * 4] + pqsum[lrow * 4 + 1] + pqsum[lrow * 4 + 2] + pqsum[lrow * 4 + 3];
    float m = S * (1.f / 384.f);
    float rs = rsqrtf(SQ * (1.f / 384.f) - m * m + 1e-5f);
    int row = m0 + lrow;
    int bimg = row / 196;
    int pp = row - bimg * 196;
    f16* orow = xh + ((size_t)bimg * NTOKC + pp + 1) * EMB;
#pragma unroll
    for (int j = 0; j < 6; j++) {
      int col = colgrp * 96 + j * 16 + fr;
      orow[col] = (f16)((v[rg][j] - m) * rs * prm[384 + col] + prm[768 + col]);
    }
  }
}

// ---------------- scores + softmax + u  -> U16 (f16)  [HW-passed phases 0-2] ----
__global__ __launch_bounds__(768) void score_sm_u_k(
    const f16* __restrict__ xh, const float* __restrict__ Rg,
    const float* __restrict__ Cg, f16* __restrict__ U16) {
  __shared__ float Rs[6 * 384];
  __shared__ float cs[6];
  __shared__ float ps[6][208];
  __shared__ float sinv[6];
  __shared__ float us[4 * 6 * 384];
  const int b = blockIdx.x, tid = threadIdx.x;
  const int wave = tid >> 6, lane = tid & 63;

  for (int i = tid; i < 2304; i += 768) Rs[i] = Rg[i];
  if (tid < 6) cs[tid] = Cg[tid];
  __syncthreads();

  // scores S[h][t] = xh[b,t,:] . r_h + c_h
  {
    const int grp = tid >> 2;
    const int qtr = tid & 3;
    for (int t = grp; t < 197; t += 192) {
      const f16* xp = xh + ((size_t)b * NTOKC + t) * EMB + qtr * 96;
      float a[6];
#pragma unroll
      for (int h = 0; h < 6; h++) a[h] = 0.f;
#pragma unroll
      for (int i = 0; i < 12; i++) {
        f16x8 v = *(const f16x8*)(xp + i * 8);
        float xf[8];
#pragma unroll
        for (int j = 0; j < 8; j++) xf[j] = (float)v[j];
#pragma unroll
        for (int h = 0; h < 6; h++) {
          const float* rp = &Rs[h * 384 + qtr * 96 + i * 8];
          float aa = a[h];
#pragma unroll
          for (int j = 0; j < 8; j++) aa += xf[j] * rp[j];
          a[h] = aa;
        }
      }
#pragma unroll
      for (int h = 0; h < 6; h++) {
        a[h] += __shfl_xor(a[h], 1);
        a[h] += __shfl_xor(a[h], 2);
      }
      if (qtr < 4) {
        int h0 = qtr;
        ps[h0][t] = a[h0] + cs[h0];
        if (qtr < 2) ps[qtr + 4][t] = a[qtr + 4] + cs[qtr + 4];
      }
    }
  }
  __syncthreads();

  // per-head softmax over 197 keys (waves 0..5), in place
  if (wave < 6) {
    float z[4];
#pragma unroll
    for (int k = 0; k < 4; k++) {
      int t = lane + 64 * k;
      z[k] = (t < 197) ? ps[wave][t] * 0.125f : -1e30f;
    }
    float mx = fmaxf(fmaxf(z[0], z[1]), fmaxf(z[2], z[3]));
#pragma unroll
    for (int off = 32; off; off >>= 1) mx = fmaxf(mx, __shfl_xor(mx, off));
    float sum = 0.f;
#pragma unroll
    for (int k = 0; k < 4; k++) {
      int t = lane + 64 * k;
      if (t < 197) {
        float p = __expf(z[k] - mx);
        ps[wave][t] = p;
        sum += p;
      }
    }
#pragma unroll
    for (int off = 32; off; off >>= 1) sum += __shfl_xor(sum, off);
    if (lane == 0) sinv[wave] = 1.f / sum;
  }
  __syncthreads();

  // u[h][col] = sum_t p[h][t] * xh[b][t][col]
  {
    const int qg = tid / 192;
    const int within = tid - qg * 192;
    const int col0 = within * 2;
    const int t0 = 49 * qg;
    const int t1 = (qg == 3) ? 197 : 49 * (qg + 1);
    float acc0[6], acc1[6];
#pragma unroll
    for (int h = 0; h < 6; h++) { acc0[h] = 0.f; acc1[h] = 0.f; }
    const f16* xp = xh + ((size_t)b * NTOKC + t0) * EMB + col0;
    for (int t = t0; t < t1; t++) {
      float x0 = (float)xp[0];
      float x1 = (float)xp[1];
      xp += EMB;
#pragma unroll
      for (int h = 0; h < 6; h++) {
        float p = ps[h][t];
        acc0[h] += p * x0;
        acc1[h] += p * x1;
      }
    }
#pragma unroll
    for (int h = 0; h < 6; h++) {
      us[(qg * 6 + h) * 384 + col0] = acc0[h];
      us[(qg * 6 + h) * 384 + col0 + 1] = acc1[h];
    }
  }
  __syncthreads();
  for (int idx = tid; idx < 2304; idx += 768) {
    int h = idx / 384;
    float uval = (us[idx] + us[2304 + idx] + us[4608 + idx] + us[6912 + idx]) * sinv[h];
    U16[(size_t)b * 2304 + idx] = (f16)uval;
  }
}

// ---------------- V-projection GEMM: o[b][h*64+n] = Wv_h[n,:].u[b][h] + bv ------
// grid (6 heads), 256 thr. M=128, N=64, K=384. A=U16 (row stride 2304, col off h*384)
__global__ __launch_bounds__(256) void vproj_k(
    const f16* __restrict__ U16, const f16* __restrict__ wv16,
    const float* __restrict__ inp_b, f16* __restrict__ O16) {
  __shared__ f16 As[128 * 32];
  __shared__ f16 Bs[64 * 32];
  const int tid = threadIdx.x;
  const int lane = tid & 63;
  const int wave = tid >> 6;
  const int h = (int)blockIdx.x;
  const int wm = (wave >> 1) * 64;
  const int wn = (wave & 1) * 32;
  const int fr = lane & 15;
  const int fq = lane >> 4;
  const float* bv = inp_b + 768 + h * 64;

  f32x4 acc[4][2];
#pragma unroll
  for (int i = 0; i < 4; i++)
#pragma unroll
    for (int j = 0; j < 2; j++) acc[i][j] = f32x4{0.f, 0.f, 0.f, 0.f};

  const int sr = lane >> 2;
  const int sc = (lane & 3) * 8;
  const f16* ag = U16 + (size_t)(wave * 32 + sr) * 2304 + h * 384 + sc;
  const f16* bg = wv16 + (size_t)(h * 64 + wave * 16 + sr) * 384 + sc;
  const size_t rstepA = (size_t)16 * 2304;
  f16* la = As + wave * 32 * 32;
  f16* lb = Bs + wave * 16 * 32;

  for (int k0 = 0; k0 < 384; k0 += 32) {
    gload16(ag, la);  gload16(ag + rstepA, la + 16 * 32);
    gload16(bg, lb);
    ag += 32; bg += 32;
    __syncthreads();
    f16x8 af[4], bf[2];
#pragma unroll
    for (int i = 0; i < 4; i++)
      af[i] = *(const f16x8*)&As[(wm + i * 16 + fr) * 32 + fq * 8];
#pragma unroll
    for (int j = 0; j < 2; j++)
      bf[j] = *(const f16x8*)&Bs[(wn + j * 16 + fr) * 32 + fq * 8];
#pragma unroll
    for (int i = 0; i < 4; i++)
#pragma unroll
      for (int j = 0; j < 2; j++)
        acc[i][j] = __builtin_amdgcn_mfma_f32_16x16x32_f16(af[i], bf[j], acc[i][j], 0, 0, 0);
    __syncthreads();
  }

#pragma unroll
  for (int i = 0; i < 4; i++)
#pragma unroll
    for (int j = 0; j < 2; j++)
#pragma unroll
      for (int rg = 0; rg < 4; rg++) {
        int gm = wm + i * 16 + fq * 4 + rg;
        int gn = wn + j * 16 + fr;
        O16[(size_t)gm * EMB + h * 64 + gn] = (f16)(acc[i][j][rg] + bv[gn]);
      }
}

// ---------------- out-projection GEMM: o2 = Wout.o + bout (f32 out) -------------
// grid (6 n-tiles of 64), 256 thr. M=128, N=64, K=384.
__global__ __launch_bounds__(256) void oproj_k(
    const f16* __restrict__ O16, const f16* __restrict__ wout16,
    const float* __restrict__ bout, float* __restrict__ o2cls) {
  __shared__ f16 As[128 * 32];
  __shared__ f16 Bs[64 * 32];
  const int tid = threadIdx.x;
  const int lane = tid & 63;
  const int wave = tid >> 6;
  const int n0 = (int)blockIdx.x * 64;
  const int wm = (wave >> 1) * 64;
  const int wn = (wave & 1) * 32;
  const int fr = lane & 15;
  const int fq = lane >> 4;

  f32x4 acc[4][2];
#pragma unroll
  for (int i = 0; i < 4; i++)
#pragma unroll
    for (int j = 0; j < 2; j++) acc[i][j] = f32x4{0.f, 0.f, 0.f, 0.f};

  const int sr = lane >> 2;
  const int sc = (lane & 3) * 8;
  const f16* ag = O16 + (size_t)(wave * 32 + sr) * 384 + sc;
  const f16* bg = wout16 + (size_t)(n0 + wave * 16 + sr) * 384 + sc;
  const size_t rstep = (size_t)16 * 384;
  f16* la = As + wave * 32 * 32;
  f16* lb = Bs + wave * 16 * 32;

  for (int k0 = 0; k0 < 384; k0 += 32) {
    gload16(ag, la);  gload16(ag + rstep, la + 16 * 32);
    gload16(bg, lb);
    ag += 32; bg += 32;
    __syncthreads();
    f16x8 af[4], bf[2];
#pragma unroll
    for (int i = 0; i < 4; i++)
      af[i] = *(const f16x8*)&As[(wm + i * 16 + fr) * 32 + fq * 8];
#pragma unroll
    for (int j = 0; j < 2; j++)
      bf[j] = *(const f16x8*)&Bs[(wn + j * 16 + fr) * 32 + fq * 8];
#pragma unroll
    for (int i = 0; i < 4; i++)
#pragma unroll
      for (int j = 0; j < 2; j++)
        acc[i][j] = __builtin_amdgcn_mfma_f32_16x16x32_f16(af[i], bf[j], acc[i][j], 0, 0, 0);
    __syncthreads();
  }

#pragma unroll
  for (int i = 0; i < 4; i++)
#pragma unroll
    for (int j = 0; j < 2; j++)
#pragma unroll
      for (int rg = 0; rg < 4; rg++) {
        int gm = wm + i * 16 + fq * 4 + rg;
        int gn = n0 + wn + j * 16 + fr;
        o2cls[(size_t)gm * EMB + gn] = acc[i][j][rg] + bout[gn];
      }
}

// ---------------- fused LN (ln1 params) + router top-2 ----------------
__global__ __launch_bounds__(384) void ln_router_k(
    const float* __restrict__ o2cls, const float* __restrict__ g, const float* __restrict__ bb,
    const float* __restrict__ rw, const float* __restrict__ rb,
    f16* __restrict__ hcls16, float* __restrict__ maskw) {
  __shared__ float red[16];
  __shared__ float part[6][4];
  __shared__ float logits[4];
  int b = blockIdx.x, t = threadIdx.x;
  int lane = t & 63, wave = t >> 6;
  float v = o2cls[(size_t)b * EMB + t];
  float s = v, sq = v * v;
#pragma unroll
  for (int off = 32; off; off >>= 1) {
    s += __shfl_xor(s, off);
    sq += __shfl_xor(sq, off);
  }
  if (lane == 0) { red[wave] = s; red[8 + wave] = sq; }
  __syncthreads();
  float S = 0.f, SQ = 0.f;
#pragma unroll
  for (int i = 0; i < 6; i++) { S += red[i]; SQ += red[8 + i]; }
  float m = S * (1.f / 384.f);
  float rs = rsqrtf(SQ * (1.f / 384.f) - m * m + 1e-5f);
  float y = (v - m) * rs * g[t] + bb[t];
  hcls16[(size_t)b * EMB + t] = (f16)y;
  float p0 = y * rw[t];
  float p1 = y * rw[EMB + t];
  float p2 = y * rw[2 * EMB + t];
  float p3 = y * rw[3 * EMB + t];
#pragma unroll
  for (int off = 32; off; off >>= 1) {
    p0 += __shfl_xor(p0, off);
    p1 += __shfl_xor(p1, off);
    p2 += __shfl_xor(p2, off);
    p3 += __shfl_xor(p3, off);
  }
  if (lane == 0) { part[wave][0] = p0; part[wave][1] = p1; part[wave][2] = p2; part[wave][3] = p3; }
  __syncthreads();
  if (t < 4) {
    float a = rb[t];
#pragma unroll
    for (int i = 0; i < 6; i++) a += part[i][t];
    logits[t] = a;
  }
  __syncthreads();
  if (t == 0) {
    float l0 = logits[0], l1 = logits[1], l2 = logits[2], l3 = logits[3];
    int i1 = 0; float b1 = l0;
    if (l1 > b1) { b1 = l1; i1 = 1; }
    if (l2 > b1) { b1 = l2; i1 = 2; }
    if (l3 > b1) { b1 = l3; i1 = 3; }
    int i2 = -1; float b2 = 0.f;
    float lv[4] = {l0, l1, l2, l3};
#pragma unroll
    for (int i = 0; i < 4; i++) {
      if (i == i1) continue;
      if (i2 < 0 || lv[i] > b2) { i2 = i; b2 = lv[i]; }
    }
#pragma unroll
    for (int e = 0; e < 4; e++)
      maskw[(size_t)b * 4 + e] = (e == i1 || e == i2) ? 0.5f : 0.f;
  }
}

// ---------------- MoE GEMM1: hcls16[128x384] @ ew1t^T + GELU -> ehbuf f16 ---------
__global__ __launch_bounds__(256) void moe1_k(
    const f16* __restrict__ A, const f16* __restrict__ Bm,
    const float* __restrict__ bias, f16* __restrict__ outh) {
  __shared__ f16 As[128 * 32];
  __shared__ f16 Bs[64 * 32];
  const int K = EMB;
  const int tid = threadIdx.x;
  const int lane = tid & 63;
  const int wave = tid >> 6;
  const int e = (int)blockIdx.y;
  const int n0 = (int)blockIdx.x * 64;
  const int wm = (wave >> 1) * 64;
  const int wn = (wave & 1) * 32;
  const int fr = lane & 15;
  const int fq = lane >> 4;
  Bm += (size_t)e * HID * EMB;
  bias += (size_t)e * HID;

  f32x4 acc[4][2];
#pragma unroll
  for (int i = 0; i < 4; i++)
#pragma unroll
    for (int j = 0; j < 2; j++) acc[i][j] = f32x4{0.f, 0.f, 0.f, 0.f};

  const int sr = lane >> 2;
  const int sc = (lane & 3) * 8;
  const f16* ag = A + (size_t)(wave * 32 + sr) * K + sc;
  const f16* bg = Bm + (size_t)(n0 + wave * 16 + sr) * K + sc;
  const size_t rstep = (size_t)16 * K;
  f16* la = As + wave * 32 * 32;
  f16* lb = Bs + wave * 16 * 32;

  for (int k0 = 0; k0 < K; k0 += 32) {
    gload16(ag, la);  gload16(ag + rstep, la + 16 * 32);
    gload16(bg, lb);
    ag += 32; bg += 32;
    __syncthreads();
    f16x8 af[4], bf[2];
#pragma unroll
    for (int i = 0; i < 4; i++)
      af[i] = *(const f16x8*)&As[(wm + i * 16 + fr) * 32 + fq * 8];
#pragma unroll
    for (int j = 0; j < 2; j++)
      bf[j] = *(const f16x8*)&Bs[(wn + j * 16 + fr) * 32 + fq * 8];
#pragma unroll
    for (int i = 0; i < 4; i++)
#pragma unroll
      for (int j = 0; j < 2; j++)
        acc[i][j] = __builtin_amdgcn_mfma_f32_16x16x32_f16(af[i], bf[j], acc[i][j], 0, 0, 0);
    __syncthreads();
  }

#pragma unroll
  for (int i = 0; i < 4; i++)
#pragma unroll
    for (int j = 0; j < 2; j++)
#pragma unroll
      for (int rg = 0; rg < 4; rg++) {
        int gm = wm + i * 16 + fq * 4 + rg;
        int gn = n0 + wn + j * 16 + fr;
        float v = acc[i][j][rg] + bias[gn];
        float gl = 0.5f * v * (1.0f + erff(v * 0.70710678118654752f));
        outh[(size_t)e * 128 * HID + (size_t)gm * HID + gn] = (f16)gl;
      }
}

// ---------------- MoE GEMM2 split-K ----------------
__global__ __launch_bounds__(256) void moe2_k(
    const f16* __restrict__ EH, const f16* __restrict__ W2,
    float* __restrict__ part) {
  __shared__ f16 As[128 * 32];
  __shared__ f16 Bs[64 * 32];
  const int tid = threadIdx.x;
  const int lane = tid & 63;
  const int wave = tid >> 6;
  const int n0 = (int)blockIdx.x * 64;
  const int e = (int)blockIdx.y;
  const int kc = (int)blockIdx.z;
  const int wm = (wave >> 1) * 64;
  const int wn = (wave & 1) * 32;
  const int fr = lane & 15;
  const int fq = lane >> 4;
  const f16* A = EH + (size_t)e * 128 * HID + kc * 384;
  const f16* B = W2 + (size_t)e * EMB * HID + kc * 384;

  f32x4 acc[4][2];
#pragma unroll
  for (int i = 0; i < 4; i++)
#pragma unroll
    for (int j = 0; j < 2; j++) acc[i][j] = f32x4{0.f, 0.f, 0.f, 0.f};

  const int sr = lane >> 2;
  const int sc = (lane & 3) * 8;
  const f16* ag = A + (size_t)(wave * 32 + sr) * HID + sc;
  const f16* bg = B + (size_t)(n0 + wave * 16 + sr) * HID + sc;
  const size_t rstep = (size_t)16 * HID;
  f16* la = As + wave * 32 * 32;
  f16* lb = Bs + wave * 16 * 32;

  for (int k0 = 0; k0 < 384; k0 += 32) {
    gload16(ag, la);  gload16(ag + rstep, la + 16 * 32);
    gload16(bg, lb);
    ag += 32; bg += 32;
    __syncthreads();
    f16x8 af[4], bf[2];
#pragma unroll
    for (int i = 0; i < 4; i++)
      af[i] = *(const f16x8*)&As[(wm + i * 16 + fr) * 32 + fq * 8];
#pragma unroll
    for (int j = 0; j < 2; j++)
      bf[j] = *(const f16x8*)&Bs[(wn + j * 16 + fr) * 32 + fq * 8];
#pragma unroll
    for (int i = 0; i < 4; i++)
#pragma unroll
      for (int j = 0; j < 2; j++)
        acc[i][j] = __builtin_amdgcn_mfma_f32_16x16x32_f16(af[i], bf[j], acc[i][j], 0, 0, 0);
    __syncthreads();
  }

#pragma unroll
  for (int i = 0; i < 4; i++)
#pragma unroll
    for (int j = 0; j < 2; j++)
#pragma unroll
      for (int rg = 0; rg < 4; rg++) {
        int gm = wm + i * 16 + fq * 4 + rg;
        int gn = n0 + wn + j * 16 + fr;
        part[(((size_t)kc * 4 + e) * 128 + gm) * EMB + gn] = acc[i][j][rg];
      }
}

// ---------------- combine split-K + experts + LN2 -> f16 ----------------
__global__ __launch_bounds__(384) void combine_ln2_k(
    const float* __restrict__ part, const float* __restrict__ eb2,
    const float* __restrict__ maskw,
    const float* __restrict__ g, const float* __restrict__ bb,
    f16* __restrict__ hfin) {
  __shared__ float red[16];
  int b = blockIdx.x, t = threadIdx.x;
  int lane = t & 63, wave = t >> 6;
  float v = 0.f;
#pragma unroll
  for (int e = 0; e < 4; e++) {
    float s = eb2[e * EMB + t];
#pragma unroll
    for (int kc = 0; kc < 4; kc++)
      s += part[(((size_t)kc * 4 + e) * 128 + b) * EMB + t];
    v += maskw[b * 4 + e] * s;
  }
  float s = v, sq = v * v;
#pragma unroll
  for (int off = 32; off; off >>= 1) {
    s += __shfl_xor(s, off);
    sq += __shfl_xor(sq, off);
  }
  if (lane == 0) { red[wave] = s; red[8 + wave] = sq; }
  __syncthreads();
  float S = 0.f, SQ = 0.f;
#pragma unroll
  for (int i = 0; i < 6; i++) { S += red[i]; SQ += red[8 + i]; }
  float m = S * (1.f / 384.f);
  float rs = rsqrtf(SQ * (1.f / 384.f) - m * m + 1e-5f);
  hfin[(size_t)b * EMB + t] = (f16)((v - m) * rs * g[t] + bb[t]);
}

// ---------------- head GEMM ----------------
__global__ __launch_bounds__(256) void head_gemm_k(
    const f16* __restrict__ A, const f16* __restrict__ B,
    const float* __restrict__ hb, float* __restrict__ outp) {
  __shared__ f16 As[128 * 32];
  __shared__ f16 Bs[128 * 32];
  const int K = 384;
  const int tid = threadIdx.x;
  const int lane = tid & 63;
  const int wave = tid >> 6;
  const int n0 = (int)blockIdx.x * 128;
  const int wm = (wave >> 1) * 64;
  const int wn = (wave & 1) * 64;
  const int fr = lane & 15;
  const int fq = lane >> 4;

  f32x4 acc[4][4];
#pragma unroll
  for (int i = 0; i < 4; i++)
#pragma unroll
    for (int j = 0; j < 4; j++) acc[i][j] = f32x4{0.f, 0.f, 0.f, 0.f};

  const int srow = wave * 32 + (lane >> 2);
  const int scol = (lane & 3) * 8;
  const f16* ag = A + (size_t)srow * K + scol;
  const f16* bg = B + (size_t)(n0 + srow) * K + scol;
  const size_t rstep = (size_t)16 * K;
  f16* la = As + wave * 32 * 32;
  f16* lb = Bs + wave * 32 * 32;

  for (int k0 = 0; k0 < K; k0 += 32) {
    gload16(ag, la);          gload16(ag + rstep, la + 16 * 32);
    gload16(bg, lb);          gload16(bg + rstep, lb + 16 * 32);
    ag += 32; bg += 32;
    __syncthreads();
    f16x8 af[4], bf[4];
#pragma unroll
    for (int i = 0; i < 4; i++) {
      af[i] = *(const f16x8*)&As[(wm + i * 16 + fr) * 32 + fq * 8];
      bf[i] = *(const f16x8*)&Bs[(wn + i * 16 + fr) * 32 + fq * 8];
    }
#pragma unroll
    for (int i = 0; i < 4; i++)
#pragma unroll
      for (int j = 0; j < 4; j++)
        acc[i][j] = __builtin_amdgcn_mfma_f32_16x16x32_f16(af[i], bf[j], acc[i][j], 0, 0, 0);
    __syncthreads();
  }

#pragma unroll
  for (int i = 0; i < 4; i++)
#pragma unroll
    for (int j = 0; j < 4; j++)
#pragma unroll
      for (int rg = 0; rg < 4; rg++) {
        int gm = wm + i * 16 + fq * 4 + rg;
        int gn = n0 + wn + j * 16 + fr;
        if (gn < 1000)
          outp[(size_t)gm * 1000 + gn] = acc[i][j][rg] + hb[gn];
      }
}

// ---------------- host ----------------
extern "C" void kernel_launch(void* const* d_in, const int* in_sizes, int n_in,
                              void* d_out, int out_size, void* d_ws, size_t ws_size,
                              hipStream_t stream) {
  const float* x      = (const float*)d_in[0];
  const float* conv_w = (const float*)d_in[1];
  const float* conv_b = (const float*)d_in[2];
  const float* cls_t  = (const float*)d_in[3];
  const float* pos    = (const float*)d_in[4];
  const float* ln1_g  = (const float*)d_in[5];
  const float* ln1_b  = (const float*)d_in[6];
  const float* inp_w  = (const float*)d_in[7];
  const float* inp_b  = (const float*)d_in[8];
  const float* outp_w = (const float*)d_in[9];
  const float* outp_b = (const float*)d_in[10];
  const float* rt_w   = (const float*)d_in[11];
  const float* rt_b   = (const float*)d_in[12];
  const float* ew1    = (const float*)d_in[13];
  const float* eb1    = (const float*)d_in[14];
  const float* ew2    = (const float*)d_in[15];
  const float* eb2    = (const float*)d_in[16];
  const float* ln2_g  = (const float*)d_in[17];
  const float* ln2_b  = (const float*)d_in[18];
  const float* head_w = (const float*)d_in[19];
  const float* head_b = (const float*)d_in[20];
  float* out = (float*)d_out;
  char* w = (char*)d_ws;
  if (ws_size < WS_NEEDED) return;

  f16* convw    = (f16*)(w + OFF_CONVW);
  f16* ew1t     = (f16*)(w + OFF_EW1T);
  f16* ew2t     = (f16*)(w + OFF_EW2T);
  f16* headw16  = (f16*)(w + OFF_HEADW16);
  f16* xcls16   = (f16*)(w + OFF_XCLS16);
  float* qvec   = (float*)(w + OFF_Q);
  f16* hcls16   = (f16*)(w + OFF_HCLS16);
  float* maskw  = (float*)(w + OFF_MASKW);
  f16* ehbuf    = (f16*)(w + OFF_EH);
  float* epart  = (float*)(w + OFF_EPART);
  f16* hfin     = (f16*)(w + OFF_HFIN);
  f16* xh       = (f16*)(w + OFF_XH);
  float* Rg     = (float*)(w + OFF_R);
  float* Cg     = (float*)(w + OFF_CVEC);
  f16* u16      = (f16*)(w + OFF_U16);
  f16* o16      = (f16*)(w + OFF_O16);
  f16* wv16     = (f16*)(w + OFF_WV16);
  f16* wout16   = (f16*)(w + OFF_WOUT16);
  float* o2cls  = (float*)(w + OFF_O2CLS);

  // ---- weight prep ----
  prep_cast_k<<<dim3(3840), 256, 0, stream>>>(
      conv_w, head_w, inp_w, outp_w, convw, headw16, wv16, wout16);
  transpose_cast_k<<<dim3(48, 12, 4), 256, 0, stream>>>(ew1, ew1t, 384, 1536);
  transpose_cast_k<<<dim3(12, 48, 4), 256, 0, stream>>>(ew2, ew2t, 1536, 384);

  // ---- cls precompute + r_h precompute + broadcast ----
  clsprep_k<<<dim3(1), 384, 0, stream>>>(cls_t, pos, ln1_g, ln1_b, inp_w, inp_b, xcls16, qvec);
  rprep_k<<<dim3(6), 384, 0, stream>>>(inp_w, inp_b, qvec, Rg, Cg);
  bcast_cls_k<<<dim3(128), 384, 0, stream>>>(xcls16, xh);

  // ---- fused implicit-im2col embed GEMM + LN1 -> xh patch rows ----
  embed_ln_k<<<dim3(392), 1024, 0, stream>>>(x, convw, conv_b, pos, ln1_g, ln1_b, xh);

  // ---- attention tail: scores+softmax+u -> U16; then GEMM projections ----
  score_sm_u_k<<<dim3(128), 768, 0, stream>>>(xh, Rg, Cg, u16);
  vproj_k<<<dim3(6), 256, 0, stream>>>(u16, wv16, inp_b, o16);
  oproj_k<<<dim3(6), 256, 0, stream>>>(o16, wout16, outp_b, o2cls);
  ln_router_k<<<dim3(128), 384, 0, stream>>>(
      o2cls, ln1_g, ln1_b, rt_w, rt_b, hcls16, maskw);

  // ---- MoE ----
  moe1_k<<<dim3(24, 4), 256, 0, stream>>>(hcls16, ew1t, eb1, ehbuf);
  moe2_k<<<dim3(6, 4, 4), 256, 0, stream>>>(ehbuf, ew2t, epart);
  combine_ln2_k<<<dim3(128), 384, 0, stream>>>(epart, eb2, maskw, ln2_g, ln2_b, hfin);

  // ---- head ----
  head_gemm_k<<<dim3(8), 256, 0, stream>>>(hfin, headw16, head_b, out);
  (void)in_sizes; (void)n_in; (void)out_size;
}

// Round 5
// 423.618 us; speedup vs baseline: 1.0536x; 1.0276x over previous
//
#include <hip/hip_runtime.h>
#include <cstdint>
#include <cstddef>

typedef _Float16 f16;
typedef _Float16 f16x8 __attribute__((ext_vector_type(8)));
typedef float    f32x4 __attribute__((ext_vector_type(4)));

// ---------------- problem constants ----------------
constexpr int NTOKC  = 197;
constexpr int TTOK   = 128 * 197;         // 25216
constexpr int EMB    = 384;
constexpr int HID    = 1536;

// ---------------- workspace layout (bytes) ----------------
constexpr size_t OFF_CONVW   = 0;                        // 384*768 f16
constexpr size_t OFF_EW1T    = 1179648;                  // 4*1536*384 f16
constexpr size_t OFF_EW2T    = 5898240;                  // 4*384*1536 f16
constexpr size_t OFF_HEADW16 = 10616832;                 // 1024*384 f16
constexpr size_t OFF_XCLS16  = 11403264;                 // 384 f16
constexpr size_t OFF_Q       = 11404800;                 // 384 f32
constexpr size_t OFF_HCLS16  = 11799552;                 // 128*384 f16
constexpr size_t OFF_MASKW   = 11897856;                 // 128*4 f32
constexpr size_t OFF_EH      = 11899904;                 // 4*128*1536 f16
constexpr size_t OFF_EPART   = 13472768;                 // 4kc*4e*128*384 f32
constexpr size_t OFF_HFIN    = 16618496;                 // 128*384 f16
constexpr size_t OFF_XH      = 16716800;                 // TTOK*384 f16
constexpr size_t OFF_R       = 36082688;                 // 6*384 f32
constexpr size_t OFF_CVEC    = 36094976;                 // 6 f32
constexpr size_t OFF_U16     = 36099072;                 // 128*2304 f16
constexpr size_t OFF_O16     = 36688896;                 // 128*384 f16
constexpr size_t OFF_WV16    = 36787200;                 // 384*384 f16
constexpr size_t OFF_WOUT16  = 37082112;                 // 384*384 f16
constexpr size_t OFF_O2CLS   = 37377024;                 // 128*384 f32
constexpr size_t OFF_P32     = 37573632;                 // 128*6*208 f32
constexpr size_t WS_NEEDED   = 38212608;                 // ~38.2 MB

// ---------------- global_load_lds helper ----------------
__device__ __forceinline__ void gload16(const void* g, void* l) {
  __builtin_amdgcn_global_load_lds(
      (__attribute__((address_space(1))) void*)(void*)g,
      (__attribute__((address_space(3))) void*)l, 16, 0, 0);
}

// ---------------- prep: all weight casts in one launch ------------
__global__ __launch_bounds__(256) void prep_cast_k(
    const float* __restrict__ conv_w, const float* __restrict__ head_w,
    const float* __restrict__ inp_w, const float* __restrict__ outp_w,
    f16* __restrict__ convw, f16* __restrict__ headw16,
    f16* __restrict__ wv16, f16* __restrict__ wout16) {
  int i = blockIdx.x * 256 + threadIdx.x;
  if (i < 294912) convw[i] = (f16)conv_w[i];
  int j = i - 294912;
  if (j >= 0 && j < 393216) {
    int row = j / 384;
    headw16[j] = (row < 1000) ? (f16)head_w[j] : (f16)0.f;
  }
  int k = i - 688128;
  if (k >= 0 && k < 147456) wv16[k] = (f16)inp_w[294912 + k];
  int l = i - 835584;
  if (l >= 0 && l < 147456) wout16[l] = (f16)outp_w[l];
}

__global__ __launch_bounds__(256) void transpose_cast_k(
    const float* __restrict__ in, f16* __restrict__ outp, int R, int C) {
  __shared__ float tile[32][33];
  int e = blockIdx.z;
  const float* pin = in + (size_t)e * R * C;
  f16* pout = outp + (size_t)e * R * C;
  int c0 = blockIdx.x * 32, r0 = blockIdx.y * 32;
  int tx = threadIdx.x & 31, ty = threadIdx.x >> 5;
#pragma unroll
  for (int i = 0; i < 4; i++)
    tile[ty + 8 * i][tx] = pin[(size_t)(r0 + ty + 8 * i) * C + c0 + tx];
  __syncthreads();
#pragma unroll
  for (int i = 0; i < 4; i++)
    pout[(size_t)(c0 + ty + 8 * i) * R + r0 + tx] = (f16)tile[tx][ty + 8 * i];
}

// ---------------- cls precompute: xcls = LN(cls+pos[0]); q = Wq.xcls + bq ----------
__global__ __launch_bounds__(384) void clsprep_k(
    const float* __restrict__ cls, const float* __restrict__ posw,
    const float* __restrict__ g, const float* __restrict__ bb,
    const float* __restrict__ Wq, const float* __restrict__ bq,
    f16* __restrict__ xcls16, float* __restrict__ qout) {
  __shared__ float xs[EMB];
  __shared__ float red[16];
  int t = threadIdx.x, lane = t & 63, wave = t >> 6;
  float v = cls[t] + posw[t];
  float s = v, sq = v * v;
#pragma unroll
  for (int off = 32; off; off >>= 1) {
    s += __shfl_xor(s, off);
    sq += __shfl_xor(sq, off);
  }
  if (lane == 0) { red[wave] = s; red[8 + wave] = sq; }
  __syncthreads();
  float S = 0.f, SQ = 0.f;
#pragma unroll
  for (int i = 0; i < 6; i++) { S += red[i]; SQ += red[8 + i]; }
  float m = S * (1.f / 384.f);
  float rs = rsqrtf(SQ * (1.f / 384.f) - m * m + 1e-5f);
  float y = (v - m) * rs * g[t] + bb[t];
  xs[t] = y;
  xcls16[t] = (f16)y;
  __syncthreads();
  const float4* w4 = (const float4*)(Wq + (size_t)t * EMB);
  const float4* s4 = (const float4*)xs;
  float a = bq[t];
#pragma unroll 8
  for (int i = 0; i < 96; i++) {
    float4 xx = s4[i], ww = w4[i];
    a += xx.x * ww.x + xx.y * ww.y + xx.z * ww.z + xx.w * ww.w;
  }
  qout[t] = a;
}

// ---------------- R precompute: r_h = Wk_h^T q_h, c_h = q_h . bk_h -------------
__global__ __launch_bounds__(384) void rprep_k(
    const float* __restrict__ inp_w, const float* __restrict__ inp_b,
    const float* __restrict__ qv, float* __restrict__ Rg, float* __restrict__ Cg) {
  int h = blockIdx.x, t = threadIdx.x;
  __shared__ float qs[64];
  __shared__ float cred[64];
  if (t < 64) {
    float q = qv[h * 64 + t];
    qs[t] = q;
    cred[t] = q * inp_b[384 + h * 64 + t];
  }
  __syncthreads();
  const float* wp = inp_w + ((size_t)(384 + h * 64)) * 384 + t;
  float a = 0.f;
#pragma unroll 8
  for (int d = 0; d < 64; d++) a += wp[(size_t)d * 384] * qs[d];
  Rg[h * 384 + t] = a;
  if (t == 0) {
    float c = 0.f;
    for (int d = 0; d < 64; d++) c += cred[d];
    Cg[h] = c;
  }
}

__global__ __launch_bounds__(384) void bcast_cls_k(
    const f16* __restrict__ xcls16, f16* __restrict__ xh) {
  int b = blockIdx.x, t = threadIdx.x;
  xh[(size_t)b * NTOKC * EMB + t] = xcls16[t];
}

// ---------------- fused IMPLICIT-im2col patch-embed GEMM + bias + pos + LN1 ------
__global__ __launch_bounds__(1024) void embed_ln_k(
    const float* __restrict__ img, const f16* __restrict__ B,
    const float* __restrict__ bias, const float* __restrict__ posw,
    const float* __restrict__ g, const float* __restrict__ bb,
    f16* __restrict__ xh) {
  __shared__ f16 As[64 * 32];       // 4 KB
  __shared__ f16 Bs[384 * 32];      // 24 KB
  __shared__ float prm[3 * 384];    // bias | gamma | beta
  __shared__ float psum[64 * 4];
  __shared__ float pqsum[64 * 4];
  const int K = 768;
  const int tid = threadIdx.x;
  const int lane = tid & 63;
  const int wave = tid >> 6;        // 0..15
  const int rowgrp = wave & 3;
  const int colgrp = wave >> 2;
  const int m0 = (int)blockIdx.x * 64;
  const int fr = lane & 15;
  const int fq = lane >> 4;

  for (int i = tid; i < 384; i += 1024) {
    prm[i] = bias[i]; prm[384 + i] = g[i]; prm[768 + i] = bb[i];
  }

  f32x4 acc[6];
#pragma unroll
  for (int j = 0; j < 6; j++) acc[j] = f32x4{0.f, 0.f, 0.f, 0.f};

  const int sr = lane >> 2, sc = (lane & 3) * 8;
  const float* abase = nullptr;
  f16* adst = nullptr;
  if (wave < 4) {
    int row = m0 + wave * 16 + sr;          // patch index 0..25087
    int bimg = row / 196;
    int pp = row - bimg * 196;
    int py = pp / 14, px = pp - py * 14;
    int kx0 = sc & 15;                      // 0 or 8
    abase = img + ((size_t)(bimg * 3) * 224 + py * 16) * 224 + px * 16 + kx0;
    adst = As + (wave * 16 + sr) * 32 + sc;
  }
  const f16* gb0 = nullptr;
  f16* lb0 = nullptr;
  if (wave >= 4) {
    int brow = (wave - 4) * 32;
    gb0 = B + (size_t)(brow + sr) * K + sc;
    lb0 = Bs + brow * 32;
  }

  for (int k0 = 0; k0 < K; k0 += 32) {
    if (wave < 4) {
      int col = k0 + sc;
      int c = col >> 8;
      int ky = (col >> 4) & 15;
      const float* src = abase + c * 50176 + ky * 224;
      float4 p0 = *(const float4*)src;
      float4 p1 = *(const float4*)(src + 4);
      f16x8 hv;
      hv[0] = (f16)p0.x; hv[1] = (f16)p0.y; hv[2] = (f16)p0.z; hv[3] = (f16)p0.w;
      hv[4] = (f16)p1.x; hv[5] = (f16)p1.y; hv[6] = (f16)p1.z; hv[7] = (f16)p1.w;
      *(f16x8*)adst = hv;
    } else {
      gload16(gb0, lb0); gload16(gb0 + (size_t)16 * K, lb0 + 16 * 32);
      gb0 += 32;
    }
    __syncthreads();
    f16x8 af = *(const f16x8*)&As[(rowgrp * 16 + fr) * 32 + fq * 8];
#pragma unroll
    for (int j = 0; j < 6; j++) {
      f16x8 bf = *(const f16x8*)&Bs[(colgrp * 96 + j * 16 + fr) * 32 + fq * 8];
      acc[j] = __builtin_amdgcn_mfma_f32_16x16x32_f16(af, bf, acc[j], 0, 0, 0);
    }
    __syncthreads();
  }

  float v[4][6];
#pragma unroll
  for (int rg = 0; rg < 4; rg++) {
    int lrow = rowgrp * 16 + fq * 4 + rg;
    int row = m0 + lrow;
    int bimg = row / 196;
    int pp = row - bimg * 196;
    const float* prow = posw + (size_t)(pp + 1) * EMB;
    float s = 0.f, sq = 0.f;
#pragma unroll
    for (int j = 0; j < 6; j++) {
      int col = colgrp * 96 + j * 16 + fr;
      float t = acc[j][rg] + prm[col] + prow[col];
      v[rg][j] = t;
      s += t; sq += t * t;
    }
#pragma unroll
    for (int off = 1; off < 16; off <<= 1) {
      s += __shfl_xor(s, off);
      sq += __shfl_xor(sq, off);
    }
    if (fr == 0) { psum[lrow * 4 + colgrp] = s; pqsum[lrow * 4 + colgrp] = sq; }
  }
  __syncthreads();

#pragma unroll
  for (int rg = 0; rg < 4; rg++) {
    int lrow = rowgrp * 16 + fq * 4 + rg;
    float S = psum[lrow * 4] + psum[lrow * 4 + 1] + psum[lrow * 4 + 2] + psum[lrow * 4 + 3];
    float SQ = pqsum[lrow * 4] + pqsum[lrow * 4 + 1] + pqsum[lrow * 4 + 2] + pqsum[lrow * 4 + 3];
    float m = S * (1.f / 384.f);
    float rs = rsqrtf(SQ * (1.f / 384.f) - m * m + 1e-5f);
    int row = m0 + lrow;
    int bimg = row / 196;
    int pp = row - bimg * 196;
    f16* orow = xh + ((size_t)bimg * NTOKC + pp + 1) * EMB;
#pragma unroll
    for (int j = 0; j < 6; j++) {
      int col = colgrp * 96 + j * 16 + fr;
      orow[col] = (f16)((v[rg][j] - m) * rs * prm[384 + col] + prm[768 + col]);
    }
  }
}

// ---------------- scores + softmax -> normalized P32[b][6][208] ----------------
// grid 128 x 768. Rs padded (stride 104 per qtr => banks 0/8/16/24, conflict-free).
__global__ __launch_bounds__(768) void score_sm_k(
    const f16* __restrict__ xh, const float* __restrict__ Rg,
    const float* __restrict__ Cg, float* __restrict__ P32) {
  __shared__ float Rs[6 * 416];       // h*416 + q*104 + r
  __shared__ float cs[6];
  __shared__ float ps[6][208];        // raw scores
  const int b = blockIdx.x, tid = threadIdx.x;
  const int wave = tid >> 6, lane = tid & 63;

  for (int i = tid; i < 2304; i += 768) {
    int h = i / 384, c = i - h * 384;
    int q = c / 96, r = c - q * 96;
    Rs[h * 416 + q * 104 + r] = Rg[i];
  }
  if (tid < 6) cs[tid] = Cg[tid];
  __syncthreads();

  // scores S[h][t] = xh[b,t,:] . r_h + c_h   (4 threads per token)
  {
    const int grp = tid >> 2;
    const int qtr = tid & 3;
    for (int t = grp; t < 197; t += 192) {
      const f16* xp = xh + ((size_t)b * NTOKC + t) * EMB + qtr * 96;
      float a[6];
#pragma unroll
      for (int h = 0; h < 6; h++) a[h] = 0.f;
#pragma unroll
      for (int i = 0; i < 12; i++) {
        f16x8 v = *(const f16x8*)(xp + i * 8);
        float xf[8];
#pragma unroll
        for (int j = 0; j < 8; j++) xf[j] = (float)v[j];
#pragma unroll
        for (int h = 0; h < 6; h++) {
          const float* rp = &Rs[h * 416 + qtr * 104 + i * 8];
          float aa = a[h];
#pragma unroll
          for (int j = 0; j < 8; j++) aa += xf[j] * rp[j];
          a[h] = aa;
        }
      }
#pragma unroll
      for (int h = 0; h < 6; h++) {
        a[h] += __shfl_xor(a[h], 1);
        a[h] += __shfl_xor(a[h], 2);
      }
      if (qtr < 4) {
        ps[qtr][t] = a[qtr] + cs[qtr];
        if (qtr < 2) ps[qtr + 4][t] = a[qtr + 4] + cs[qtr + 4];
      }
    }
  }
  __syncthreads();

  // per-head softmax over 197 keys (waves 0..5) -> normalized P32, pad 0
  if (wave < 6) {
    float z[4], pk[4];
#pragma unroll
    for (int k = 0; k < 4; k++) {
      int t = lane + 64 * k;
      z[k] = (t < 197) ? ps[wave][t] * 0.125f : -1e30f;
      pk[k] = 0.f;
    }
    float mx = fmaxf(fmaxf(z[0], z[1]), fmaxf(z[2], z[3]));
#pragma unroll
    for (int off = 32; off; off >>= 1) mx = fmaxf(mx, __shfl_xor(mx, off));
    float sum = 0.f;
#pragma unroll
    for (int k = 0; k < 4; k++) {
      int t = lane + 64 * k;
      if (t < 197) {
        pk[k] = __expf(z[k] - mx);
        sum += pk[k];
      }
    }
#pragma unroll
    for (int off = 32; off; off >>= 1) sum += __shfl_xor(sum, off);
    float si = 1.f / sum;
#pragma unroll
    for (int k = 0; k < 4; k++) {
      int t = lane + 64 * k;
      if (t < 208) P32[(size_t)b * 1248 + wave * 208 + t] = pk[k] * si;
    }
  }
}

// ---------------- u[b][h][col] = sum_t P[b][h][t] * xh[b][t][col] -> U16 ---------
// grid (3 col-tiles of 128, 128 b) x 256 thr. 64 col-pairs x 4 token-quarters.
__global__ __launch_bounds__(256) void u_gemv_k(
    const float* __restrict__ P32, const f16* __restrict__ xh,
    f16* __restrict__ U16) {
  __shared__ float pf[6 * 208];        // 4992 B
  __shared__ float part[4][64][12];    // 12 KB
  const int cq = (int)blockIdx.x;      // 0..2
  const int b  = (int)blockIdx.y;
  const int tid = threadIdx.x;
  for (int i = tid; i < 1248; i += 256) pf[i] = P32[(size_t)b * 1248 + i];
  __syncthreads();
  const int cp = tid & 63;
  const int tq = tid >> 6;
  const int col0 = cq * 128 + cp * 2;
  const int t0 = 49 * tq;
  const int t1 = (tq == 3) ? 197 : t0 + 49;
  float acc[12];
#pragma unroll
  for (int r = 0; r < 12; r++) acc[r] = 0.f;
  const f16* xp = xh + ((size_t)b * NTOKC + t0) * EMB + col0;
#pragma unroll 2
  for (int t = t0; t < t1; t++) {
    float x0 = (float)xp[0];
    float x1 = (float)xp[1];
    xp += EMB;
#pragma unroll
    for (int h = 0; h < 6; h++) {
      float p = pf[h * 208 + t];
      acc[h * 2]     += p * x0;
      acc[h * 2 + 1] += p * x1;
    }
  }
#pragma unroll
  for (int r = 0; r < 12; r++) part[tq][cp][r] = acc[r];
  __syncthreads();
#pragma unroll
  for (int k = 0; k < 3; k++) {
    int idx = tid + k * 256;            // 0..767
    int cp2 = idx / 12, slot = idx - cp2 * 12;
    int h = slot >> 1, c01 = slot & 1;
    float u = part[0][cp2][slot] + part[1][cp2][slot] +
              part[2][cp2][slot] + part[3][cp2][slot];
    U16[(size_t)b * 2304 + h * 384 + cq * 128 + cp2 * 2 + c01] = (f16)u;
  }
}

// ---------------- V-projection GEMM: o[b][h*64+n] = Wv_h[n,:].u[b][h] + bv ------
__global__ __launch_bounds__(256) void vproj_k(
    const f16* __restrict__ U16, const f16* __restrict__ wv16,
    const float* __restrict__ inp_b, f16* __restrict__ O16) {
  __shared__ f16 As[128 * 32];
  __shared__ f16 Bs[64 * 32];
  const int tid = threadIdx.x;
  const int lane = tid & 63;
  const int wave = tid >> 6;
  const int h = (int)blockIdx.x;
  const int wm = (wave >> 1) * 64;
  const int wn = (wave & 1) * 32;
  const int fr = lane & 15;
  const int fq = lane >> 4;
  const float* bv = inp_b + 768 + h * 64;

  f32x4 acc[4][2];
#pragma unroll
  for (int i = 0; i < 4; i++)
#pragma unroll
    for (int j = 0; j < 2; j++) acc[i][j] = f32x4{0.f, 0.f, 0.f, 0.f};

  const int sr = lane >> 2;
  const int sc = (lane & 3) * 8;
  const f16* ag = U16 + (size_t)(wave * 32 + sr) * 2304 + h * 384 + sc;
  const f16* bg = wv16 + (size_t)(h * 64 + wave * 16 + sr) * 384 + sc;
  const size_t rstepA = (size_t)16 * 2304;
  f16* la = As + wave * 32 * 32;
  f16* lb = Bs + wave * 16 * 32;

  for (int k0 = 0; k0 < 384; k0 += 32) {
    gload16(ag, la);  gload16(ag + rstepA, la + 16 * 32);
    gload16(bg, lb);
    ag += 32; bg += 32;
    __syncthreads();
    f16x8 af[4], bf[2];
#pragma unroll
    for (int i = 0; i < 4; i++)
      af[i] = *(const f16x8*)&As[(wm + i * 16 + fr) * 32 + fq * 8];
#pragma unroll
    for (int j = 0; j < 2; j++)
      bf[j] = *(const f16x8*)&Bs[(wn + j * 16 + fr) * 32 + fq * 8];
#pragma unroll
    for (int i = 0; i < 4; i++)
#pragma unroll
      for (int j = 0; j < 2; j++)
        acc[i][j] = __builtin_amdgcn_mfma_f32_16x16x32_f16(af[i], bf[j], acc[i][j], 0, 0, 0);
    __syncthreads();
  }

#pragma unroll
  for (int i = 0; i < 4; i++)
#pragma unroll
    for (int j = 0; j < 2; j++)
#pragma unroll
      for (int rg = 0; rg < 4; rg++) {
        int gm = wm + i * 16 + fq * 4 + rg;
        int gn = wn + j * 16 + fr;
        O16[(size_t)gm * EMB + h * 64 + gn] = (f16)(acc[i][j][rg] + bv[gn]);
      }
}

// ---------------- out-projection GEMM: o2 = Wout.o + bout (f32 out) -------------
__global__ __launch_bounds__(256) void oproj_k(
    const f16* __restrict__ O16, const f16* __restrict__ wout16,
    const float* __restrict__ bout, float* __restrict__ o2cls) {
  __shared__ f16 As[128 * 32];
  __shared__ f16 Bs[64 * 32];
  const int tid = threadIdx.x;
  const int lane = tid & 63;
  const int wave = tid >> 6;
  const int n0 = (int)blockIdx.x * 64;
  const int wm = (wave >> 1) * 64;
  const int wn = (wave & 1) * 32;
  const int fr = lane & 15;
  const int fq = lane >> 4;

  f32x4 acc[4][2];
#pragma unroll
  for (int i = 0; i < 4; i++)
#pragma unroll
    for (int j = 0; j < 2; j++) acc[i][j] = f32x4{0.f, 0.f, 0.f, 0.f};

  const int sr = lane >> 2;
  const int sc = (lane & 3) * 8;
  const f16* ag = O16 + (size_t)(wave * 32 + sr) * 384 + sc;
  const f16* bg = wout16 + (size_t)(n0 + wave * 16 + sr) * 384 + sc;
  const size_t rstep = (size_t)16 * 384;
  f16* la = As + wave * 32 * 32;
  f16* lb = Bs + wave * 16 * 32;

  for (int k0 = 0; k0 < 384; k0 += 32) {
    gload16(ag, la);  gload16(ag + rstep, la + 16 * 32);
    gload16(bg, lb);
    ag += 32; bg += 32;
    __syncthreads();
    f16x8 af[4], bf[2];
#pragma unroll
    for (int i = 0; i < 4; i++)
      af[i] = *(const f16x8*)&As[(wm + i * 16 + fr) * 32 + fq * 8];
#pragma unroll
    for (int j = 0; j < 2; j++)
      bf[j] = *(const f16x8*)&Bs[(wn + j * 16 + fr) * 32 + fq * 8];
#pragma unroll
    for (int i = 0; i < 4; i++)
#pragma unroll
      for (int j = 0; j < 2; j++)
        acc[i][j] = __builtin_amdgcn_mfma_f32_16x16x32_f16(af[i], bf[j], acc[i][j], 0, 0, 0);
    __syncthreads();
  }

#pragma unroll
  for (int i = 0; i < 4; i++)
#pragma unroll
    for (int j = 0; j < 2; j++)
#pragma unroll
      for (int rg = 0; rg < 4; rg++) {
        int gm = wm + i * 16 + fq * 4 + rg;
        int gn = n0 + wn + j * 16 + fr;
        o2cls[(size_t)gm * EMB + gn] = acc[i][j][rg] + bout[gn];
      }
}

// ---------------- fused LN (ln1 params) + router top-2 ----------------
__global__ __launch_bounds__(384) void ln_router_k(
    const float* __restrict__ o2cls, const float* __restrict__ g, const float* __restrict__ bb,
    const float* __restrict__ rw, const float* __restrict__ rb,
    f16* __restrict__ hcls16, float* __restrict__ maskw) {
  __shared__ float red[16];
  __shared__ float part[6][4];
  __shared__ float logits[4];
  int b = blockIdx.x, t = threadIdx.x;
  int lane = t & 63, wave = t >> 6;
  float v = o2cls[(size_t)b * EMB + t];
  float s = v, sq = v * v;
#pragma unroll
  for (int off = 32; off; off >>= 1) {
    s += __shfl_xor(s, off);
    sq += __shfl_xor(sq, off);
  }
  if (lane == 0) { red[wave] = s; red[8 + wave] = sq; }
  __syncthreads();
  float S = 0.f, SQ = 0.f;
#pragma unroll
  for (int i = 0; i < 6; i++) { S += red[i]; SQ += red[8 + i]; }
  float m = S * (1.f / 384.f);
  float rs = rsqrtf(SQ * (1.f / 384.f) - m * m + 1e-5f);
  float y = (v - m) * rs * g[t] + bb[t];
  hcls16[(size_t)b * EMB + t] = (f16)y;
  float p0 = y * rw[t];
  float p1 = y * rw[EMB + t];
  float p2 = y * rw[2 * EMB + t];
  float p3 = y * rw[3 * EMB + t];
#pragma unroll
  for (int off = 32; off; off >>= 1) {
    p0 += __shfl_xor(p0, off);
    p1 += __shfl_xor(p1, off);
    p2 += __shfl_xor(p2, off);
    p3 += __shfl_xor(p3, off);
  }
  if (lane == 0) { part[wave][0] = p0; part[wave][1] = p1; part[wave][2] = p2; part[wave][3] = p3; }
  __syncthreads();
  if (t < 4) {
    float a = rb[t];
#pragma unroll
    for (int i = 0; i < 6; i++) a += part[i][t];
    logits[t] = a;
  }
  __syncthreads();
  if (t == 0) {
    float l0 = logits[0], l1 = logits[1], l2 = logits[2], l3 = logits[3];
    int i1 = 0; float b1 = l0;
    if (l1 > b1) { b1 = l1; i1 = 1; }
    if (l2 > b1) { b1 = l2; i1 = 2; }
    if (l3 > b1) { b1 = l3; i1 = 3; }
    int i2 = -1; float b2 = 0.f;
    float lv[4] = {l0, l1, l2, l3};
#pragma unroll
    for (int i = 0; i < 4; i++) {
      if (i == i1) continue;
      if (i2 < 0 || lv[i] > b2) { i2 = i; b2 = lv[i]; }
    }
#pragma unroll
    for (int e = 0; e < 4; e++)
      maskw[(size_t)b * 4 + e] = (e == i1 || e == i2) ? 0.5f : 0.f;
  }
}

// ---------------- MoE GEMM1: hcls16[128x384] @ ew1t^T + GELU -> ehbuf f16 ---------
__global__ __launch_bounds__(256) void moe1_k(
    const f16* __restrict__ A, const f16* __restrict__ Bm,
    const float* __restrict__ bias, f16* __restrict__ outh) {
  __shared__ f16 As[128 * 32];
  __shared__ f16 Bs[64 * 32];
  const int K = EMB;
  const int tid = threadIdx.x;
  const int lane = tid & 63;
  const int wave = tid >> 6;
  const int e = (int)blockIdx.y;
  const int n0 = (int)blockIdx.x * 64;
  const int wm = (wave >> 1) * 64;
  const int wn = (wave & 1) * 32;
  const int fr = lane & 15;
  const int fq = lane >> 4;
  Bm += (size_t)e * HID * EMB;
  bias += (size_t)e * HID;

  f32x4 acc[4][2];
#pragma unroll
  for (int i = 0; i < 4; i++)
#pragma unroll
    for (int j = 0; j < 2; j++) acc[i][j] = f32x4{0.f, 0.f, 0.f, 0.f};

  const int sr = lane >> 2;
  const int sc = (lane & 3) * 8;
  const f16* ag = A + (size_t)(wave * 32 + sr) * K + sc;
  const f16* bg = Bm + (size_t)(n0 + wave * 16 + sr) * K + sc;
  const size_t rstep = (size_t)16 * K;
  f16* la = As + wave * 32 * 32;
  f16* lb = Bs + wave * 16 * 32;

  for (int k0 = 0; k0 < K; k0 += 32) {
    gload16(ag, la);  gload16(ag + rstep, la + 16 * 32);
    gload16(bg, lb);
    ag += 32; bg += 32;
    __syncthreads();
    f16x8 af[4], bf[2];
#pragma unroll
    for (int i = 0; i < 4; i++)
      af[i] = *(const f16x8*)&As[(wm + i * 16 + fr) * 32 + fq * 8];
#pragma unroll
    for (int j = 0; j < 2; j++)
      bf[j] = *(const f16x8*)&Bs[(wn + j * 16 + fr) * 32 + fq * 8];
#pragma unroll
    for (int i = 0; i < 4; i++)
#pragma unroll
      for (int j = 0; j < 2; j++)
        acc[i][j] = __builtin_amdgcn_mfma_f32_16x16x32_f16(af[i], bf[j], acc[i][j], 0, 0, 0);
    __syncthreads();
  }

#pragma unroll
  for (int i = 0; i < 4; i++)
#pragma unroll
    for (int j = 0; j < 2; j++)
#pragma unroll
      for (int rg = 0; rg < 4; rg++) {
        int gm = wm + i * 16 + fq * 4 + rg;
        int gn = n0 + wn + j * 16 + fr;
        float v = acc[i][j][rg] + bias[gn];
        float gl = 0.5f * v * (1.0f + erff(v * 0.70710678118654752f));
        outh[(size_t)e * 128 * HID + (size_t)gm * HID + gn] = (f16)gl;
      }
}

// ---------------- MoE GEMM2 split-K ----------------
__global__ __launch_bounds__(256) void moe2_k(
    const f16* __restrict__ EH, const f16* __restrict__ W2,
    float* __restrict__ part) {
  __shared__ f16 As[128 * 32];
  __shared__ f16 Bs[64 * 32];
  const int tid = threadIdx.x;
  const int lane = tid & 63;
  const int wave = tid >> 6;
  const int n0 = (int)blockIdx.x * 64;
  const int e = (int)blockIdx.y;
  const int kc = (int)blockIdx.z;
  const int wm = (wave >> 1) * 64;
  const int wn = (wave & 1) * 32;
  const int fr = lane & 15;
  const int fq = lane >> 4;
  const f16* A = EH + (size_t)e * 128 * HID + kc * 384;
  const f16* B = W2 + (size_t)e * EMB * HID + kc * 384;

  f32x4 acc[4][2];
#pragma unroll
  for (int i = 0; i < 4; i++)
#pragma unroll
    for (int j = 0; j < 2; j++) acc[i][j] = f32x4{0.f, 0.f, 0.f, 0.f};

  const int sr = lane >> 2;
  const int sc = (lane & 3) * 8;
  const f16* ag = A + (size_t)(wave * 32 + sr) * HID + sc;
  const f16* bg = B + (size_t)(n0 + wave * 16 + sr) * HID + sc;
  const size_t rstep = (size_t)16 * HID;
  f16* la = As + wave * 32 * 32;
  f16* lb = Bs + wave * 16 * 32;

  for (int k0 = 0; k0 < 384; k0 += 32) {
    gload16(ag, la);  gload16(ag + rstep, la + 16 * 32);
    gload16(bg, lb);
    ag += 32; bg += 32;
    __syncthreads();
    f16x8 af[4], bf[2];
#pragma unroll
    for (int i = 0; i < 4; i++)
      af[i] = *(const f16x8*)&As[(wm + i * 16 + fr) * 32 + fq * 8];
#pragma unroll
    for (int j = 0; j < 2; j++)
      bf[j] = *(const f16x8*)&Bs[(wn + j * 16 + fr) * 32 + fq * 8];
#pragma unroll
    for (int i = 0; i < 4; i++)
#pragma unroll
      for (int j = 0; j < 2; j++)
        acc[i][j] = __builtin_amdgcn_mfma_f32_16x16x32_f16(af[i], bf[j], acc[i][j], 0, 0, 0);
    __syncthreads();
  }

#pragma unroll
  for (int i = 0; i < 4; i++)
#pragma unroll
    for (int j = 0; j < 2; j++)
#pragma unroll
      for (int rg = 0; rg < 4; rg++) {
        int gm = wm + i * 16 + fq * 4 + rg;
        int gn = n0 + wn + j * 16 + fr;
        part[(((size_t)kc * 4 + e) * 128 + gm) * EMB + gn] = acc[i][j][rg];
      }
}

// ---------------- combine split-K + experts + LN2 -> f16 ----------------
__global__ __launch_bounds__(384) void combine_ln2_k(
    const float* __restrict__ part, const float* __restrict__ eb2,
    const float* __restrict__ maskw,
    const float* __restrict__ g, const float* __restrict__ bb,
    f16* __restrict__ hfin) {
  __shared__ float red[16];
  int b = blockIdx.x, t = threadIdx.x;
  int lane = t & 63, wave = t >> 6;
  float v = 0.f;
#pragma unroll
  for (int e = 0; e < 4; e++) {
    float s = eb2[e * EMB + t];
#pragma unroll
    for (int kc = 0; kc < 4; kc++)
      s += part[(((size_t)kc * 4 + e) * 128 + b) * EMB + t];
    v += maskw[b * 4 + e] * s;
  }
  float s = v, sq = v * v;
#pragma unroll
  for (int off = 32; off; off >>= 1) {
    s += __shfl_xor(s, off);
    sq += __shfl_xor(sq, off);
  }
  if (lane == 0) { red[wave] = s; red[8 + wave] = sq; }
  __syncthreads();
  float S = 0.f, SQ = 0.f;
#pragma unroll
  for (int i = 0; i < 6; i++) { S += red[i]; SQ += red[8 + i]; }
  float m = S * (1.f / 384.f);
  float rs = rsqrtf(SQ * (1.f / 384.f) - m * m + 1e-5f);
  hfin[(size_t)b * EMB + t] = (f16)((v - m) * rs * g[t] + bb[t]);
}

// ---------------- head GEMM ----------------
__global__ __launch_bounds__(256) void head_gemm_k(
    const f16* __restrict__ A, const f16* __restrict__ B,
    const float* __restrict__ hb, float* __restrict__ outp) {
  __shared__ f16 As[128 * 32];
  __shared__ f16 Bs[128 * 32];
  const int K = 384;
  const int tid = threadIdx.x;
  const int lane = tid & 63;
  const int wave = tid >> 6;
  const int n0 = (int)blockIdx.x * 128;
  const int wm = (wave >> 1) * 64;
  const int wn = (wave & 1) * 64;
  const int fr = lane & 15;
  const int fq = lane >> 4;

  f32x4 acc[4][4];
#pragma unroll
  for (int i = 0; i < 4; i++)
#pragma unroll
    for (int j = 0; j < 4; j++) acc[i][j] = f32x4{0.f, 0.f, 0.f, 0.f};

  const int srow = wave * 32 + (lane >> 2);
  const int scol = (lane & 3) * 8;
  const f16* ag = A + (size_t)srow * K + scol;
  const f16* bg = B + (size_t)(n0 + srow) * K + scol;
  const size_t rstep = (size_t)16 * K;
  f16* la = As + wave * 32 * 32;
  f16* lb = Bs + wave * 32 * 32;

  for (int k0 = 0; k0 < K; k0 += 32) {
    gload16(ag, la);          gload16(ag + rstep, la + 16 * 32);
    gload16(bg, lb);          gload16(bg + rstep, lb + 16 * 32);
    ag += 32; bg += 32;
    __syncthreads();
    f16x8 af[4], bf[4];
#pragma unroll
    for (int i = 0; i < 4; i++) {
      af[i] = *(const f16x8*)&As[(wm + i * 16 + fr) * 32 + fq * 8];
      bf[i] = *(const f16x8*)&Bs[(wn + i * 16 + fr) * 32 + fq * 8];
    }
#pragma unroll
    for (int i = 0; i < 4; i++)
#pragma unroll
      for (int j = 0; j < 4; j++)
        acc[i][j] = __builtin_amdgcn_mfma_f32_16x16x32_f16(af[i], bf[j], acc[i][j], 0, 0, 0);
    __syncthreads();
  }

#pragma unroll
  for (int i = 0; i < 4; i++)
#pragma unroll
    for (int j = 0; j < 4; j++)
#pragma unroll
      for (int rg = 0; rg < 4; rg++) {
        int gm = wm + i * 16 + fq * 4 + rg;
        int gn = n0 + wn + j * 16 + fr;
        if (gn < 1000)
          outp[(size_t)gm * 1000 + gn] = acc[i][j][rg] + hb[gn];
      }
}

// ---------------- host ----------------
extern "C" void kernel_launch(void* const* d_in, const int* in_sizes, int n_in,
                              void* d_out, int out_size, void* d_ws, size_t ws_size,
                              hipStream_t stream) {
  const float* x      = (const float*)d_in[0];
  const float* conv_w = (const float*)d_in[1];
  const float* conv_b = (const float*)d_in[2];
  const float* cls_t  = (const float*)d_in[3];
  const float* pos    = (const float*)d_in[4];
  const float* ln1_g  = (const float*)d_in[5];
  const float* ln1_b  = (const float*)d_in[6];
  const float* inp_w  = (const float*)d_in[7];
  const float* inp_b  = (const float*)d_in[8];
  const float* outp_w = (const float*)d_in[9];
  const float* outp_b = (const float*)d_in[10];
  const float* rt_w   = (const float*)d_in[11];
  const float* rt_b   = (const float*)d_in[12];
  const float* ew1    = (const float*)d_in[13];
  const float* eb1    = (const float*)d_in[14];
  const float* ew2    = (const float*)d_in[15];
  const float* eb2    = (const float*)d_in[16];
  const float* ln2_g  = (const float*)d_in[17];
  const float* ln2_b  = (const float*)d_in[18];
  const float* head_w = (const float*)d_in[19];
  const float* head_b = (const float*)d_in[20];
  float* out = (float*)d_out;
  char* w = (char*)d_ws;
  if (ws_size < WS_NEEDED) return;

  f16* convw    = (f16*)(w + OFF_CONVW);
  f16* ew1t     = (f16*)(w + OFF_EW1T);
  f16* ew2t     = (f16*)(w + OFF_EW2T);
  f16* headw16  = (f16*)(w + OFF_HEADW16);
  f16* xcls16   = (f16*)(w + OFF_XCLS16);
  float* qvec   = (float*)(w + OFF_Q);
  f16* hcls16   = (f16*)(w + OFF_HCLS16);
  float* maskw  = (float*)(w + OFF_MASKW);
  f16* ehbuf    = (f16*)(w + OFF_EH);
  float* epart  = (float*)(w + OFF_EPART);
  f16* hfin     = (f16*)(w + OFF_HFIN);
  f16* xh       = (f16*)(w + OFF_XH);
  float* Rg     = (float*)(w + OFF_R);
  float* Cg     = (float*)(w + OFF_CVEC);
  f16* u16      = (f16*)(w + OFF_U16);
  f16* o16      = (f16*)(w + OFF_O16);
  f16* wv16     = (f16*)(w + OFF_WV16);
  f16* wout16   = (f16*)(w + OFF_WOUT16);
  float* o2cls  = (float*)(w + OFF_O2CLS);
  float* p32    = (float*)(w + OFF_P32);

  // ---- weight prep ----
  prep_cast_k<<<dim3(3840), 256, 0, stream>>>(
      conv_w, head_w, inp_w, outp_w, convw, headw16, wv16, wout16);
  transpose_cast_k<<<dim3(48, 12, 4), 256, 0, stream>>>(ew1, ew1t, 384, 1536);
  transpose_cast_k<<<dim3(12, 48, 4), 256, 0, stream>>>(ew2, ew2t, 1536, 384);

  // ---- cls precompute + r_h precompute + broadcast ----
  clsprep_k<<<dim3(1), 384, 0, stream>>>(cls_t, pos, ln1_g, ln1_b, inp_w, inp_b, xcls16, qvec);
  rprep_k<<<dim3(6), 384, 0, stream>>>(inp_w, inp_b, qvec, Rg, Cg);
  bcast_cls_k<<<dim3(128), 384, 0, stream>>>(xcls16, xh);

  // ---- fused implicit-im2col embed GEMM + LN1 -> xh patch rows ----
  embed_ln_k<<<dim3(392), 1024, 0, stream>>>(x, convw, conv_b, pos, ln1_g, ln1_b, xh);

  // ---- attention middle: scores+softmax -> P32; u-GEMV -> U16; projections ----
  score_sm_k<<<dim3(128), 768, 0, stream>>>(xh, Rg, Cg, p32);
  u_gemv_k<<<dim3(3, 128), 256, 0, stream>>>(p32, xh, u16);
  vproj_k<<<dim3(6), 256, 0, stream>>>(u16, wv16, inp_b, o16);
  oproj_k<<<dim3(6), 256, 0, stream>>>(o16, wout16, outp_b, o2cls);
  ln_router_k<<<dim3(128), 384, 0, stream>>>(
      o2cls, ln1_g, ln1_b, rt_w, rt_b, hcls16, maskw);

  // ---- MoE ----
  moe1_k<<<dim3(24, 4), 256, 0, stream>>>(hcls16, ew1t, eb1, ehbuf);
  moe2_k<<<dim3(6, 4, 4), 256, 0, stream>>>(ehbuf, ew2t, epart);
  combine_ln2_k<<<dim3(128), 384, 0, stream>>>(epart, eb2, maskw, ln2_g, ln2_b, hfin);

  // ---- head ----
  head_gemm_k<<<dim3(8), 256, 0, stream>>>(hfin, headw16, head_b, out);
  (void)in_sizes; (void)n_in; (void)out_size;
}

// Round 6
// 344.471 us; speedup vs baseline: 1.2956x; 1.2298x over previous
//
#include <hip/hip_runtime.h>
#include <cstdint>
#include <cstddef>

typedef _Float16 f16;
typedef _Float16 f16x2 __attribute__((ext_vector_type(2)));
typedef _Float16 f16x8 __attribute__((ext_vector_type(8)));
typedef float    f32x4 __attribute__((ext_vector_type(4)));

// ---------------- problem constants ----------------
constexpr int NTOKC  = 197;
constexpr int TTOK   = 128 * 197;         // 25216
constexpr int EMB    = 384;
constexpr int HID    = 1536;

// ---------------- workspace layout (bytes) ----------------
constexpr size_t OFF_CONVW   = 0;                        // 384*768 f16
constexpr size_t OFF_EW1T    = 1179648;                  // 4*1536*384 f16
constexpr size_t OFF_EW2T    = 5898240;                  // 4*384*1536 f16
constexpr size_t OFF_HEADW16 = 10616832;                 // 1024*384 f16
constexpr size_t OFF_XCLS16  = 11403264;                 // 384 f16
constexpr size_t OFF_Q       = 11404800;                 // 384 f32
constexpr size_t OFF_HCLS16  = 11799552;                 // 128*384 f16
constexpr size_t OFF_MASKW   = 11897856;                 // 128*4 f32
constexpr size_t OFF_EH      = 11899904;                 // 4*128*1536 f16
constexpr size_t OFF_EPART   = 13472768;                 // 4kc*4e*128*384 f32
constexpr size_t OFF_HFIN    = 16618496;                 // 128*384 f16
constexpr size_t OFF_XH      = 16716800;                 // TTOK*384 f16
constexpr size_t OFF_R       = 36082688;                 // 6*384 f32
constexpr size_t OFF_CVEC    = 36094976;                 // 6 f32
constexpr size_t OFF_U16     = 36099072;                 // 128*2304 f16
constexpr size_t OFF_O16     = 36688896;                 // 128*384 f16
constexpr size_t OFF_WV16    = 36787200;                 // 384*384 f16
constexpr size_t OFF_WOUT16  = 37082112;                 // 384*384 f16
constexpr size_t OFF_O2CLS   = 37377024;                 // 128*384 f32
constexpr size_t OFF_P32     = 37573632;                 // 128*6*208 f32
constexpr size_t OFF_SG      = 38212608;                 // 128*6*197 f32
constexpr size_t OFF_SCLS    = 38817792;                 // 6 f32
constexpr size_t WS_NEEDED   = 38818816;                 // ~38.8 MB

// ---------------- global_load_lds helper ----------------
__device__ __forceinline__ void gload16(const void* g, void* l) {
  __builtin_amdgcn_global_load_lds(
      (__attribute__((address_space(1))) void*)(void*)g,
      (__attribute__((address_space(3))) void*)l, 16, 0, 0);
}

// ---------------- prep: all weight casts in one launch ------------
__global__ __launch_bounds__(256) void prep_cast_k(
    const float* __restrict__ conv_w, const float* __restrict__ head_w,
    const float* __restrict__ inp_w, const float* __restrict__ outp_w,
    f16* __restrict__ convw, f16* __restrict__ headw16,
    f16* __restrict__ wv16, f16* __restrict__ wout16) {
  int i = blockIdx.x * 256 + threadIdx.x;
  if (i < 294912) convw[i] = (f16)conv_w[i];
  int j = i - 294912;
  if (j >= 0 && j < 393216) {
    int row = j / 384;
    headw16[j] = (row < 1000) ? (f16)head_w[j] : (f16)0.f;
  }
  int k = i - 688128;
  if (k >= 0 && k < 147456) wv16[k] = (f16)inp_w[294912 + k];
  int l = i - 835584;
  if (l >= 0 && l < 147456) wout16[l] = (f16)outp_w[l];
}

__global__ __launch_bounds__(256) void transpose_cast_k(
    const float* __restrict__ in, f16* __restrict__ outp, int R, int C) {
  __shared__ float tile[32][33];
  int e = blockIdx.z;
  const float* pin = in + (size_t)e * R * C;
  f16* pout = outp + (size_t)e * R * C;
  int c0 = blockIdx.x * 32, r0 = blockIdx.y * 32;
  int tx = threadIdx.x & 31, ty = threadIdx.x >> 5;
#pragma unroll
  for (int i = 0; i < 4; i++)
    tile[ty + 8 * i][tx] = pin[(size_t)(r0 + ty + 8 * i) * C + c0 + tx];
  __syncthreads();
#pragma unroll
  for (int i = 0; i < 4; i++)
    pout[(size_t)(c0 + ty + 8 * i) * R + r0 + tx] = (f16)tile[tx][ty + 8 * i];
}

// ---------------- cls precompute: xcls = LN(cls+pos[0]); q = Wq.xcls + bq ----------
__global__ __launch_bounds__(384) void clsprep_k(
    const float* __restrict__ cls, const float* __restrict__ posw,
    const float* __restrict__ g, const float* __restrict__ bb,
    const float* __restrict__ Wq, const float* __restrict__ bq,
    f16* __restrict__ xcls16, float* __restrict__ qout) {
  __shared__ float xs[EMB];
  __shared__ float red[16];
  int t = threadIdx.x, lane = t & 63, wave = t >> 6;
  float v = cls[t] + posw[t];
  float s = v, sq = v * v;
#pragma unroll
  for (int off = 32; off; off >>= 1) {
    s += __shfl_xor(s, off);
    sq += __shfl_xor(sq, off);
  }
  if (lane == 0) { red[wave] = s; red[8 + wave] = sq; }
  __syncthreads();
  float S = 0.f, SQ = 0.f;
#pragma unroll
  for (int i = 0; i < 6; i++) { S += red[i]; SQ += red[8 + i]; }
  float m = S * (1.f / 384.f);
  float rs = rsqrtf(SQ * (1.f / 384.f) - m * m + 1e-5f);
  float y = (v - m) * rs * g[t] + bb[t];
  xs[t] = y;
  xcls16[t] = (f16)y;
  __syncthreads();
  const float4* w4 = (const float4*)(Wq + (size_t)t * EMB);
  const float4* s4 = (const float4*)xs;
  float a = bq[t];
#pragma unroll 8
  for (int i = 0; i < 96; i++) {
    float4 xx = s4[i], ww = w4[i];
    a += xx.x * ww.x + xx.y * ww.y + xx.z * ww.z + xx.w * ww.w;
  }
  qout[t] = a;
}

// ---------------- R precompute: r_h = Wk_h^T q_h, c_h = q_h.bk_h,
//                  Scls_h = xcls . r_h + c_h  (batch-independent) -------------
__global__ __launch_bounds__(384) void rprep_k(
    const float* __restrict__ inp_w, const float* __restrict__ inp_b,
    const float* __restrict__ qv, const f16* __restrict__ xcls16,
    float* __restrict__ Rg, float* __restrict__ Cg, float* __restrict__ Scls) {
  int h = blockIdx.x, t = threadIdx.x;
  __shared__ float qs[64];
  __shared__ float cred[64];
  __shared__ float sred[6];
  if (t < 64) {
    float q = qv[h * 64 + t];
    qs[t] = q;
    cred[t] = q * inp_b[384 + h * 64 + t];
  }
  __syncthreads();
  const float* wp = inp_w + ((size_t)(384 + h * 64)) * 384 + t;
  float a = 0.f;
#pragma unroll 8
  for (int d = 0; d < 64; d++) a += wp[(size_t)d * 384] * qs[d];
  Rg[h * 384 + t] = a;
  // cls-score partial: Rg[h][t] * xcls[t]
  float part = a * (float)xcls16[t];
  int lane = t & 63, wave = t >> 6;
#pragma unroll
  for (int off = 32; off; off >>= 1) part += __shfl_xor(part, off);
  if (lane == 0) sred[wave] = part;
  __syncthreads();
  if (t == 0) {
    float c = 0.f;
    for (int d = 0; d < 64; d++) c += cred[d];
    Cg[h] = c;
    float stot = c;
#pragma unroll
    for (int i = 0; i < 6; i++) stot += sred[i];
    Scls[h] = stot;
  }
}

// ---------------- broadcast cls row into xh; splat cls score into Sg ----------
__global__ __launch_bounds__(384) void bcast_cls_k(
    const f16* __restrict__ xcls16, const float* __restrict__ Scls,
    f16* __restrict__ xh, float* __restrict__ Sg) {
  int b = blockIdx.x, t = threadIdx.x;
  xh[(size_t)b * NTOKC * EMB + t] = xcls16[t];
  if (t < 6) Sg[((size_t)b * 6 + t) * 197] = Scls[t];
}

// ---------------- fused IMPLICIT-im2col patch-embed GEMM + bias + pos + LN1
//                  + score epilogue: Sg[b][h][t] = y . r_h + c_h --------------
__global__ __launch_bounds__(1024) void embed_ln_k(
    const float* __restrict__ img, const f16* __restrict__ B,
    const float* __restrict__ bias, const float* __restrict__ posw,
    const float* __restrict__ g, const float* __restrict__ bb,
    const float* __restrict__ Rg, const float* __restrict__ Cg,
    f16* __restrict__ xh, float* __restrict__ Sg) {
  __shared__ f16 As[64 * 32];       // 4 KB
  __shared__ f16 Bs[384 * 32];      // 24 KB
  __shared__ float prm[3 * 384];    // bias | gamma | beta
  __shared__ float psum[64 * 4];
  __shared__ float pqsum[64 * 4];
  __shared__ float Rs2[2304];       // 9 KB  (r_h vectors)
  __shared__ float psc[64 * 24];    // 6 KB  ([lrow][colgrp][h] score partials)
  const int K = 768;
  const int tid = threadIdx.x;
  const int lane = tid & 63;
  const int wave = tid >> 6;        // 0..15
  const int rowgrp = wave & 3;
  const int colgrp = wave >> 2;
  const int m0 = (int)blockIdx.x * 64;
  const int fr = lane & 15;
  const int fq = lane >> 4;

  for (int i = tid; i < 384; i += 1024) {
    prm[i] = bias[i]; prm[384 + i] = g[i]; prm[768 + i] = bb[i];
  }
  for (int i = tid; i < 2304; i += 1024) Rs2[i] = Rg[i];

  f32x4 acc[6];
#pragma unroll
  for (int j = 0; j < 6; j++) acc[j] = f32x4{0.f, 0.f, 0.f, 0.f};

  const int sr = lane >> 2, sc = (lane & 3) * 8;
  const float* abase = nullptr;
  f16* adst = nullptr;
  if (wave < 4) {
    int row = m0 + wave * 16 + sr;          // patch index 0..25087
    int bimg = row / 196;
    int pp = row - bimg * 196;
    int py = pp / 14, px = pp - py * 14;
    int kx0 = sc & 15;                      // 0 or 8
    abase = img + ((size_t)(bimg * 3) * 224 + py * 16) * 224 + px * 16 + kx0;
    adst = As + (wave * 16 + sr) * 32 + sc;
  }
  const f16* gb0 = nullptr;
  f16* lb0 = nullptr;
  if (wave >= 4) {
    int brow = (wave - 4) * 32;
    gb0 = B + (size_t)(brow + sr) * K + sc;
    lb0 = Bs + brow * 32;
  }

  for (int k0 = 0; k0 < K; k0 += 32) {
    if (wave < 4) {
      int col = k0 + sc;
      int c = col >> 8;
      int ky = (col >> 4) & 15;
      const float* src = abase + c * 50176 + ky * 224;
      float4 p0 = *(const float4*)src;
      float4 p1 = *(const float4*)(src + 4);
      f16x8 hv;
      hv[0] = (f16)p0.x; hv[1] = (f16)p0.y; hv[2] = (f16)p0.z; hv[3] = (f16)p0.w;
      hv[4] = (f16)p1.x; hv[5] = (f16)p1.y; hv[6] = (f16)p1.z; hv[7] = (f16)p1.w;
      *(f16x8*)adst = hv;
    } else {
      gload16(gb0, lb0); gload16(gb0 + (size_t)16 * K, lb0 + 16 * 32);
      gb0 += 32;
    }
    __syncthreads();
    f16x8 af = *(const f16x8*)&As[(rowgrp * 16 + fr) * 32 + fq * 8];
#pragma unroll
    for (int j = 0; j < 6; j++) {
      f16x8 bf = *(const f16x8*)&Bs[(colgrp * 96 + j * 16 + fr) * 32 + fq * 8];
      acc[j] = __builtin_amdgcn_mfma_f32_16x16x32_f16(af, bf, acc[j], 0, 0, 0);
    }
    __syncthreads();
  }

  // ---- epilogue 1: bias+pos, LN partial sums ----
  float v[4][6];
#pragma unroll
  for (int rg = 0; rg < 4; rg++) {
    int lrow = rowgrp * 16 + fq * 4 + rg;
    int row = m0 + lrow;
    int bimg = row / 196;
    int pp = row - bimg * 196;
    const float* prow = posw + (size_t)(pp + 1) * EMB;
    float s = 0.f, sq = 0.f;
#pragma unroll
    for (int j = 0; j < 6; j++) {
      int col = colgrp * 96 + j * 16 + fr;
      float t = acc[j][rg] + prm[col] + prow[col];
      v[rg][j] = t;
      s += t; sq += t * t;
    }
#pragma unroll
    for (int off = 1; off < 16; off <<= 1) {
      s += __shfl_xor(s, off);
      sq += __shfl_xor(sq, off);
    }
    if (fr == 0) { psum[lrow * 4 + colgrp] = s; pqsum[lrow * 4 + colgrp] = sq; }
  }
  __syncthreads();

  // ---- epilogue 2: LN normalize -> y (kept in v), store xh f16 ----
#pragma unroll
  for (int rg = 0; rg < 4; rg++) {
    int lrow = rowgrp * 16 + fq * 4 + rg;
    float S = psum[lrow * 4] + psum[lrow * 4 + 1] + psum[lrow * 4 + 2] + psum[lrow * 4 + 3];
    float SQ = pqsum[lrow * 4] + pqsum[lrow * 4 + 1] + pqsum[lrow * 4 + 2] + pqsum[lrow * 4 + 3];
    float m = S * (1.f / 384.f);
    float rs = rsqrtf(SQ * (1.f / 384.f) - m * m + 1e-5f);
    int row = m0 + lrow;
    int bimg = row / 196;
    int pp = row - bimg * 196;
    f16* orow = xh + ((size_t)bimg * NTOKC + pp + 1) * EMB;
#pragma unroll
    for (int j = 0; j < 6; j++) {
      int col = colgrp * 96 + j * 16 + fr;
      float y = (v[rg][j] - m) * rs * prm[384 + col] + prm[768 + col];
      v[rg][j] = y;
      orow[col] = (f16)y;
    }
  }

  // ---- epilogue 3: score partials p[row][h] = sum_col y*r_h ----
#pragma unroll
  for (int h = 0; h < 6; h++) {
    float rv[6];
#pragma unroll
    for (int j = 0; j < 6; j++)
      rv[j] = Rs2[h * 384 + colgrp * 96 + j * 16 + fr];
#pragma unroll
    for (int rg = 0; rg < 4; rg++) {
      float p = v[rg][0] * rv[0] + v[rg][1] * rv[1] + v[rg][2] * rv[2]
              + v[rg][3] * rv[3] + v[rg][4] * rv[4] + v[rg][5] * rv[5];
#pragma unroll
      for (int off = 1; off < 16; off <<= 1) p += __shfl_xor(p, off);
      if (fr == 0) psc[(rowgrp * 16 + fq * 4 + rg) * 24 + colgrp * 6 + h] = p;
    }
  }
  __syncthreads();
  if (tid < 384) {
    int lrow = tid / 6, h = tid - lrow * 6;
    float s = psc[lrow * 24 + h] + psc[lrow * 24 + 6 + h]
            + psc[lrow * 24 + 12 + h] + psc[lrow * 24 + 18 + h] + Cg[h];
    int row = m0 + lrow;
    int bimg = row / 196, pp = row - bimg * 196;
    Sg[((size_t)bimg * 6 + h) * 197 + pp + 1] = s;
  }
}

// ---------------- softmax over Sg -> normalized P32[b][6][208] -----------------
// grid 128 x 384 (6 waves, one head each).
__global__ __launch_bounds__(384) void softmax_k(
    const float* __restrict__ Sg, float* __restrict__ P32) {
  const int b = blockIdx.x, tid = threadIdx.x;
  const int wave = tid >> 6, lane = tid & 63;
  const float* sp = Sg + ((size_t)b * 6 + wave) * 197;
  float z[4], pk[4];
#pragma unroll
  for (int k = 0; k < 4; k++) {
    int t = lane + 64 * k;
    z[k] = (t < 197) ? sp[t] * 0.125f : -1e30f;
    pk[k] = 0.f;
  }
  float mx = fmaxf(fmaxf(z[0], z[1]), fmaxf(z[2], z[3]));
#pragma unroll
  for (int off = 32; off; off >>= 1) mx = fmaxf(mx, __shfl_xor(mx, off));
  float sum = 0.f;
#pragma unroll
  for (int k = 0; k < 4; k++) {
    int t = lane + 64 * k;
    if (t < 197) {
      pk[k] = __expf(z[k] - mx);
      sum += pk[k];
    }
  }
#pragma unroll
  for (int off = 32; off; off >>= 1) sum += __shfl_xor(sum, off);
  float si = 1.f / sum;
#pragma unroll
  for (int k = 0; k < 4; k++) {
    int t = lane + 64 * k;
    if (t < 208) P32[(size_t)b * 1248 + wave * 208 + t] = pk[k] * si;
  }
}

// ---------------- u[b][h][col] = sum_t P[b][h][t] * xh[b][t][col] -> U16 ---------
__global__ __launch_bounds__(256) void u_gemv_k(
    const float* __restrict__ P32, const f16* __restrict__ xh,
    f16* __restrict__ U16) {
  __shared__ float pf[6 * 208];        // 4992 B
  __shared__ float part[4][64][12];    // 12 KB
  const int cq = (int)blockIdx.x;      // 0..2
  const int b  = (int)blockIdx.y;
  const int tid = threadIdx.x;
  for (int i = tid; i < 1248; i += 256) pf[i] = P32[(size_t)b * 1248 + i];
  __syncthreads();
  const int cp = tid & 63;
  const int tq = tid >> 6;
  const int col0 = cq * 128 + cp * 2;
  const int t0 = 49 * tq;
  const int t1 = (tq == 3) ? 197 : t0 + 49;
  float acc[12];
#pragma unroll
  for (int r = 0; r < 12; r++) acc[r] = 0.f;
  const f16* xp = xh + ((size_t)b * NTOKC + t0) * EMB + col0;
#pragma unroll 2
  for (int t = t0; t < t1; t++) {
    f16x2 xv = *(const f16x2*)xp;
    float x0 = (float)xv[0];
    float x1 = (float)xv[1];
    xp += EMB;
#pragma unroll
    for (int h = 0; h < 6; h++) {
      float p = pf[h * 208 + t];
      acc[h * 2]     += p * x0;
      acc[h * 2 + 1] += p * x1;
    }
  }
#pragma unroll
  for (int r = 0; r < 12; r++) part[tq][cp][r] = acc[r];
  __syncthreads();
#pragma unroll
  for (int k = 0; k < 3; k++) {
    int idx = tid + k * 256;            // 0..767
    int cp2 = idx / 12, slot = idx - cp2 * 12;
    int h = slot >> 1, c01 = slot & 1;
    float u = part[0][cp2][slot] + part[1][cp2][slot] +
              part[2][cp2][slot] + part[3][cp2][slot];
    U16[(size_t)b * 2304 + h * 384 + cq * 128 + cp2 * 2 + c01] = (f16)u;
  }
}

// ---------------- V-projection GEMM: o[b][h*64+n] = Wv_h[n,:].u[b][h] + bv ------
__global__ __launch_bounds__(256) void vproj_k(
    const f16* __restrict__ U16, const f16* __restrict__ wv16,
    const float* __restrict__ inp_b, f16* __restrict__ O16) {
  __shared__ f16 As[128 * 32];
  __shared__ f16 Bs[64 * 32];
  const int tid = threadIdx.x;
  const int lane = tid & 63;
  const int wave = tid >> 6;
  const int h = (int)blockIdx.x;
  const int wm = (wave >> 1) * 64;
  const int wn = (wave & 1) * 32;
  const int fr = lane & 15;
  const int fq = lane >> 4;
  const float* bv = inp_b + 768 + h * 64;

  f32x4 acc[4][2];
#pragma unroll
  for (int i = 0; i < 4; i++)
#pragma unroll
    for (int j = 0; j < 2; j++) acc[i][j] = f32x4{0.f, 0.f, 0.f, 0.f};

  const int sr = lane >> 2;
  const int sc = (lane & 3) * 8;
  const f16* ag = U16 + (size_t)(wave * 32 + sr) * 2304 + h * 384 + sc;
  const f16* bg = wv16 + (size_t)(h * 64 + wave * 16 + sr) * 384 + sc;
  const size_t rstepA = (size_t)16 * 2304;
  f16* la = As + wave * 32 * 32;
  f16* lb = Bs + wave * 16 * 32;

  for (int k0 = 0; k0 < 384; k0 += 32) {
    gload16(ag, la);  gload16(ag + rstepA, la + 16 * 32);
    gload16(bg, lb);
    ag += 32; bg += 32;
    __syncthreads();
    f16x8 af[4], bf[2];
#pragma unroll
    for (int i = 0; i < 4; i++)
      af[i] = *(const f16x8*)&As[(wm + i * 16 + fr) * 32 + fq * 8];
#pragma unroll
    for (int j = 0; j < 2; j++)
      bf[j] = *(const f16x8*)&Bs[(wn + j * 16 + fr) * 32 + fq * 8];
#pragma unroll
    for (int i = 0; i < 4; i++)
#pragma unroll
      for (int j = 0; j < 2; j++)
        acc[i][j] = __builtin_amdgcn_mfma_f32_16x16x32_f16(af[i], bf[j], acc[i][j], 0, 0, 0);
    __syncthreads();
  }

#pragma unroll
  for (int i = 0; i < 4; i++)
#pragma unroll
    for (int j = 0; j < 2; j++)
#pragma unroll
      for (int rg = 0; rg < 4; rg++) {
        int gm = wm + i * 16 + fq * 4 + rg;
        int gn = wn + j * 16 + fr;
        O16[(size_t)gm * EMB + h * 64 + gn] = (f16)(acc[i][j][rg] + bv[gn]);
      }
}

// ---------------- out-projection GEMM: o2 = Wout.o + bout (f32 out) -------------
__global__ __launch_bounds__(256) void oproj_k(
    const f16* __restrict__ O16, const f16* __restrict__ wout16,
    const float* __restrict__ bout, float* __restrict__ o2cls) {
  __shared__ f16 As[128 * 32];
  __shared__ f16 Bs[64 * 32];
  const int tid = threadIdx.x;
  const int lane = tid & 63;
  const int wave = tid >> 6;
  const int n0 = (int)blockIdx.x * 64;
  const int wm = (wave >> 1) * 64;
  const int wn = (wave & 1) * 32;
  const int fr = lane & 15;
  const int fq = lane >> 4;

  f32x4 acc[4][2];
#pragma unroll
  for (int i = 0; i < 4; i++)
#pragma unroll
    for (int j = 0; j < 2; j++) acc[i][j] = f32x4{0.f, 0.f, 0.f, 0.f};

  const int sr = lane >> 2;
  const int sc = (lane & 3) * 8;
  const f16* ag = O16 + (size_t)(wave * 32 + sr) * 384 + sc;
  const f16* bg = wout16 + (size_t)(n0 + wave * 16 + sr) * 384 + sc;
  const size_t rstep = (size_t)16 * 384;
  f16* la = As + wave * 32 * 32;
  f16* lb = Bs + wave * 16 * 32;

  for (int k0 = 0; k0 < 384; k0 += 32) {
    gload16(ag, la);  gload16(ag + rstep, la + 16 * 32);
    gload16(bg, lb);
    ag += 32; bg += 32;
    __syncthreads();
    f16x8 af[4], bf[2];
#pragma unroll
    for (int i = 0; i < 4; i++)
      af[i] = *(const f16x8*)&As[(wm + i * 16 + fr) * 32 + fq * 8];
#pragma unroll
    for (int j = 0; j < 2; j++)
      bf[j] = *(const f16x8*)&Bs[(wn + j * 16 + fr) * 32 + fq * 8];
#pragma unroll
    for (int i = 0; i < 4; i++)
#pragma unroll
      for (int j = 0; j < 2; j++)
        acc[i][j] = __builtin_amdgcn_mfma_f32_16x16x32_f16(af[i], bf[j], acc[i][j], 0, 0, 0);
    __syncthreads();
  }

#pragma unroll
  for (int i = 0; i < 4; i++)
#pragma unroll
    for (int j = 0; j < 2; j++)
#pragma unroll
      for (int rg = 0; rg < 4; rg++) {
        int gm = wm + i * 16 + fq * 4 + rg;
        int gn = n0 + wn + j * 16 + fr;
        o2cls[(size_t)gm * EMB + gn] = acc[i][j][rg] + bout[gn];
      }
}

// ---------------- fused LN (ln1 params) + router top-2 ----------------
__global__ __launch_bounds__(384) void ln_router_k(
    const float* __restrict__ o2cls, const float* __restrict__ g, const float* __restrict__ bb,
    const float* __restrict__ rw, const float* __restrict__ rb,
    f16* __restrict__ hcls16, float* __restrict__ maskw) {
  __shared__ float red[16];
  __shared__ float part[6][4];
  __shared__ float logits[4];
  int b = blockIdx.x, t = threadIdx.x;
  int lane = t & 63, wave = t >> 6;
  float v = o2cls[(size_t)b * EMB + t];
  float s = v, sq = v * v;
#pragma unroll
  for (int off = 32; off; off >>= 1) {
    s += __shfl_xor(s, off);
    sq += __shfl_xor(sq, off);
  }
  if (lane == 0) { red[wave] = s; red[8 + wave] = sq; }
  __syncthreads();
  float S = 0.f, SQ = 0.f;
#pragma unroll
  for (int i = 0; i < 6; i++) { S += red[i]; SQ += red[8 + i]; }
  float m = S * (1.f / 384.f);
  float rs = rsqrtf(SQ * (1.f / 384.f) - m * m + 1e-5f);
  float y = (v - m) * rs * g[t] + bb[t];
  hcls16[(size_t)b * EMB + t] = (f16)y;
  float p0 = y * rw[t];
  float p1 = y * rw[EMB + t];
  float p2 = y * rw[2 * EMB + t];
  float p3 = y * rw[3 * EMB + t];
#pragma unroll
  for (int off = 32; off; off >>= 1) {
    p0 += __shfl_xor(p0, off);
    p1 += __shfl_xor(p1, off);
    p2 += __shfl_xor(p2, off);
    p3 += __shfl_xor(p3, off);
  }
  if (lane == 0) { part[wave][0] = p0; part[wave][1] = p1; part[wave][2] = p2; part[wave][3] = p3; }
  __syncthreads();
  if (t < 4) {
    float a = rb[t];
#pragma unroll
    for (int i = 0; i < 6; i++) a += part[i][t];
    logits[t] = a;
  }
  __syncthreads();
  if (t == 0) {
    float l0 = logits[0], l1 = logits[1], l2 = logits[2], l3 = logits[3];
    int i1 = 0; float b1 = l0;
    if (l1 > b1) { b1 = l1; i1 = 1; }
    if (l2 > b1) { b1 = l2; i1 = 2; }
    if (l3 > b1) { b1 = l3; i1 = 3; }
    int i2 = -1; float b2 = 0.f;
    float lv[4] = {l0, l1, l2, l3};
#pragma unroll
    for (int i = 0; i < 4; i++) {
      if (i == i1) continue;
      if (i2 < 0 || lv[i] > b2) { i2 = i; b2 = lv[i]; }
    }
#pragma unroll
    for (int e = 0; e < 4; e++)
      maskw[(size_t)b * 4 + e] = (e == i1 || e == i2) ? 0.5f : 0.f;
  }
}

// ---------------- MoE GEMM1: hcls16[128x384] @ ew1t^T + GELU -> ehbuf f16 ---------
__global__ __launch_bounds__(256) void moe1_k(
    const f16* __restrict__ A, const f16* __restrict__ Bm,
    const float* __restrict__ bias, f16* __restrict__ outh) {
  __shared__ f16 As[128 * 32];
  __shared__ f16 Bs[64 * 32];
  const int K = EMB;
  const int tid = threadIdx.x;
  const int lane = tid & 63;
  const int wave = tid >> 6;
  const int e = (int)blockIdx.y;
  const int n0 = (int)blockIdx.x * 64;
  const int wm = (wave >> 1) * 64;
  const int wn = (wave & 1) * 32;
  const int fr = lane & 15;
  const int fq = lane >> 4;
  Bm += (size_t)e * HID * EMB;
  bias += (size_t)e * HID;

  f32x4 acc[4][2];
#pragma unroll
  for (int i = 0; i < 4; i++)
#pragma unroll
    for (int j = 0; j < 2; j++) acc[i][j] = f32x4{0.f, 0.f, 0.f, 0.f};

  const int sr = lane >> 2;
  const int sc = (lane & 3) * 8;
  const f16* ag = A + (size_t)(wave * 32 + sr) * K + sc;
  const f16* bg = Bm + (size_t)(n0 + wave * 16 + sr) * K + sc;
  const size_t rstep = (size_t)16 * K;
  f16* la = As + wave * 32 * 32;
  f16* lb = Bs + wave * 16 * 32;

  for (int k0 = 0; k0 < K; k0 += 32) {
    gload16(ag, la);  gload16(ag + rstep, la + 16 * 32);
    gload16(bg, lb);
    ag += 32; bg += 32;
    __syncthreads();
    f16x8 af[4], bf[2];
#pragma unroll
    for (int i = 0; i < 4; i++)
      af[i] = *(const f16x8*)&As[(wm + i * 16 + fr) * 32 + fq * 8];
#pragma unroll
    for (int j = 0; j < 2; j++)
      bf[j] = *(const f16x8*)&Bs[(wn + j * 16 + fr) * 32 + fq * 8];
#pragma unroll
    for (int i = 0; i < 4; i++)
#pragma unroll
      for (int j = 0; j < 2; j++)
        acc[i][j] = __builtin_amdgcn_mfma_f32_16x16x32_f16(af[i], bf[j], acc[i][j], 0, 0, 0);
    __syncthreads();
  }

#pragma unroll
  for (int i = 0; i < 4; i++)
#pragma unroll
    for (int j = 0; j < 2; j++)
#pragma unroll
      for (int rg = 0; rg < 4; rg++) {
        int gm = wm + i * 16 + fq * 4 + rg;
        int gn = n0 + wn + j * 16 + fr;
        float v = acc[i][j][rg] + bias[gn];
        float gl = 0.5f * v * (1.0f + erff(v * 0.70710678118654752f));
        outh[(size_t)e * 128 * HID + (size_t)gm * HID + gn] = (f16)gl;
      }
}

// ---------------- MoE GEMM2 split-K ----------------
__global__ __launch_bounds__(256) void moe2_k(
    const f16* __restrict__ EH, const f16* __restrict__ W2,
    float* __restrict__ part) {
  __shared__ f16 As[128 * 32];
  __shared__ f16 Bs[64 * 32];
  const int tid = threadIdx.x;
  const int lane = tid & 63;
  const int wave = tid >> 6;
  const int n0 = (int)blockIdx.x * 64;
  const int e = (int)blockIdx.y;
  const int kc = (int)blockIdx.z;
  const int wm = (wave >> 1) * 64;
  const int wn = (wave & 1) * 32;
  const int fr = lane & 15;
  const int fq = lane >> 4;
  const f16* A = EH + (size_t)e * 128 * HID + kc * 384;
  const f16* B = W2 + (size_t)e * EMB * HID + kc * 384;

  f32x4 acc[4][2];
#pragma unroll
  for (int i = 0; i < 4; i++)
#pragma unroll
    for (int j = 0; j < 2; j++) acc[i][j] = f32x4{0.f, 0.f, 0.f, 0.f};

  const int sr = lane >> 2;
  const int sc = (lane & 3) * 8;
  const f16* ag = A + (size_t)(wave * 32 + sr) * HID + sc;
  const f16* bg = B + (size_t)(n0 + wave * 16 + sr) * HID + sc;
  const size_t rstep = (size_t)16 * HID;
  f16* la = As + wave * 32 * 32;
  f16* lb = Bs + wave * 16 * 32;

  for (int k0 = 0; k0 < 384; k0 += 32) {
    gload16(ag, la);  gload16(ag + rstep, la + 16 * 32);
    gload16(bg, lb);
    ag += 32; bg += 32;
    __syncthreads();
    f16x8 af[4], bf[2];
#pragma unroll
    for (int i = 0; i < 4; i++)
      af[i] = *(const f16x8*)&As[(wm + i * 16 + fr) * 32 + fq * 8];
#pragma unroll
    for (int j = 0; j < 2; j++)
      bf[j] = *(const f16x8*)&Bs[(wn + j * 16 + fr) * 32 + fq * 8];
#pragma unroll
    for (int i = 0; i < 4; i++)
#pragma unroll
      for (int j = 0; j < 2; j++)
        acc[i][j] = __builtin_amdgcn_mfma_f32_16x16x32_f16(af[i], bf[j], acc[i][j], 0, 0, 0);
    __syncthreads();
  }

#pragma unroll
  for (int i = 0; i < 4; i++)
#pragma unroll
    for (int j = 0; j < 2; j++)
#pragma unroll
      for (int rg = 0; rg < 4; rg++) {
        int gm = wm + i * 16 + fq * 4 + rg;
        int gn = n0 + wn + j * 16 + fr;
        part[(((size_t)kc * 4 + e) * 128 + gm) * EMB + gn] = acc[i][j][rg];
      }
}

// ---------------- combine split-K + experts + LN2 -> f16 ----------------
__global__ __launch_bounds__(384) void combine_ln2_k(
    const float* __restrict__ part, const float* __restrict__ eb2,
    const float* __restrict__ maskw,
    const float* __restrict__ g, const float* __restrict__ bb,
    f16* __restrict__ hfin) {
  __shared__ float red[16];
  int b = blockIdx.x, t = threadIdx.x;
  int lane = t & 63, wave = t >> 6;
  float v = 0.f;
#pragma unroll
  for (int e = 0; e < 4; e++) {
    float s = eb2[e * EMB + t];
#pragma unroll
    for (int kc = 0; kc < 4; kc++)
      s += part[(((size_t)kc * 4 + e) * 128 + b) * EMB + t];
    v += maskw[b * 4 + e] * s;
  }
  float s = v, sq = v * v;
#pragma unroll
  for (int off = 32; off; off >>= 1) {
    s += __shfl_xor(s, off);
    sq += __shfl_xor(sq, off);
  }
  if (lane == 0) { red[wave] = s; red[8 + wave] = sq; }
  __syncthreads();
  float S = 0.f, SQ = 0.f;
#pragma unroll
  for (int i = 0; i < 6; i++) { S += red[i]; SQ += red[8 + i]; }
  float m = S * (1.f / 384.f);
  float rs = rsqrtf(SQ * (1.f / 384.f) - m * m + 1e-5f);
  hfin[(size_t)b * EMB + t] = (f16)((v - m) * rs * g[t] + bb[t]);
}

// ---------------- head GEMM ----------------
__global__ __launch_bounds__(256) void head_gemm_k(
    const f16* __restrict__ A, const f16* __restrict__ B,
    const float* __restrict__ hb, float* __restrict__ outp) {
  __shared__ f16 As[128 * 32];
  __shared__ f16 Bs[128 * 32];
  const int K = 384;
  const int tid = threadIdx.x;
  const int lane = tid & 63;
  const int wave = tid >> 6;
  const int n0 = (int)blockIdx.x * 128;
  const int wm = (wave >> 1) * 64;
  const int wn = (wave & 1) * 64;
  const int fr = lane & 15;
  const int fq = lane >> 4;

  f32x4 acc[4][4];
#pragma unroll
  for (int i = 0; i < 4; i++)
#pragma unroll
    for (int j = 0; j < 4; j++) acc[i][j] = f32x4{0.f, 0.f, 0.f, 0.f};

  const int srow = wave * 32 + (lane >> 2);
  const int scol = (lane & 3) * 8;
  const f16* ag = A + (size_t)srow * K + scol;
  const f16* bg = B + (size_t)(n0 + srow) * K + scol;
  const size_t rstep = (size_t)16 * K;
  f16* la = As + wave * 32 * 32;
  f16* lb = Bs + wave * 32 * 32;

  for (int k0 = 0; k0 < K; k0 += 32) {
    gload16(ag, la);          gload16(ag + rstep, la + 16 * 32);
    gload16(bg, lb);          gload16(bg + rstep, lb + 16 * 32);
    ag += 32; bg += 32;
    __syncthreads();
    f16x8 af[4], bf[4];
#pragma unroll
    for (int i = 0; i < 4; i++) {
      af[i] = *(const f16x8*)&As[(wm + i * 16 + fr) * 32 + fq * 8];
      bf[i] = *(const f16x8*)&Bs[(wn + i * 16 + fr) * 32 + fq * 8];
    }
#pragma unroll
    for (int i = 0; i < 4; i++)
#pragma unroll
      for (int j = 0; j < 4; j++)
        acc[i][j] = __builtin_amdgcn_mfma_f32_16x16x32_f16(af[i], bf[j], acc[i][j], 0, 0, 0);
    __syncthreads();
  }

#pragma unroll
  for (int i = 0; i < 4; i++)
#pragma unroll
    for (int j = 0; j < 4; j++)
#pragma unroll
      for (int rg = 0; rg < 4; rg++) {
        int gm = wm + i * 16 + fq * 4 + rg;
        int gn = n0 + wn + j * 16 + fr;
        if (gn < 1000)
          outp[(size_t)gm * 1000 + gn] = acc[i][j][rg] + hb[gn];
      }
}

// ---------------- host ----------------
extern "C" void kernel_launch(void* const* d_in, const int* in_sizes, int n_in,
                              void* d_out, int out_size, void* d_ws, size_t ws_size,
                              hipStream_t stream) {
  const float* x      = (const float*)d_in[0];
  const float* conv_w = (const float*)d_in[1];
  const float* conv_b = (const float*)d_in[2];
  const float* cls_t  = (const float*)d_in[3];
  const float* pos    = (const float*)d_in[4];
  const float* ln1_g  = (const float*)d_in[5];
  const float* ln1_b  = (const float*)d_in[6];
  const float* inp_w  = (const float*)d_in[7];
  const float* inp_b  = (const float*)d_in[8];
  const float* outp_w = (const float*)d_in[9];
  const float* outp_b = (const float*)d_in[10];
  const float* rt_w   = (const float*)d_in[11];
  const float* rt_b   = (const float*)d_in[12];
  const float* ew1    = (const float*)d_in[13];
  const float* eb1    = (const float*)d_in[14];
  const float* ew2    = (const float*)d_in[15];
  const float* eb2    = (const float*)d_in[16];
  const float* ln2_g  = (const float*)d_in[17];
  const float* ln2_b  = (const float*)d_in[18];
  const float* head_w = (const float*)d_in[19];
  const float* head_b = (const float*)d_in[20];
  float* out = (float*)d_out;
  char* w = (char*)d_ws;
  if (ws_size < WS_NEEDED) return;

  f16* convw    = (f16*)(w + OFF_CONVW);
  f16* ew1t     = (f16*)(w + OFF_EW1T);
  f16* ew2t     = (f16*)(w + OFF_EW2T);
  f16* headw16  = (f16*)(w + OFF_HEADW16);
  f16* xcls16   = (f16*)(w + OFF_XCLS16);
  float* qvec   = (float*)(w + OFF_Q);
  f16* hcls16   = (f16*)(w + OFF_HCLS16);
  float* maskw  = (float*)(w + OFF_MASKW);
  f16* ehbuf    = (f16*)(w + OFF_EH);
  float* epart  = (float*)(w + OFF_EPART);
  f16* hfin     = (f16*)(w + OFF_HFIN);
  f16* xh       = (f16*)(w + OFF_XH);
  float* Rg     = (float*)(w + OFF_R);
  float* Cg     = (float*)(w + OFF_CVEC);
  f16* u16      = (f16*)(w + OFF_U16);
  f16* o16      = (f16*)(w + OFF_O16);
  f16* wv16     = (f16*)(w + OFF_WV16);
  f16* wout16   = (f16*)(w + OFF_WOUT16);
  float* o2cls  = (float*)(w + OFF_O2CLS);
  float* p32    = (float*)(w + OFF_P32);
  float* sg     = (float*)(w + OFF_SG);
  float* scls   = (float*)(w + OFF_SCLS);

  // ---- weight prep ----
  prep_cast_k<<<dim3(3840), 256, 0, stream>>>(
      conv_w, head_w, inp_w, outp_w, convw, headw16, wv16, wout16);
  transpose_cast_k<<<dim3(48, 12, 4), 256, 0, stream>>>(ew1, ew1t, 384, 1536);
  transpose_cast_k<<<dim3(12, 48, 4), 256, 0, stream>>>(ew2, ew2t, 1536, 384);

  // ---- cls precompute + r_h / cls-score precompute + broadcast ----
  clsprep_k<<<dim3(1), 384, 0, stream>>>(cls_t, pos, ln1_g, ln1_b, inp_w, inp_b, xcls16, qvec);
  rprep_k<<<dim3(6), 384, 0, stream>>>(inp_w, inp_b, qvec, xcls16, Rg, Cg, scls);
  bcast_cls_k<<<dim3(128), 384, 0, stream>>>(xcls16, scls, xh, sg);

  // ---- fused implicit-im2col embed GEMM + LN1 + score epilogue ----
  embed_ln_k<<<dim3(392), 1024, 0, stream>>>(
      x, convw, conv_b, pos, ln1_g, ln1_b, Rg, Cg, xh, sg);

  // ---- softmax -> P32; u-GEMV -> U16; projections ----
  softmax_k<<<dim3(128), 384, 0, stream>>>(sg, p32);
  u_gemv_k<<<dim3(3, 128), 256, 0, stream>>>(p32, xh, u16);
  vproj_k<<<dim3(6), 256, 0, stream>>>(u16, wv16, inp_b, o16);
  oproj_k<<<dim3(6), 256, 0, stream>>>(o16, wout16, outp_b, o2cls);
  ln_router_k<<<dim3(128), 384, 0, stream>>>(
      o2cls, ln1_g, ln1_b, rt_w, rt_b, hcls16, maskw);

  // ---- MoE ----
  moe1_k<<<dim3(24, 4), 256, 0, stream>>>(hcls16, ew1t, eb1, ehbuf);
  moe2_k<<<dim3(6, 4, 4), 256, 0, stream>>>(ehbuf, ew2t, epart);
  combine_ln2_k<<<dim3(128), 384, 0, stream>>>(epart, eb2, maskw, ln2_g, ln2_b, hfin);

  // ---- head ----
  head_gemm_k<<<dim3(8), 256, 0, stream>>>(hfin, headw16, head_b, out);
  (void)in_sizes; (void)n_in; (void)out_size;
}

// Round 7
// 321.677 us; speedup vs baseline: 1.3874x; 1.0709x over previous
//
#include <hip/hip_runtime.h>
#include <cstdint>
#include <cstddef>

typedef _Float16 f16;
typedef _Float16 f16x2 __attribute__((ext_vector_type(2)));
typedef _Float16 f16x8 __attribute__((ext_vector_type(8)));
typedef float    f32x4 __attribute__((ext_vector_type(4)));

// ---------------- problem constants ----------------
constexpr int NTOKC  = 197;
constexpr int TTOK   = 128 * 197;         // 25216
constexpr int EMB    = 384;
constexpr int HID    = 1536;

// ---------------- workspace layout (bytes) ----------------
constexpr size_t OFF_CONVW   = 0;                        // 384*768 f16
constexpr size_t OFF_EW1T    = 1179648;                  // 4*1536*384 f16
constexpr size_t OFF_EW2T    = 5898240;                  // 4*384*1536 f16
constexpr size_t OFF_HEADW16 = 10616832;                 // 1024*384 f16
constexpr size_t OFF_XCLS16  = 11403264;                 // 384 f16
constexpr size_t OFF_Q       = 11404800;                 // 384 f32
constexpr size_t OFF_HCLS16  = 11799552;                 // 128*384 f16
constexpr size_t OFF_MASKW   = 11897856;                 // 128*4 f32
constexpr size_t OFF_EH      = 11899904;                 // 4*128*1536 f16
constexpr size_t OFF_EPART   = 13472768;                 // 4kc*4e*128*384 f32
constexpr size_t OFF_HFIN    = 16618496;                 // 128*384 f16
constexpr size_t OFF_XH      = 16716800;                 // TTOK*384 f16
constexpr size_t OFF_R       = 36082688;                 // 6*384 f32
constexpr size_t OFF_CVEC    = 36094976;                 // 6 f32
constexpr size_t OFF_U16     = 36099072;                 // 128*2304 f16
constexpr size_t OFF_O16     = 36688896;                 // 128*384 f16
constexpr size_t OFF_WV16    = 36787200;                 // 384*384 f16
constexpr size_t OFF_WOUT16  = 37082112;                 // 384*384 f16
constexpr size_t OFF_O2CLS   = 37377024;                 // 128*384 f32
constexpr size_t OFF_P32     = 37573632;                 // 128*6*208 f32
constexpr size_t OFF_SG      = 38212608;                 // 128*6*197 f32
constexpr size_t OFF_SCLS    = 38817792;                 // 6 f32
constexpr size_t WS_NEEDED   = 38818816;                 // ~38.8 MB

// ---------------- global_load_lds helper ----------------
__device__ __forceinline__ void gload16(const void* g, void* l) {
  __builtin_amdgcn_global_load_lds(
      (__attribute__((address_space(1))) void*)(void*)g,
      (__attribute__((address_space(3))) void*)l, 16, 0, 0);
}

// ---------------- prep: all weight casts in one launch ------------
__global__ __launch_bounds__(256) void prep_cast_k(
    const float* __restrict__ conv_w, const float* __restrict__ head_w,
    const float* __restrict__ inp_w, const float* __restrict__ outp_w,
    f16* __restrict__ convw, f16* __restrict__ headw16,
    f16* __restrict__ wv16, f16* __restrict__ wout16) {
  int i = blockIdx.x * 256 + threadIdx.x;
  if (i < 294912) convw[i] = (f16)conv_w[i];
  int j = i - 294912;
  if (j >= 0 && j < 393216) {
    int row = j / 384;
    headw16[j] = (row < 1000) ? (f16)head_w[j] : (f16)0.f;
  }
  int k = i - 688128;
  if (k >= 0 && k < 147456) wv16[k] = (f16)inp_w[294912 + k];
  int l = i - 835584;
  if (l >= 0 && l < 147456) wout16[l] = (f16)outp_w[l];
}

__global__ __launch_bounds__(256) void transpose_cast_k(
    const float* __restrict__ in, f16* __restrict__ outp, int R, int C) {
  __shared__ float tile[32][33];
  int e = blockIdx.z;
  const float* pin = in + (size_t)e * R * C;
  f16* pout = outp + (size_t)e * R * C;
  int c0 = blockIdx.x * 32, r0 = blockIdx.y * 32;
  int tx = threadIdx.x & 31, ty = threadIdx.x >> 5;
#pragma unroll
  for (int i = 0; i < 4; i++)
    tile[ty + 8 * i][tx] = pin[(size_t)(r0 + ty + 8 * i) * C + c0 + tx];
  __syncthreads();
#pragma unroll
  for (int i = 0; i < 4; i++)
    pout[(size_t)(c0 + ty + 8 * i) * R + r0 + tx] = (f16)tile[tx][ty + 8 * i];
}

// ---------------- cls precompute: xcls = LN(cls+pos[0]); q = Wq.xcls + bq ----------
__global__ __launch_bounds__(384) void clsprep_k(
    const float* __restrict__ cls, const float* __restrict__ posw,
    const float* __restrict__ g, const float* __restrict__ bb,
    const float* __restrict__ Wq, const float* __restrict__ bq,
    f16* __restrict__ xcls16, float* __restrict__ qout) {
  __shared__ float xs[EMB];
  __shared__ float red[16];
  int t = threadIdx.x, lane = t & 63, wave = t >> 6;
  float v = cls[t] + posw[t];
  float s = v, sq = v * v;
#pragma unroll
  for (int off = 32; off; off >>= 1) {
    s += __shfl_xor(s, off);
    sq += __shfl_xor(sq, off);
  }
  if (lane == 0) { red[wave] = s; red[8 + wave] = sq; }
  __syncthreads();
  float S = 0.f, SQ = 0.f;
#pragma unroll
  for (int i = 0; i < 6; i++) { S += red[i]; SQ += red[8 + i]; }
  float m = S * (1.f / 384.f);
  float rs = rsqrtf(SQ * (1.f / 384.f) - m * m + 1e-5f);
  float y = (v - m) * rs * g[t] + bb[t];
  xs[t] = y;
  xcls16[t] = (f16)y;
  __syncthreads();
  const float4* w4 = (const float4*)(Wq + (size_t)t * EMB);
  const float4* s4 = (const float4*)xs;
  float a = bq[t];
#pragma unroll 8
  for (int i = 0; i < 96; i++) {
    float4 xx = s4[i], ww = w4[i];
    a += xx.x * ww.x + xx.y * ww.y + xx.z * ww.z + xx.w * ww.w;
  }
  qout[t] = a;
}

// ---------------- R precompute: r_h = Wk_h^T q_h, c_h = q_h.bk_h,
//                  Scls_h = xcls . r_h + c_h  (batch-independent) -------------
__global__ __launch_bounds__(384) void rprep_k(
    const float* __restrict__ inp_w, const float* __restrict__ inp_b,
    const float* __restrict__ qv, const f16* __restrict__ xcls16,
    float* __restrict__ Rg, float* __restrict__ Cg, float* __restrict__ Scls) {
  int h = blockIdx.x, t = threadIdx.x;
  __shared__ float qs[64];
  __shared__ float cred[64];
  __shared__ float sred[6];
  if (t < 64) {
    float q = qv[h * 64 + t];
    qs[t] = q;
    cred[t] = q * inp_b[384 + h * 64 + t];
  }
  __syncthreads();
  const float* wp = inp_w + ((size_t)(384 + h * 64)) * 384 + t;
  float a = 0.f;
#pragma unroll 8
  for (int d = 0; d < 64; d++) a += wp[(size_t)d * 384] * qs[d];
  Rg[h * 384 + t] = a;
  // cls-score partial: Rg[h][t] * xcls[t]
  float part = a * (float)xcls16[t];
  int lane = t & 63, wave = t >> 6;
#pragma unroll
  for (int off = 32; off; off >>= 1) part += __shfl_xor(part, off);
  if (lane == 0) sred[wave] = part;
  __syncthreads();
  if (t == 0) {
    float c = 0.f;
    for (int d = 0; d < 64; d++) c += cred[d];
    Cg[h] = c;
    float stot = c;
#pragma unroll
    for (int i = 0; i < 6; i++) stot += sred[i];
    Scls[h] = stot;
  }
}

// ---------------- broadcast cls row into xh; splat cls score into Sg ----------
__global__ __launch_bounds__(384) void bcast_cls_k(
    const f16* __restrict__ xcls16, const float* __restrict__ Scls,
    f16* __restrict__ xh, float* __restrict__ Sg) {
  int b = blockIdx.x, t = threadIdx.x;
  xh[(size_t)b * NTOKC * EMB + t] = xcls16[t];
  if (t < 6) Sg[((size_t)b * 6 + t) * 197] = Scls[t];
}

// ---------------- fused IMPLICIT-im2col patch-embed GEMM + bias + pos + LN1
//                  + score epilogue.  Double-buffered single-barrier K-loop. ----
__global__ __launch_bounds__(1024) void embed_ln_k(
    const float* __restrict__ img, const f16* __restrict__ B,
    const float* __restrict__ bias, const float* __restrict__ posw,
    const float* __restrict__ g, const float* __restrict__ bb,
    const float* __restrict__ Rg, const float* __restrict__ Cg,
    f16* __restrict__ xh, float* __restrict__ Sg) {
  // staging: As dbuf 2x(64*32 f16)=8KB, Bs dbuf 2x(384*32 f16)=48KB  -> 56KB
  // epilogue arrays alias the same storage after the K-loop.
  __shared__ __attribute__((aligned(16))) char smem[57344];
  f16* As0 = (f16*)smem;
  f16* As1 = (f16*)(smem + 4096);
  f16* Bs0 = (f16*)(smem + 8192);
  f16* Bs1 = (f16*)(smem + 32768);
  const int K = 768;
  const int NT = 24;                 // K/32
  const int tid = threadIdx.x;
  const int lane = tid & 63;
  const int wave = tid >> 6;        // 0..15
  const int rowgrp = wave & 3;
  const int colgrp = wave >> 2;
  const int m0 = (int)blockIdx.x * 64;
  const int fr = lane & 15;
  const int fq = lane >> 4;

  f32x4 acc[6];
#pragma unroll
  for (int j = 0; j < 6; j++) acc[j] = f32x4{0.f, 0.f, 0.f, 0.f};

  const int sr = lane >> 2, sc = (lane & 3) * 8;
  // ---- A-staging lane constants (waves 0..3, implicit im2col) ----
  const float* abase = nullptr;
  int adoff = 0;
  if (wave < 4) {
    int row = m0 + wave * 16 + sr;          // patch index 0..25087
    int bimg = row / 196;
    int pp = row - bimg * 196;
    int py = pp / 14, px = pp - py * 14;
    int kx0 = sc & 15;                      // 0 or 8
    abase = img + ((size_t)(bimg * 3) * 224 + py * 16) * 224 + px * 16 + kx0;
    adoff = (wave * 16 + sr) * 32 + sc;
  }
  // ---- B-staging lane constants (waves 4..15) ----
  const f16* gb0 = nullptr;
  int lboff = 0;
  if (wave >= 4) {
    int brow = (wave - 4) * 32;
    gb0 = B + (size_t)(brow + sr) * K + sc;
    lboff = brow * 32;
  }

  // ---- prologue: stage step 0 into buf0; prefetch step 1 into regs ----
  float4 n0, n1;
  if (wave < 4) {
    {
      int col = sc;                         // step 0
      const float* src = abase + (col >> 8) * 50176 + ((col >> 4) & 15) * 224;
      float4 p0 = *(const float4*)src;
      float4 p1 = *(const float4*)(src + 4);
      f16x8 hv;
      hv[0] = (f16)p0.x; hv[1] = (f16)p0.y; hv[2] = (f16)p0.z; hv[3] = (f16)p0.w;
      hv[4] = (f16)p1.x; hv[5] = (f16)p1.y; hv[6] = (f16)p1.z; hv[7] = (f16)p1.w;
      *(f16x8*)(As0 + adoff) = hv;
    }
    {
      int col = 32 + sc;                    // step 1 prefetch
      const float* src = abase + (col >> 8) * 50176 + ((col >> 4) & 15) * 224;
      n0 = *(const float4*)src;
      n1 = *(const float4*)(src + 4);
    }
  } else {
    gload16(gb0, Bs0 + lboff);
    gload16(gb0 + (size_t)16 * K, Bs0 + lboff + 16 * 32);
    gb0 += 32;
  }
  __syncthreads();

  f16* AsC = As0; f16* AsN = As1;
  f16* BsC = Bs0; f16* BsN = Bs1;

  for (int t = 0; t < NT; ++t) {
    if (wave < 4) {
      if (t + 1 < NT) {
        f16x8 hv;
        hv[0] = (f16)n0.x; hv[1] = (f16)n0.y; hv[2] = (f16)n0.z; hv[3] = (f16)n0.w;
        hv[4] = (f16)n1.x; hv[5] = (f16)n1.y; hv[6] = (f16)n1.z; hv[7] = (f16)n1.w;
        *(f16x8*)(AsN + adoff) = hv;
      }
      if (t + 2 < NT) {
        int col = (t + 2) * 32 + sc;
        const float* src = abase + (col >> 8) * 50176 + ((col >> 4) & 15) * 224;
        n0 = *(const float4*)src;
        n1 = *(const float4*)(src + 4);
      }
    } else {
      if (t + 1 < NT) {
        gload16(gb0, BsN + lboff);
        gload16(gb0 + (size_t)16 * K, BsN + lboff + 16 * 32);
        gb0 += 32;
      }
    }
    f16x8 af = *(const f16x8*)&AsC[(rowgrp * 16 + fr) * 32 + fq * 8];
#pragma unroll
    for (int j = 0; j < 6; j++) {
      f16x8 bf = *(const f16x8*)&BsC[(colgrp * 96 + j * 16 + fr) * 32 + fq * 8];
      acc[j] = __builtin_amdgcn_mfma_f32_16x16x32_f16(af, bf, acc[j], 0, 0, 0);
    }
    __syncthreads();
    f16* tA = AsC; AsC = AsN; AsN = tA;
    f16* tB = BsC; BsC = BsN; BsN = tB;
  }

  // ---- epilogue LDS (aliases staging storage; loop's final barrier passed) ----
  float* prm   = (float*)smem;              // 1152 f32: bias | gamma | beta
  float* psum  = (float*)(smem + 4608);     // 256 f32
  float* pqsum = (float*)(smem + 5632);     // 256 f32
  float* Rs2   = (float*)(smem + 6656);     // 2304 f32
  float* psc   = (float*)(smem + 15872);    // 1536 f32
  for (int i = tid; i < 1152; i += 1024)
    prm[i] = (i < 384) ? bias[i] : ((i < 768) ? g[i - 384] : bb[i - 768]);
  for (int i = tid; i < 2304; i += 1024) Rs2[i] = Rg[i];
  __syncthreads();

  // ---- epilogue 1: bias+pos, LN partial sums ----
  float v[4][6];
#pragma unroll
  for (int rg = 0; rg < 4; rg++) {
    int lrow = rowgrp * 16 + fq * 4 + rg;
    int row = m0 + lrow;
    int bimg = row / 196;
    int pp = row - bimg * 196;
    const float* prow = posw + (size_t)(pp + 1) * EMB;
    float s = 0.f, sq = 0.f;
#pragma unroll
    for (int j = 0; j < 6; j++) {
      int col = colgrp * 96 + j * 16 + fr;
      float t = acc[j][rg] + prm[col] + prow[col];
      v[rg][j] = t;
      s += t; sq += t * t;
    }
#pragma unroll
    for (int off = 1; off < 16; off <<= 1) {
      s += __shfl_xor(s, off);
      sq += __shfl_xor(sq, off);
    }
    if (fr == 0) { psum[lrow * 4 + colgrp] = s; pqsum[lrow * 4 + colgrp] = sq; }
  }
  __syncthreads();

  // ---- epilogue 2: LN normalize -> y (kept in v), store xh f16 ----
#pragma unroll
  for (int rg = 0; rg < 4; rg++) {
    int lrow = rowgrp * 16 + fq * 4 + rg;
    float S = psum[lrow * 4] + psum[lrow * 4 + 1] + psum[lrow * 4 + 2] + psum[lrow * 4 + 3];
    float SQ = pqsum[lrow * 4] + pqsum[lrow * 4 + 1] + pqsum[lrow * 4 + 2] + pqsum[lrow * 4 + 3];
    float m = S * (1.f / 384.f);
    float rs = rsqrtf(SQ * (1.f / 384.f) - m * m + 1e-5f);
    int row = m0 + lrow;
    int bimg = row / 196;
    int pp = row - bimg * 196;
    f16* orow = xh + ((size_t)bimg * NTOKC + pp + 1) * EMB;
#pragma unroll
    for (int j = 0; j < 6; j++) {
      int col = colgrp * 96 + j * 16 + fr;
      float y = (v[rg][j] - m) * rs * prm[384 + col] + prm[768 + col];
      v[rg][j] = y;
      orow[col] = (f16)y;
    }
  }

  // ---- epilogue 3: score partials p[row][h] = sum_col y*r_h ----
#pragma unroll
  for (int h = 0; h < 6; h++) {
    float rv[6];
#pragma unroll
    for (int j = 0; j < 6; j++)
      rv[j] = Rs2[h * 384 + colgrp * 96 + j * 16 + fr];
#pragma unroll
    for (int rg = 0; rg < 4; rg++) {
      float p = v[rg][0] * rv[0] + v[rg][1] * rv[1] + v[rg][2] * rv[2]
              + v[rg][3] * rv[3] + v[rg][4] * rv[4] + v[rg][5] * rv[5];
#pragma unroll
      for (int off = 1; off < 16; off <<= 1) p += __shfl_xor(p, off);
      if (fr == 0) psc[(rowgrp * 16 + fq * 4 + rg) * 24 + colgrp * 6 + h] = p;
    }
  }
  __syncthreads();
  if (tid < 384) {
    int lrow = tid / 6, h = tid - lrow * 6;
    float s = psc[lrow * 24 + h] + psc[lrow * 24 + 6 + h]
            + psc[lrow * 24 + 12 + h] + psc[lrow * 24 + 18 + h] + Cg[h];
    int row = m0 + lrow;
    int bimg = row / 196, pp = row - bimg * 196;
    Sg[((size_t)bimg * 6 + h) * 197 + pp + 1] = s;
  }
}

// ---------------- softmax over Sg -> normalized P32[b][6][208] -----------------
// grid 128 x 384 (6 waves, one head each).
__global__ __launch_bounds__(384) void softmax_k(
    const float* __restrict__ Sg, float* __restrict__ P32) {
  const int b = blockIdx.x, tid = threadIdx.x;
  const int wave = tid >> 6, lane = tid & 63;
  const float* sp = Sg + ((size_t)b * 6 + wave) * 197;
  float z[4], pk[4];
#pragma unroll
  for (int k = 0; k < 4; k++) {
    int t = lane + 64 * k;
    z[k] = (t < 197) ? sp[t] * 0.125f : -1e30f;
    pk[k] = 0.f;
  }
  float mx = fmaxf(fmaxf(z[0], z[1]), fmaxf(z[2], z[3]));
#pragma unroll
  for (int off = 32; off; off >>= 1) mx = fmaxf(mx, __shfl_xor(mx, off));
  float sum = 0.f;
#pragma unroll
  for (int k = 0; k < 4; k++) {
    int t = lane + 64 * k;
    if (t < 197) {
      pk[k] = __expf(z[k] - mx);
      sum += pk[k];
    }
  }
#pragma unroll
  for (int off = 32; off; off >>= 1) sum += __shfl_xor(sum, off);
  float si = 1.f / sum;
#pragma unroll
  for (int k = 0; k < 4; k++) {
    int t = lane + 64 * k;
    if (t < 208) P32[(size_t)b * 1248 + wave * 208 + t] = pk[k] * si;
  }
}

// ---------------- u[b][h][col] = sum_t P[b][h][t] * xh[b][t][col] -> U16 ---------
__global__ __launch_bounds__(256) void u_gemv_k(
    const float* __restrict__ P32, const f16* __restrict__ xh,
    f16* __restrict__ U16) {
  __shared__ float pf[6 * 208];        // 4992 B
  __shared__ float part[4][64][12];    // 12 KB
  const int cq = (int)blockIdx.x;      // 0..2
  const int b  = (int)blockIdx.y;
  const int tid = threadIdx.x;
  for (int i = tid; i < 1248; i += 256) pf[i] = P32[(size_t)b * 1248 + i];
  __syncthreads();
  const int cp = tid & 63;
  const int tq = tid >> 6;
  const int col0 = cq * 128 + cp * 2;
  const int t0 = 49 * tq;
  const int t1 = (tq == 3) ? 197 : t0 + 49;
  float acc[12];
#pragma unroll
  for (int r = 0; r < 12; r++) acc[r] = 0.f;
  const f16* xp = xh + ((size_t)b * NTOKC + t0) * EMB + col0;
#pragma unroll 2
  for (int t = t0; t < t1; t++) {
    f16x2 xv = *(const f16x2*)xp;
    float x0 = (float)xv[0];
    float x1 = (float)xv[1];
    xp += EMB;
#pragma unroll
    for (int h = 0; h < 6; h++) {
      float p = pf[h * 208 + t];
      acc[h * 2]     += p * x0;
      acc[h * 2 + 1] += p * x1;
    }
  }
#pragma unroll
  for (int r = 0; r < 12; r++) part[tq][cp][r] = acc[r];
  __syncthreads();
#pragma unroll
  for (int k = 0; k < 3; k++) {
    int idx = tid + k * 256;            // 0..767
    int cp2 = idx / 12, slot = idx - cp2 * 12;
    int h = slot >> 1, c01 = slot & 1;
    float u = part[0][cp2][slot] + part[1][cp2][slot] +
              part[2][cp2][slot] + part[3][cp2][slot];
    U16[(size_t)b * 2304 + h * 384 + cq * 128 + cp2 * 2 + c01] = (f16)u;
  }
}

// ---------------- V-projection GEMM: o[b][h*64+n] = Wv_h[n,:].u[b][h] + bv ------
__global__ __launch_bounds__(256) void vproj_k(
    const f16* __restrict__ U16, const f16* __restrict__ wv16,
    const float* __restrict__ inp_b, f16* __restrict__ O16) {
  __shared__ f16 As[128 * 32];
  __shared__ f16 Bs[64 * 32];
  const int tid = threadIdx.x;
  const int lane = tid & 63;
  const int wave = tid >> 6;
  const int h = (int)blockIdx.x;
  const int wm = (wave >> 1) * 64;
  const int wn = (wave & 1) * 32;
  const int fr = lane & 15;
  const int fq = lane >> 4;
  const float* bv = inp_b + 768 + h * 64;

  f32x4 acc[4][2];
#pragma unroll
  for (int i = 0; i < 4; i++)
#pragma unroll
    for (int j = 0; j < 2; j++) acc[i][j] = f32x4{0.f, 0.f, 0.f, 0.f};

  const int sr = lane >> 2;
  const int sc = (lane & 3) * 8;
  const f16* ag = U16 + (size_t)(wave * 32 + sr) * 2304 + h * 384 + sc;
  const f16* bg = wv16 + (size_t)(h * 64 + wave * 16 + sr) * 384 + sc;
  const size_t rstepA = (size_t)16 * 2304;
  f16* la = As + wave * 32 * 32;
  f16* lb = Bs + wave * 16 * 32;

  for (int k0 = 0; k0 < 384; k0 += 32) {
    gload16(ag, la);  gload16(ag + rstepA, la + 16 * 32);
    gload16(bg, lb);
    ag += 32; bg += 32;
    __syncthreads();
    f16x8 af[4], bf[2];
#pragma unroll
    for (int i = 0; i < 4; i++)
      af[i] = *(const f16x8*)&As[(wm + i * 16 + fr) * 32 + fq * 8];
#pragma unroll
    for (int j = 0; j < 2; j++)
      bf[j] = *(const f16x8*)&Bs[(wn + j * 16 + fr) * 32 + fq * 8];
#pragma unroll
    for (int i = 0; i < 4; i++)
#pragma unroll
      for (int j = 0; j < 2; j++)
        acc[i][j] = __builtin_amdgcn_mfma_f32_16x16x32_f16(af[i], bf[j], acc[i][j], 0, 0, 0);
    __syncthreads();
  }

#pragma unroll
  for (int i = 0; i < 4; i++)
#pragma unroll
    for (int j = 0; j < 2; j++)
#pragma unroll
      for (int rg = 0; rg < 4; rg++) {
        int gm = wm + i * 16 + fq * 4 + rg;
        int gn = wn + j * 16 + fr;
        O16[(size_t)gm * EMB + h * 64 + gn] = (f16)(acc[i][j][rg] + bv[gn]);
      }
}

// ---------------- out-projection GEMM: o2 = Wout.o + bout (f32 out) -------------
__global__ __launch_bounds__(256) void oproj_k(
    const f16* __restrict__ O16, const f16* __restrict__ wout16,
    const float* __restrict__ bout, float* __restrict__ o2cls) {
  __shared__ f16 As[128 * 32];
  __shared__ f16 Bs[64 * 32];
  const int tid = threadIdx.x;
  const int lane = tid & 63;
  const int wave = tid >> 6;
  const int n0 = (int)blockIdx.x * 64;
  const int wm = (wave >> 1) * 64;
  const int wn = (wave & 1) * 32;
  const int fr = lane & 15;
  const int fq = lane >> 4;

  f32x4 acc[4][2];
#pragma unroll
  for (int i = 0; i < 4; i++)
#pragma unroll
    for (int j = 0; j < 2; j++) acc[i][j] = f32x4{0.f, 0.f, 0.f, 0.f};

  const int sr = lane >> 2;
  const int sc = (lane & 3) * 8;
  const f16* ag = O16 + (size_t)(wave * 32 + sr) * 384 + sc;
  const f16* bg = wout16 + (size_t)(n0 + wave * 16 + sr) * 384 + sc;
  const size_t rstep = (size_t)16 * 384;
  f16* la = As + wave * 32 * 32;
  f16* lb = Bs + wave * 16 * 32;

  for (int k0 = 0; k0 < 384; k0 += 32) {
    gload16(ag, la);  gload16(ag + rstep, la + 16 * 32);
    gload16(bg, lb);
    ag += 32; bg += 32;
    __syncthreads();
    f16x8 af[4], bf[2];
#pragma unroll
    for (int i = 0; i < 4; i++)
      af[i] = *(const f16x8*)&As[(wm + i * 16 + fr) * 32 + fq * 8];
#pragma unroll
    for (int j = 0; j < 2; j++)
      bf[j] = *(const f16x8*)&Bs[(wn + j * 16 + fr) * 32 + fq * 8];
#pragma unroll
    for (int i = 0; i < 4; i++)
#pragma unroll
      for (int j = 0; j < 2; j++)
        acc[i][j] = __builtin_amdgcn_mfma_f32_16x16x32_f16(af[i], bf[j], acc[i][j], 0, 0, 0);
    __syncthreads();
  }

#pragma unroll
  for (int i = 0; i < 4; i++)
#pragma unroll
    for (int j = 0; j < 2; j++)
#pragma unroll
      for (int rg = 0; rg < 4; rg++) {
        int gm = wm + i * 16 + fq * 4 + rg;
        int gn = n0 + wn + j * 16 + fr;
        o2cls[(size_t)gm * EMB + gn] = acc[i][j][rg] + bout[gn];
      }
}

// ---------------- fused LN (ln1 params) + router top-2 ----------------
__global__ __launch_bounds__(384) void ln_router_k(
    const float* __restrict__ o2cls, const float* __restrict__ g, const float* __restrict__ bb,
    const float* __restrict__ rw, const float* __restrict__ rb,
    f16* __restrict__ hcls16, float* __restrict__ maskw) {
  __shared__ float red[16];
  __shared__ float part[6][4];
  __shared__ float logits[4];
  int b = blockIdx.x, t = threadIdx.x;
  int lane = t & 63, wave = t >> 6;
  float v = o2cls[(size_t)b * EMB + t];
  float s = v, sq = v * v;
#pragma unroll
  for (int off = 32; off; off >>= 1) {
    s += __shfl_xor(s, off);
    sq += __shfl_xor(sq, off);
  }
  if (lane == 0) { red[wave] = s; red[8 + wave] = sq; }
  __syncthreads();
  float S = 0.f, SQ = 0.f;
#pragma unroll
  for (int i = 0; i < 6; i++) { S += red[i]; SQ += red[8 + i]; }
  float m = S * (1.f / 384.f);
  float rs = rsqrtf(SQ * (1.f / 384.f) - m * m + 1e-5f);
  float y = (v - m) * rs * g[t] + bb[t];
  hcls16[(size_t)b * EMB + t] = (f16)y;
  float p0 = y * rw[t];
  float p1 = y * rw[EMB + t];
  float p2 = y * rw[2 * EMB + t];
  float p3 = y * rw[3 * EMB + t];
#pragma unroll
  for (int off = 32; off; off >>= 1) {
    p0 += __shfl_xor(p0, off);
    p1 += __shfl_xor(p1, off);
    p2 += __shfl_xor(p2, off);
    p3 += __shfl_xor(p3, off);
  }
  if (lane == 0) { part[wave][0] = p0; part[wave][1] = p1; part[wave][2] = p2; part[wave][3] = p3; }
  __syncthreads();
  if (t < 4) {
    float a = rb[t];
#pragma unroll
    for (int i = 0; i < 6; i++) a += part[i][t];
    logits[t] = a;
  }
  __syncthreads();
  if (t == 0) {
    float l0 = logits[0], l1 = logits[1], l2 = logits[2], l3 = logits[3];
    int i1 = 0; float b1 = l0;
    if (l1 > b1) { b1 = l1; i1 = 1; }
    if (l2 > b1) { b1 = l2; i1 = 2; }
    if (l3 > b1) { b1 = l3; i1 = 3; }
    int i2 = -1; float b2 = 0.f;
    float lv[4] = {l0, l1, l2, l3};
#pragma unroll
    for (int i = 0; i < 4; i++) {
      if (i == i1) continue;
      if (i2 < 0 || lv[i] > b2) { i2 = i; b2 = lv[i]; }
    }
#pragma unroll
    for (int e = 0; e < 4; e++)
      maskw[(size_t)b * 4 + e] = (e == i1 || e == i2) ? 0.5f : 0.f;
  }
}

// ---------------- MoE GEMM1: hcls16[128x384] @ ew1t^T + GELU -> ehbuf f16 ---------
__global__ __launch_bounds__(256) void moe1_k(
    const f16* __restrict__ A, const f16* __restrict__ Bm,
    const float* __restrict__ bias, f16* __restrict__ outh) {
  __shared__ f16 As[128 * 32];
  __shared__ f16 Bs[64 * 32];
  const int K = EMB;
  const int tid = threadIdx.x;
  const int lane = tid & 63;
  const int wave = tid >> 6;
  const int e = (int)blockIdx.y;
  const int n0 = (int)blockIdx.x * 64;
  const int wm = (wave >> 1) * 64;
  const int wn = (wave & 1) * 32;
  const int fr = lane & 15;
  const int fq = lane >> 4;
  Bm += (size_t)e * HID * EMB;
  bias += (size_t)e * HID;

  f32x4 acc[4][2];
#pragma unroll
  for (int i = 0; i < 4; i++)
#pragma unroll
    for (int j = 0; j < 2; j++) acc[i][j] = f32x4{0.f, 0.f, 0.f, 0.f};

  const int sr = lane >> 2;
  const int sc = (lane & 3) * 8;
  const f16* ag = A + (size_t)(wave * 32 + sr) * K + sc;
  const f16* bg = Bm + (size_t)(n0 + wave * 16 + sr) * K + sc;
  const size_t rstep = (size_t)16 * K;
  f16* la = As + wave * 32 * 32;
  f16* lb = Bs + wave * 16 * 32;

  for (int k0 = 0; k0 < K; k0 += 32) {
    gload16(ag, la);  gload16(ag + rstep, la + 16 * 32);
    gload16(bg, lb);
    ag += 32; bg += 32;
    __syncthreads();
    f16x8 af[4], bf[2];
#pragma unroll
    for (int i = 0; i < 4; i++)
      af[i] = *(const f16x8*)&As[(wm + i * 16 + fr) * 32 + fq * 8];
#pragma unroll
    for (int j = 0; j < 2; j++)
      bf[j] = *(const f16x8*)&Bs[(wn + j * 16 + fr) * 32 + fq * 8];
#pragma unroll
    for (int i = 0; i < 4; i++)
#pragma unroll
      for (int j = 0; j < 2; j++)
        acc[i][j] = __builtin_amdgcn_mfma_f32_16x16x32_f16(af[i], bf[j], acc[i][j], 0, 0, 0);
    __syncthreads();
  }

#pragma unroll
  for (int i = 0; i < 4; i++)
#pragma unroll
    for (int j = 0; j < 2; j++)
#pragma unroll
      for (int rg = 0; rg < 4; rg++) {
        int gm = wm + i * 16 + fq * 4 + rg;
        int gn = n0 + wn + j * 16 + fr;
        float v = acc[i][j][rg] + bias[gn];
        float gl = 0.5f * v * (1.0f + erff(v * 0.70710678118654752f));
        outh[(size_t)e * 128 * HID + (size_t)gm * HID + gn] = (f16)gl;
      }
}

// ---------------- MoE GEMM2 split-K ----------------
__global__ __launch_bounds__(256) void moe2_k(
    const f16* __restrict__ EH, const f16* __restrict__ W2,
    float* __restrict__ part) {
  __shared__ f16 As[128 * 32];
  __shared__ f16 Bs[64 * 32];
  const int tid = threadIdx.x;
  const int lane = tid & 63;
  const int wave = tid >> 6;
  const int n0 = (int)blockIdx.x * 64;
  const int e = (int)blockIdx.y;
  const int kc = (int)blockIdx.z;
  const int wm = (wave >> 1) * 64;
  const int wn = (wave & 1) * 32;
  const int fr = lane & 15;
  const int fq = lane >> 4;
  const f16* A = EH + (size_t)e * 128 * HID + kc * 384;
  const f16* B = W2 + (size_t)e * EMB * HID + kc * 384;

  f32x4 acc[4][2];
#pragma unroll
  for (int i = 0; i < 4; i++)
#pragma unroll
    for (int j = 0; j < 2; j++) acc[i][j] = f32x4{0.f, 0.f, 0.f, 0.f};

  const int sr = lane >> 2;
  const int sc = (lane & 3) * 8;
  const f16* ag = A + (size_t)(wave * 32 + sr) * HID + sc;
  const f16* bg = B + (size_t)(n0 + wave * 16 + sr) * HID + sc;
  const size_t rstep = (size_t)16 * HID;
  f16* la = As + wave * 32 * 32;
  f16* lb = Bs + wave * 16 * 32;

  for (int k0 = 0; k0 < 384; k0 += 32) {
    gload16(ag, la);  gload16(ag + rstep, la + 16 * 32);
    gload16(bg, lb);
    ag += 32; bg += 32;
    __syncthreads();
    f16x8 af[4], bf[2];
#pragma unroll
    for (int i = 0; i < 4; i++)
      af[i] = *(const f16x8*)&As[(wm + i * 16 + fr) * 32 + fq * 8];
#pragma unroll
    for (int j = 0; j < 2; j++)
      bf[j] = *(const f16x8*)&Bs[(wn + j * 16 + fr) * 32 + fq * 8];
#pragma unroll
    for (int i = 0; i < 4; i++)
#pragma unroll
      for (int j = 0; j < 2; j++)
        acc[i][j] = __builtin_amdgcn_mfma_f32_16x16x32_f16(af[i], bf[j], acc[i][j], 0, 0, 0);
    __syncthreads();
  }

#pragma unroll
  for (int i = 0; i < 4; i++)
#pragma unroll
    for (int j = 0; j < 2; j++)
#pragma unroll
      for (int rg = 0; rg < 4; rg++) {
        int gm = wm + i * 16 + fq * 4 + rg;
        int gn = n0 + wn + j * 16 + fr;
        part[(((size_t)kc * 4 + e) * 128 + gm) * EMB + gn] = acc[i][j][rg];
      }
}

// ---------------- combine split-K + experts + LN2 -> f16 ----------------
__global__ __launch_bounds__(384) void combine_ln2_k(
    const float* __restrict__ part, const float* __restrict__ eb2,
    const float* __restrict__ maskw,
    const float* __restrict__ g, const float* __restrict__ bb,
    f16* __restrict__ hfin) {
  __shared__ float red[16];
  int b = blockIdx.x, t = threadIdx.x;
  int lane = t & 63, wave = t >> 6;
  float v = 0.f;
#pragma unroll
  for (int e = 0; e < 4; e++) {
    float s = eb2[e * EMB + t];
#pragma unroll
    for (int kc = 0; kc < 4; kc++)
      s += part[(((size_t)kc * 4 + e) * 128 + b) * EMB + t];
    v += maskw[b * 4 + e] * s;
  }
  float s = v, sq = v * v;
#pragma unroll
  for (int off = 32; off; off >>= 1) {
    s += __shfl_xor(s, off);
    sq += __shfl_xor(sq, off);
  }
  if (lane == 0) { red[wave] = s; red[8 + wave] = sq; }
  __syncthreads();
  float S = 0.f, SQ = 0.f;
#pragma unroll
  for (int i = 0; i < 6; i++) { S += red[i]; SQ += red[8 + i]; }
  float m = S * (1.f / 384.f);
  float rs = rsqrtf(SQ * (1.f / 384.f) - m * m + 1e-5f);
  hfin[(size_t)b * EMB + t] = (f16)((v - m) * rs * g[t] + bb[t]);
}

// ---------------- head GEMM ----------------
__global__ __launch_bounds__(256) void head_gemm_k(
    const f16* __restrict__ A, const f16* __restrict__ B,
    const float* __restrict__ hb, float* __restrict__ outp) {
  __shared__ f16 As[128 * 32];
  __shared__ f16 Bs[128 * 32];
  const int K = 384;
  const int tid = threadIdx.x;
  const int lane = tid & 63;
  const int wave = tid >> 6;
  const int n0 = (int)blockIdx.x * 128;
  const int wm = (wave >> 1) * 64;
  const int wn = (wave & 1) * 64;
  const int fr = lane & 15;
  const int fq = lane >> 4;

  f32x4 acc[4][4];
#pragma unroll
  for (int i = 0; i < 4; i++)
#pragma unroll
    for (int j = 0; j < 4; j++) acc[i][j] = f32x4{0.f, 0.f, 0.f, 0.f};

  const int srow = wave * 32 + (lane >> 2);
  const int scol = (lane & 3) * 8;
  const f16* ag = A + (size_t)srow * K + scol;
  const f16* bg = B + (size_t)(n0 + srow) * K + scol;
  const size_t rstep = (size_t)16 * K;
  f16* la = As + wave * 32 * 32;
  f16* lb = Bs + wave * 32 * 32;

  for (int k0 = 0; k0 < K; k0 += 32) {
    gload16(ag, la);          gload16(ag + rstep, la + 16 * 32);
    gload16(bg, lb);          gload16(bg + rstep, lb + 16 * 32);
    ag += 32; bg += 32;
    __syncthreads();
    f16x8 af[4], bf[4];
#pragma unroll
    for (int i = 0; i < 4; i++) {
      af[i] = *(const f16x8*)&As[(wm + i * 16 + fr) * 32 + fq * 8];
      bf[i] = *(const f16x8*)&Bs[(wn + i * 16 + fr) * 32 + fq * 8];
    }
#pragma unroll
    for (int i = 0; i < 4; i++)
#pragma unroll
      for (int j = 0; j < 4; j++)
        acc[i][j] = __builtin_amdgcn_mfma_f32_16x16x32_f16(af[i], bf[j], acc[i][j], 0, 0, 0);
    __syncthreads();
  }

#pragma unroll
  for (int i = 0; i < 4; i++)
#pragma unroll
    for (int j = 0; j < 4; j++)
#pragma unroll
      for (int rg = 0; rg < 4; rg++) {
        int gm = wm + i * 16 + fq * 4 + rg;
        int gn = n0 + wn + j * 16 + fr;
        if (gn < 1000)
          outp[(size_t)gm * 1000 + gn] = acc[i][j][rg] + hb[gn];
      }
}

// ---------------- host ----------------
extern "C" void kernel_launch(void* const* d_in, const int* in_sizes, int n_in,
                              void* d_out, int out_size, void* d_ws, size_t ws_size,
                              hipStream_t stream) {
  const float* x      = (const float*)d_in[0];
  const float* conv_w = (const float*)d_in[1];
  const float* conv_b = (const float*)d_in[2];
  const float* cls_t  = (const float*)d_in[3];
  const float* pos    = (const float*)d_in[4];
  const float* ln1_g  = (const float*)d_in[5];
  const float* ln1_b  = (const float*)d_in[6];
  const float* inp_w  = (const float*)d_in[7];
  const float* inp_b  = (const float*)d_in[8];
  const float* outp_w = (const float*)d_in[9];
  const float* outp_b = (const float*)d_in[10];
  const float* rt_w   = (const float*)d_in[11];
  const float* rt_b   = (const float*)d_in[12];
  const float* ew1    = (const float*)d_in[13];
  const float* eb1    = (const float*)d_in[14];
  const float* ew2    = (const float*)d_in[15];
  const float* eb2    = (const float*)d_in[16];
  const float* ln2_g  = (const float*)d_in[17];
  const float* ln2_b  = (const float*)d_in[18];
  const float* head_w = (const float*)d_in[19];
  const float* head_b = (const float*)d_in[20];
  float* out = (float*)d_out;
  char* w = (char*)d_ws;
  if (ws_size < WS_NEEDED) return;

  f16* convw    = (f16*)(w + OFF_CONVW);
  f16* ew1t     = (f16*)(w + OFF_EW1T);
  f16* ew2t     = (f16*)(w + OFF_EW2T);
  f16* headw16  = (f16*)(w + OFF_HEADW16);
  f16* xcls16   = (f16*)(w + OFF_XCLS16);
  float* qvec   = (float*)(w + OFF_Q);
  f16* hcls16   = (f16*)(w + OFF_HCLS16);
  float* maskw  = (float*)(w + OFF_MASKW);
  f16* ehbuf    = (f16*)(w + OFF_EH);
  float* epart  = (float*)(w + OFF_EPART);
  f16* hfin     = (f16*)(w + OFF_HFIN);
  f16* xh       = (f16*)(w + OFF_XH);
  float* Rg     = (float*)(w + OFF_R);
  float* Cg     = (float*)(w + OFF_CVEC);
  f16* u16      = (f16*)(w + OFF_U16);
  f16* o16      = (f16*)(w + OFF_O16);
  f16* wv16     = (f16*)(w + OFF_WV16);
  f16* wout16   = (f16*)(w + OFF_WOUT16);
  float* o2cls  = (float*)(w + OFF_O2CLS);
  float* p32    = (float*)(w + OFF_P32);
  float* sg     = (float*)(w + OFF_SG);
  float* scls   = (float*)(w + OFF_SCLS);

  // ---- weight prep ----
  prep_cast_k<<<dim3(3840), 256, 0, stream>>>(
      conv_w, head_w, inp_w, outp_w, convw, headw16, wv16, wout16);
  transpose_cast_k<<<dim3(48, 12, 4), 256, 0, stream>>>(ew1, ew1t, 384, 1536);
  transpose_cast_k<<<dim3(12, 48, 4), 256, 0, stream>>>(ew2, ew2t, 1536, 384);

  // ---- cls precompute + r_h / cls-score precompute + broadcast ----
  clsprep_k<<<dim3(1), 384, 0, stream>>>(cls_t, pos, ln1_g, ln1_b, inp_w, inp_b, xcls16, qvec);
  rprep_k<<<dim3(6), 384, 0, stream>>>(inp_w, inp_b, qvec, xcls16, Rg, Cg, scls);
  bcast_cls_k<<<dim3(128), 384, 0, stream>>>(xcls16, scls, xh, sg);

  // ---- fused implicit-im2col embed GEMM + LN1 + score epilogue (pipelined) ----
  embed_ln_k<<<dim3(392), 1024, 0, stream>>>(
      x, convw, conv_b, pos, ln1_g, ln1_b, Rg, Cg, xh, sg);

  // ---- softmax -> P32; u-GEMV -> U16; projections ----
  softmax_k<<<dim3(128), 384, 0, stream>>>(sg, p32);
  u_gemv_k<<<dim3(3, 128), 256, 0, stream>>>(p32, xh, u16);
  vproj_k<<<dim3(6), 256, 0, stream>>>(u16, wv16, inp_b, o16);
  oproj_k<<<dim3(6), 256, 0, stream>>>(o16, wout16, outp_b, o2cls);
  ln_router_k<<<dim3(128), 384, 0, stream>>>(
      o2cls, ln1_g, ln1_b, rt_w, rt_b, hcls16, maskw);

  // ---- MoE ----
  moe1_k<<<dim3(24, 4), 256, 0, stream>>>(hcls16, ew1t, eb1, ehbuf);
  moe2_k<<<dim3(6, 4, 4), 256, 0, stream>>>(ehbuf, ew2t, epart);
  combine_ln2_k<<<dim3(128), 384, 0, stream>>>(epart, eb2, maskw, ln2_g, ln2_b, hfin);

  // ---- head ----
  head_gemm_k<<<dim3(8), 256, 0, stream>>>(hfin, headw16, head_b, out);
  (void)in_sizes; (void)n_in; (void)out_size;
}